// Round 6
// baseline (430.356 us; speedup 1.0000x reference)
//
#include <hip/hip_runtime.h>

#define N_NODES 50000
#define N_EDGES 200000
#define DE 32
#define N_FRAG 10000
#define N_GRAPH 2000
#define BN_SLOTS 32
#define KSTR 296   // LDS stride (fp16 elems) for the 32-row A/h1 plane

typedef _Float16 f16x8 __attribute__((ext_vector_type(8)));
typedef _Float16 f16x4 __attribute__((ext_vector_type(4)));
typedef __attribute__((ext_vector_type(4))) float f32x4;

__device__ __forceinline__ float4 ld4(const float* p) { return *(const float4*)p; }
__device__ __forceinline__ float4 ld4(const _Float16* p) {
    f16x4 h = *(const f16x4*)p;
    float4 v; v.x = (float)h[0]; v.y = (float)h[1]; v.z = (float)h[2]; v.w = (float)h[3];
    return v;
}
__device__ __forceinline__ void st4h(_Float16* p, float4 v) {
    f16x4 h = {(_Float16)v.x, (_Float16)v.y, (_Float16)v.z, (_Float16)v.w};
    *(f16x4*)p = h;
}

// ---------------------------------------------------------------------------
// CSR build: in-degree count, hierarchical scan, fill
__global__ __launch_bounds__(256)
void count_deg_kernel(const int* __restrict__ ei, int* __restrict__ deg) {
    int e = blockIdx.x * 256 + threadIdx.x;
    if (e < N_EDGES) atomicAdd(&deg[ei[N_EDGES + e]], 1);
}

__global__ __launch_bounds__(256)
void block_sum_kernel(const int* __restrict__ deg, int* __restrict__ bsum) {
    int i = blockIdx.x * 256 + threadIdx.x;
    int v = (i < N_NODES) ? deg[i] : 0;
#pragma unroll
    for (int o = 1; o < 64; o <<= 1) v += __shfl_xor(v, o);
    __shared__ int wsum[4];
    if ((threadIdx.x & 63) == 0) wsum[threadIdx.x >> 6] = v;
    __syncthreads();
    if (threadIdx.x == 0) bsum[blockIdx.x] = wsum[0] + wsum[1] + wsum[2] + wsum[3];
}

__global__ __launch_bounds__(256)
void top_scan_kernel(int* __restrict__ bsum, int nb) {
    __shared__ int s[256];
    int t = threadIdx.x;
    s[t] = (t < nb) ? bsum[t] : 0;
    __syncthreads();
    for (int o = 1; o < 256; o <<= 1) {
        int v = s[t];
        int a = (t >= o) ? s[t - o] : 0;
        __syncthreads();
        s[t] = v + a;
        __syncthreads();
    }
    if (t < nb) bsum[t] = (t > 0) ? s[t - 1] : 0;
}

__global__ __launch_bounds__(256)
void final_scan_kernel(const int* __restrict__ deg, const int* __restrict__ bsum,
                       int* __restrict__ ptr) {
    __shared__ int s[256];
    int i = blockIdx.x * 256 + threadIdx.x;
    int t = threadIdx.x;
    int v = (i < N_NODES) ? deg[i] : 0;
    s[t] = v;
    __syncthreads();
    for (int o = 1; o < 256; o <<= 1) {
        int x = s[t];
        int a = (t >= o) ? s[t - o] : 0;
        __syncthreads();
        s[t] = x + a;
        __syncthreads();
    }
    int incl = s[t];
    int base = bsum[blockIdx.x];
    if (i < N_NODES) ptr[i] = base + incl - v;
    if (i == N_NODES - 1) ptr[N_NODES] = base + incl;
}

__global__ __launch_bounds__(256)
void fill_csr_kernel(const int* __restrict__ ei, const int* __restrict__ row_ptr,
                     int* __restrict__ fill, int* __restrict__ csr_src,
                     int* __restrict__ csr_eid) {
    int e = blockIdx.x * 256 + threadIdx.x;
    if (e >= N_EDGES) return;
    int dst = ei[N_EDGES + e];
    int pos = row_ptr[dst] + atomicAdd(&fill[dst], 1);
    csr_src[pos] = ei[e];
    csr_eid[pos] = e;
}

__global__ __launch_bounds__(256)
void segptr_kernel(const int* __restrict__ batch, int nseg, int* __restrict__ ptr) {
    int s = blockIdx.x * 256 + threadIdx.x;
    if (s > nseg) return;
    int lo = 0, hi = N_NODES;
    while (lo < hi) {
        int mid = (lo + hi) >> 1;
        if (batch[mid] < s) lo = mid + 1; else hi = mid;
    }
    ptr[s] = lo;
}

// ---------------------------------------------------------------------------
// W [K][256] fp32 -> fragment-swizzled fp16 BS:
// BS[kt][cg][lane][j] = fp16(W[kt*32 + (lane>>4)*8 + j][cg*16 + (lane&15)])
__global__ __launch_bounds__(256)
void bs16_kernel(const float* __restrict__ W, _Float16* __restrict__ BS, int K) {
    int id = blockIdx.x * 256 + threadIdx.x;
    if (id >= K * 256) return;
    int j  = id & 7;
    int l  = (id >> 3) & 63;
    int cg = (id >> 9) & 15;
    int kt = id >> 13;
    int col = cg * 16 + (l & 15);
    int k   = kt * 32 + (l >> 4) * 8 + j;
    BS[id] = (_Float16)W[(size_t)k * 256 + col];
}

// ---------------------------------------------------------------------------
// agg_e[n] = sum over incoming edges of relu(edge_attr[e])  [N,32]
// depth-2 pipelined loads: next edge's 16B load issued before current's adds.
__global__ __launch_bounds__(256)
void edge_gather_kernel(const float* __restrict__ ea, const int* __restrict__ row_ptr,
                        const int* __restrict__ csr_eid, float* __restrict__ agg_e) {
    int t = threadIdx.x;
    int g = t >> 3;
    int j = t & 7;
    int n = blockIdx.x * 32 + g;
    if (n >= N_NODES) return;
    int col = j << 2;
    float4 acc = {0.f, 0.f, 0.f, 0.f};
    int beg = row_ptr[n], end = row_ptr[n + 1];
    float4 v0 = {0.f, 0.f, 0.f, 0.f};
    if (beg < end)
        v0 = *(const float4*)(ea + (size_t)csr_eid[beg] * DE + col);
    for (int e = beg; e < end; ++e) {
        float4 v1 = v0;
        if (e + 1 < end)
            v1 = *(const float4*)(ea + (size_t)csr_eid[e + 1] * DE + col);
        acc.x += fmaxf(v0.x, 0.f);
        acc.y += fmaxf(v0.y, 0.f);
        acc.z += fmaxf(v0.z, 0.f);
        acc.w += fmaxf(v0.w, 0.f);
        v0 = v1;
    }
    *(float4*)(agg_e + (size_t)n * DE + col) = acc;
}

// ---------------------------------------------------------------------------
// Pre-activation buffers for the gather: Y0 = fp16(relu(x)) (layer 0),
// Y = fp16(relu(sc*h+sh)) (layers 1,2). Gather loop then is pure fp16 adds.
__global__ __launch_bounds__(256)
void relu16_f32_kernel(const float* __restrict__ x, _Float16* __restrict__ y) {
    size_t i = (size_t)(blockIdx.x * 256 + threadIdx.x) * 4;   // N*128 total
    if (i >= (size_t)N_NODES * 128) return;
    float4 v = ld4(x + i);
    f16x4 o = {(_Float16)fmaxf(v.x, 0.f), (_Float16)fmaxf(v.y, 0.f),
               (_Float16)fmaxf(v.z, 0.f), (_Float16)fmaxf(v.w, 0.f)};
    *(f16x4*)(y + i) = o;
}

__global__ __launch_bounds__(256)
void bnrelu16_kernel(const _Float16* __restrict__ h, const float* __restrict__ sc,
                     const float* __restrict__ sh, _Float16* __restrict__ y) {
    size_t i = (size_t)(blockIdx.x * 256 + threadIdx.x) * 8;   // N*256 total
    if (i >= (size_t)N_NODES * 256) return;
    int col = (int)(i & 255);
    f16x8 v = *(const f16x8*)(h + i);
    float4 s0 = ld4(sc + col), s1 = ld4(sc + col + 4);
    float4 t0 = ld4(sh + col), t1 = ld4(sh + col + 4);
    f16x8 o;
    o[0] = (_Float16)fmaxf(fmaf((float)v[0], s0.x, t0.x), 0.f);
    o[1] = (_Float16)fmaxf(fmaf((float)v[1], s0.y, t0.y), 0.f);
    o[2] = (_Float16)fmaxf(fmaf((float)v[2], s0.z, t0.z), 0.f);
    o[3] = (_Float16)fmaxf(fmaf((float)v[3], s0.w, t0.w), 0.f);
    o[4] = (_Float16)fmaxf(fmaf((float)v[4], s1.x, t1.x), 0.f);
    o[5] = (_Float16)fmaxf(fmaf((float)v[5], s1.y, t1.y), 0.f);
    o[6] = (_Float16)fmaxf(fmaf((float)v[6], s1.z, t1.z), 0.f);
    o[7] = (_Float16)fmaxf(fmaf((float)v[7], s1.w, t1.w), 0.f);
    *(f16x8*)(y + i) = o;
}

// ---------------------------------------------------------------------------
// Fused gather + MLP (occupancy + ILP build):
//   stage: agg row = self(BN) + sum_{e} Y[src] || agg_e[n]; neighbor sum in
//          PACKED fp16, depth-2 software pipeline (next edge's 4x16B loads in
//          flight while current edge's adds retire).
//   then:  xout = fp16(relu( relu(A@W1+b1) @ W2 + b2 )), + BN stats.
// 32 rows/block, 4 waves each own a 64-col slab; ~18.9KB LDS.
// __launch_bounds__(256,6): VGPR cap ~85. Occupancy is GRID-limited at
// ~6 blocks/CU (1563 blocks / 256 CU), so regs spent on ILP are free.
// (R5 data: occ 51% @ VGPR 32 broke the occ x dur invariant -> per-wave
//  stall, not concurrency, is the limiter now.)
template <bool BNIN, typename T, int NC>   // DIN = NC*32, K1 = DIN+32
__global__ __launch_bounds__(256, 6)
void fused_mlp_kernel(const T* __restrict__ X, const _Float16* __restrict__ Yg,
                      const int* __restrict__ row_ptr, const int* __restrict__ csr_src,
                      const float* __restrict__ agg_e,
                      const float* __restrict__ bnsc, const float* __restrict__ bnsh,
                      const _Float16* __restrict__ B1, const float* __restrict__ bias1,
                      const _Float16* __restrict__ B2, const float* __restrict__ bias2,
                      _Float16* __restrict__ C, float* __restrict__ bnslot) {
    constexpr int DIN  = NC * 32;
    constexpr int K1   = DIN + 32;
    constexpr int NKT1 = K1 / 32;
    constexpr int CPT  = DIN / 8;        // cols per stage-thread
    constexpr int NV   = CPT / 8;        // f16x8 chunks per stage-thread
    __shared__ __align__(16) _Float16 sBuf[32 * KSTR];   // A tile, then h1
    const int t = threadIdx.x;
    const int l = t & 63;
    const int w = t >> 6;
    const int lr = l & 15;
    const int lq = l >> 4;
    const int row0 = blockIdx.x << 5;   // 32 rows/block
    const int cb = w << 6;

    // ---- stage: gather-aggregate directly into LDS (8 threads/row) ----
    {
        const int r = t >> 3, j = t & 7;
        const int gr = row0 + r;
        if (gr < N_NODES) {
            f16x8 acc16[NV];
#pragma unroll
            for (int c = 0; c < NV; ++c) acc16[c] = (f16x8){0, 0, 0, 0, 0, 0, 0, 0};
            const int beg = row_ptr[gr], end = row_ptr[gr + 1];
            // depth-2 pipelined fp16 neighbor loop
            f16x8 v0[NV];
            if (beg < end) {
                const _Float16* sp = Yg + (size_t)csr_src[beg] * DIN + j * CPT;
#pragma unroll
                for (int c = 0; c < NV; ++c) v0[c] = *(const f16x8*)(sp + c * 8);
            }
            for (int e = beg; e < end; ++e) {
                f16x8 v1[NV];
                if (e + 1 < end) {
                    const _Float16* sp = Yg + (size_t)csr_src[e + 1] * DIN + j * CPT;
#pragma unroll
                    for (int c = 0; c < NV; ++c) v1[c] = *(const f16x8*)(sp + c * 8);
                } else {
#pragma unroll
                    for (int c = 0; c < NV; ++c) v1[c] = v0[c];
                }
#pragma unroll
                for (int c = 0; c < NV; ++c) acc16[c] += v0[c];
#pragma unroll
                for (int c = 0; c < NV; ++c) v0[c] = v1[c];
            }
            // self term (BN if BNIN, no relu) + fp16 neighbor sum, 8 cols/chunk
            const T* xp = X + (size_t)gr * DIN + j * CPT;
#pragma unroll
            for (int c = 0; c < NV; ++c) {
                float4 v0f = ld4(xp + c * 8);
                float4 v1f = ld4(xp + c * 8 + 4);
                if (BNIN) {
                    float4 sa = *(const float4*)(bnsc + j * CPT + c * 8);
                    float4 sb = *(const float4*)(bnsc + j * CPT + c * 8 + 4);
                    float4 ta = *(const float4*)(bnsh + j * CPT + c * 8);
                    float4 tb = *(const float4*)(bnsh + j * CPT + c * 8 + 4);
                    v0f.x = fmaf(v0f.x, sa.x, ta.x);
                    v0f.y = fmaf(v0f.y, sa.y, ta.y);
                    v0f.z = fmaf(v0f.z, sa.z, ta.z);
                    v0f.w = fmaf(v0f.w, sa.w, ta.w);
                    v1f.x = fmaf(v1f.x, sb.x, tb.x);
                    v1f.y = fmaf(v1f.y, sb.y, tb.y);
                    v1f.z = fmaf(v1f.z, sb.z, tb.z);
                    v1f.w = fmaf(v1f.w, sb.w, tb.w);
                }
                f16x8 o;
                o[0] = (_Float16)(v0f.x + (float)acc16[c][0]);
                o[1] = (_Float16)(v0f.y + (float)acc16[c][1]);
                o[2] = (_Float16)(v0f.z + (float)acc16[c][2]);
                o[3] = (_Float16)(v0f.w + (float)acc16[c][3]);
                o[4] = (_Float16)(v1f.x + (float)acc16[c][4]);
                o[5] = (_Float16)(v1f.y + (float)acc16[c][5]);
                o[6] = (_Float16)(v1f.z + (float)acc16[c][6]);
                o[7] = (_Float16)(v1f.w + (float)acc16[c][7]);
                *(f16x8*)&sBuf[r * KSTR + j * CPT + c * 8] = o;
            }
            float4 ev = *(const float4*)(agg_e + (size_t)gr * DE + (j << 2));
            st4h(&sBuf[r * KSTR + DIN + (j << 2)], ev);
        } else {
            f16x8 z8 = {0, 0, 0, 0, 0, 0, 0, 0};
#pragma unroll
            for (int c = 0; c < NV; ++c)
                *(f16x8*)&sBuf[r * KSTR + j * CPT + c * 8] = z8;
            f16x4 z4 = {0, 0, 0, 0};
            *(f16x4*)&sBuf[r * KSTR + DIN + (j << 2)] = z4;
        }
    }
    __syncthreads();

    // ---- phase 1: A @ W1 (barrier-free) ----
    f32x4 acc1[2][4];
#pragma unroll
    for (int mt = 0; mt < 2; ++mt)
#pragma unroll
        for (int nt = 0; nt < 4; ++nt) acc1[mt][nt] = (f32x4){0.f, 0.f, 0.f, 0.f};
#pragma unroll
    for (int kt = 0; kt < NKT1; ++kt) {
        f16x8 af[2], bf[4];
#pragma unroll
        for (int mt = 0; mt < 2; ++mt)
            af[mt] = *(const f16x8*)&sBuf[(mt * 16 + lr) * KSTR + (kt << 5) + (lq << 3)];
        const size_t bb = ((size_t)(kt * 16 + (w << 2))) * 512 + (l << 3);
#pragma unroll
        for (int nt = 0; nt < 4; ++nt)
            bf[nt] = *(const f16x8*)(B1 + bb + nt * 512);
#pragma unroll
        for (int mt = 0; mt < 2; ++mt)
#pragma unroll
            for (int nt = 0; nt < 4; ++nt)
                acc1[mt][nt] = __builtin_amdgcn_mfma_f32_16x16x32_f16(
                    af[mt], bf[nt], acc1[mt][nt], 0, 0, 0);
    }
    __syncthreads();   // A tile dead; reuse plane for h1

    // ---- epilogue 1: relu(h1) -> LDS fp16 ----
#pragma unroll
    for (int nt = 0; nt < 4; ++nt) {
        int col = cb + nt * 16 + lr;
        float bv = bias1[col];
#pragma unroll
        for (int mt = 0; mt < 2; ++mt)
#pragma unroll
            for (int i = 0; i < 4; ++i) {
                int rr = mt * 16 + lq * 4 + i;
                sBuf[rr * KSTR + col] = (_Float16)fmaxf(acc1[mt][nt][i] + bv, 0.f);
            }
    }
    __syncthreads();

    // ---- phase 2: h1 @ W2 (barrier-free) ----
    f32x4 acc2[2][4];
#pragma unroll
    for (int mt = 0; mt < 2; ++mt)
#pragma unroll
        for (int nt = 0; nt < 4; ++nt) acc2[mt][nt] = (f32x4){0.f, 0.f, 0.f, 0.f};
#pragma unroll
    for (int kt = 0; kt < 8; ++kt) {
        f16x8 af[2], bf[4];
#pragma unroll
        for (int mt = 0; mt < 2; ++mt)
            af[mt] = *(const f16x8*)&sBuf[(mt * 16 + lr) * KSTR + (kt << 5) + (lq << 3)];
        const size_t bb = ((size_t)(kt * 16 + (w << 2))) * 512 + (l << 3);
#pragma unroll
        for (int nt = 0; nt < 4; ++nt)
            bf[nt] = *(const f16x8*)(B2 + bb + nt * 512);
#pragma unroll
        for (int mt = 0; mt < 2; ++mt)
#pragma unroll
            for (int nt = 0; nt < 4; ++nt)
                acc2[mt][nt] = __builtin_amdgcn_mfma_f32_16x16x32_f16(
                    af[mt], bf[nt], acc2[mt][nt], 0, 0, 0);
    }

    // ---- epilogue 2: bias + relu + fp16 store + BN stats ----
    float* slot = bnslot + (size_t)(blockIdx.x & (BN_SLOTS - 1)) * 512;
#pragma unroll
    for (int nt = 0; nt < 4; ++nt) {
        int col = cb + nt * 16 + lr;
        float bv = bias2[col];
        float s = 0.f, qq = 0.f;
#pragma unroll
        for (int mt = 0; mt < 2; ++mt)
#pragma unroll
            for (int i = 0; i < 4; ++i) {
                int row = row0 + mt * 16 + lq * 4 + i;
                if (row < N_NODES) {
                    float o = fmaxf(acc2[mt][nt][i] + bv, 0.f);
                    C[(size_t)row * 256 + col] = (_Float16)o;
                    s += o; qq += o * o;
                }
            }
        s += __shfl_xor(s, 16); s += __shfl_xor(s, 32);
        qq += __shfl_xor(qq, 16); qq += __shfl_xor(qq, 32);
        if (lq == 0) {
            atomicAdd(&slot[col], s);
            atomicAdd(&slot[256 + col], qq);
        }
    }
}

// reduce BN_SLOTS slots -> scale/shift
__global__ void bn_finalize_kernel(const float* __restrict__ slots,
                                   const float* __restrict__ g, const float* __restrict__ beta,
                                   float* __restrict__ scale, float* __restrict__ shift) {
    int c = threadIdx.x;
    float s = 0.f, q = 0.f;
    for (int k = 0; k < BN_SLOTS; ++k) {
        s += slots[(size_t)k * 512 + c];
        q += slots[(size_t)k * 512 + 256 + c];
    }
    float mu = s * (1.0f / N_NODES);
    float var = q * (1.0f / N_NODES) - mu * mu;
    float rstd = rsqrtf(var + 1e-5f);
    float sc = g[c] * rstd;
    scale[c] = sc;
    shift[c] = beta[c] - mu * sc;
}

// segmented sqrt-pool (fp16 input) with BN applied at load; fp32 output
__global__ __launch_bounds__(256)
void pool_seg_kernel(const _Float16* __restrict__ h, const int* __restrict__ ptr,
                     const float* __restrict__ bnsc, const float* __restrict__ bnsh,
                     float* __restrict__ out, int nseg) {
    int t = threadIdx.x;
    int g = t >> 6;
    int j = t & 63;
    int s = blockIdx.x * 4 + g;
    if (s >= nseg) return;
    int beg = ptr[s], end = ptr[s + 1];
    int col = j << 2;
    float4 sc = *(const float4*)(bnsc + col);
    float4 sh = *(const float4*)(bnsh + col);
    float4 acc = {0.f, 0.f, 0.f, 0.f};
    for (int i = beg; i < end; ++i) {
        float4 v = ld4(h + (size_t)i * 256 + col);
        acc.x += fmaf(v.x, sc.x, sh.x);
        acc.y += fmaf(v.y, sc.y, sh.y);
        acc.z += fmaf(v.z, sc.z, sh.z);
        acc.w += fmaf(v.w, sc.w, sh.w);
    }
    float w = rsqrtf(fmaxf((float)(end - beg), 1.0f));
    float4 o = {acc.x * w, acc.y * w, acc.z * w, acc.w * w};
    *(float4*)(out + (size_t)s * 256 + col) = o;
}

// ---------------------------------------------------------------------------
extern "C" void kernel_launch(void* const* d_in, const int* in_sizes, int n_in,
                              void* d_out, int out_size, void* d_ws, size_t ws_size,
                              hipStream_t stream) {
    const float* x  = (const float*)d_in[0];
    const float* ea = (const float*)d_in[1];
    const int*   ei = (const int*)d_in[2];
    const int*   fb = (const int*)d_in[3];
    const int*   gb = (const int*)d_in[4];
    const float* W1[3]   = {(const float*)d_in[5],  (const float*)d_in[11], (const float*)d_in[17]};
    const float* B1[3]   = {(const float*)d_in[6],  (const float*)d_in[12], (const float*)d_in[18]};
    const float* W2[3]   = {(const float*)d_in[7],  (const float*)d_in[13], (const float*)d_in[19]};
    const float* B2[3]   = {(const float*)d_in[8],  (const float*)d_in[14], (const float*)d_in[20]};
    const float* G[3]    = {(const float*)d_in[9],  (const float*)d_in[15], (const float*)d_in[21]};
    const float* BETA[3] = {(const float*)d_in[10], (const float*)d_in[16], (const float*)d_in[22]};

    const int FIN[3] = {160, 288, 288};
    const int NBLK = (N_NODES + 255) / 256;      // scan blocks

    float* ws = (float*)d_ws;
    size_t off = 0;
    _Float16* bufA = (_Float16*)(ws + off); off += (size_t)N_NODES * 128;  // N x 256 fp16
    _Float16* bufB = (_Float16*)(ws + off); off += (size_t)N_NODES * 128;
    _Float16* ybuf = (_Float16*)(ws + off); off += (size_t)N_NODES * 128;  // pre-activation Y
    float* agg_e = ws + off; off += (size_t)N_NODES * DE;
    float* bnss  = ws + off; off += 3 * 512;                 // per layer: scale|shift
    float* bnslots = ws + off; off += (size_t)3 * BN_SLOTS * 512;
    _Float16* w1f[3]; _Float16* w2f[3];
    {
        _Float16* sw = (_Float16*)(ws + off);
        _Float16* sw0 = sw;
        for (int l = 0; l < 3; ++l) { w1f[l] = sw; sw += 256 * FIN[l]; }
        for (int l = 0; l < 3; ++l) { w2f[l] = sw; sw += 256 * 256; }
        off += (size_t)(sw - sw0 + 1) / 2;
    }
    int* iw      = (int*)(ws + off);
    int* row_ptr = iw;                     iw += N_NODES + 1;
    int* deg     = iw;                     iw += N_NODES;
    int* fill    = iw;                     iw += N_NODES;
    int* csr_src = iw;                     iw += N_EDGES;
    int* csr_eid = iw;                     iw += N_EDGES;
    int* frag_ptr = iw;                    iw += N_FRAG + 1;
    int* graph_ptr = iw;                   iw += N_GRAPH + 1;
    int* bsum    = iw;                     iw += NBLK;

    hipMemsetAsync(deg, 0, 2 * N_NODES * sizeof(int), stream);
    hipMemsetAsync(bnslots, 0, (size_t)3 * BN_SLOTS * 512 * sizeof(float), stream);

    // weight fragment-swizzle to fp16 (once per layer)
    for (int l = 0; l < 3; ++l) {
        bs16_kernel<<<(FIN[l] * 256 + 255) / 256, 256, 0, stream>>>(W1[l], w1f[l], FIN[l]);
        bs16_kernel<<<(256 * 256 + 255) / 256, 256, 0, stream>>>(W2[l], w2f[l], 256);
    }

    // CSR build (hierarchical scan)
    count_deg_kernel<<<(N_EDGES + 255) / 256, 256, 0, stream>>>(ei, deg);
    block_sum_kernel<<<NBLK, 256, 0, stream>>>(deg, bsum);
    top_scan_kernel<<<1, 256, 0, stream>>>(bsum, NBLK);
    final_scan_kernel<<<NBLK, 256, 0, stream>>>(deg, bsum, row_ptr);
    fill_csr_kernel<<<(N_EDGES + 255) / 256, 256, 0, stream>>>(ei, row_ptr, fill, csr_src, csr_eid);

    segptr_kernel<<<(N_FRAG + 1 + 255) / 256, 256, 0, stream>>>(fb, N_FRAG, frag_ptr);
    segptr_kernel<<<(N_GRAPH + 1 + 255) / 256, 256, 0, stream>>>(gb, N_GRAPH, graph_ptr);

    edge_gather_kernel<<<(N_NODES + 31) / 32, 256, 0, stream>>>(ea, row_ptr, csr_eid, agg_e);

    const int nblk_mlp = (N_NODES + 31) / 32;    // 1563 blocks, 32 rows each
    // layer 0: Y0 = fp16(relu(x)), self = x (fp32)
    relu16_f32_kernel<<<(N_NODES * 128 / 4 + 255) / 256, 256, 0, stream>>>(x, ybuf);
    {
        float* slotsL = bnslots;
        fused_mlp_kernel<false, float, 4><<<nblk_mlp, 256, 0, stream>>>(
            x, ybuf, row_ptr, csr_src, agg_e, nullptr, nullptr,
            w1f[0], B1[0], w2f[0], B2[0], bufA, slotsL);
        bn_finalize_kernel<<<1, 256, 0, stream>>>(slotsL, G[0], BETA[0], bnss, bnss + 256);
    }
    // layer 1: Y = fp16(relu(BN0(bufA))), self = BN0(bufA)
    {
        float* slotsL = bnslots + (size_t)1 * BN_SLOTS * 512;
        const float* psc = bnss, * psh = bnss + 256;
        bnrelu16_kernel<<<(N_NODES * 256 / 8 + 255) / 256, 256, 0, stream>>>(bufA, psc, psh, ybuf);
        fused_mlp_kernel<true, _Float16, 8><<<nblk_mlp, 256, 0, stream>>>(
            bufA, ybuf, row_ptr, csr_src, agg_e, psc, psh,
            w1f[1], B1[1], w2f[1], B2[1], bufB, slotsL);
        bn_finalize_kernel<<<1, 256, 0, stream>>>(slotsL, G[1], BETA[1], bnss + 512, bnss + 768);
    }
    // layer 2: Y = fp16(relu(BN1(bufB))), self = BN1(bufB)
    {
        float* slotsL = bnslots + (size_t)2 * BN_SLOTS * 512;
        const float* psc = bnss + 512, * psh = bnss + 768;
        bnrelu16_kernel<<<(N_NODES * 256 / 8 + 255) / 256, 256, 0, stream>>>(bufB, psc, psh, ybuf);
        fused_mlp_kernel<true, _Float16, 8><<<nblk_mlp, 256, 0, stream>>>(
            bufB, ybuf, row_ptr, csr_src, agg_e, psc, psh,
            w1f[2], B1[2], w2f[2], B2[2], bufA, slotsL);
        bn_finalize_kernel<<<1, 256, 0, stream>>>(slotsL, G[2], BETA[2], bnss + 1024, bnss + 1280);
    }

    const float* fsc = bnss + 2 * 512;   // layer-2 BN scale/shift
    const float* fsh = fsc + 256;
    pool_seg_kernel<<<(N_FRAG + 3) / 4, 256, 0, stream>>>(bufA, frag_ptr, fsc, fsh,
                                                          (float*)d_out, N_FRAG);
    pool_seg_kernel<<<(N_GRAPH + 3) / 4, 256, 0, stream>>>(bufA, graph_ptr, fsc, fsh,
                                                           (float*)d_out + (size_t)N_FRAG * 256, N_GRAPH);
}

// Round 7
// 414.108 us; speedup vs baseline: 1.0392x; 1.0392x over previous
//
#include <hip/hip_runtime.h>

#define N_NODES 50000
#define N_EDGES 200000
#define DE 32
#define N_FRAG 10000
#define N_GRAPH 2000
#define BN_SLOTS 32
#define KSTR 296   // LDS stride (fp16 elems) for the 32-row A/h1 plane

typedef _Float16 f16x8 __attribute__((ext_vector_type(8)));
typedef _Float16 f16x4 __attribute__((ext_vector_type(4)));
typedef __attribute__((ext_vector_type(4))) float f32x4;

__device__ __forceinline__ float4 ld4(const float* p) { return *(const float4*)p; }
__device__ __forceinline__ float4 ld4(const _Float16* p) {
    f16x4 h = *(const f16x4*)p;
    float4 v; v.x = (float)h[0]; v.y = (float)h[1]; v.z = (float)h[2]; v.w = (float)h[3];
    return v;
}
__device__ __forceinline__ void st4h(_Float16* p, float4 v) {
    f16x4 h = {(_Float16)v.x, (_Float16)v.y, (_Float16)v.z, (_Float16)v.w};
    *(f16x4*)p = h;
}

// ---------------------------------------------------------------------------
// CSR build: in-degree count, hierarchical scan, fill
__global__ __launch_bounds__(256)
void count_deg_kernel(const int* __restrict__ ei, int* __restrict__ deg) {
    int e = blockIdx.x * 256 + threadIdx.x;
    if (e < N_EDGES) atomicAdd(&deg[ei[N_EDGES + e]], 1);
}

__global__ __launch_bounds__(256)
void block_sum_kernel(const int* __restrict__ deg, int* __restrict__ bsum) {
    int i = blockIdx.x * 256 + threadIdx.x;
    int v = (i < N_NODES) ? deg[i] : 0;
#pragma unroll
    for (int o = 1; o < 64; o <<= 1) v += __shfl_xor(v, o);
    __shared__ int wsum[4];
    if ((threadIdx.x & 63) == 0) wsum[threadIdx.x >> 6] = v;
    __syncthreads();
    if (threadIdx.x == 0) bsum[blockIdx.x] = wsum[0] + wsum[1] + wsum[2] + wsum[3];
}

__global__ __launch_bounds__(256)
void top_scan_kernel(int* __restrict__ bsum, int nb) {
    __shared__ int s[256];
    int t = threadIdx.x;
    s[t] = (t < nb) ? bsum[t] : 0;
    __syncthreads();
    for (int o = 1; o < 256; o <<= 1) {
        int v = s[t];
        int a = (t >= o) ? s[t - o] : 0;
        __syncthreads();
        s[t] = v + a;
        __syncthreads();
    }
    if (t < nb) bsum[t] = (t > 0) ? s[t - 1] : 0;
}

__global__ __launch_bounds__(256)
void final_scan_kernel(const int* __restrict__ deg, const int* __restrict__ bsum,
                       int* __restrict__ ptr) {
    __shared__ int s[256];
    int i = blockIdx.x * 256 + threadIdx.x;
    int t = threadIdx.x;
    int v = (i < N_NODES) ? deg[i] : 0;
    s[t] = v;
    __syncthreads();
    for (int o = 1; o < 256; o <<= 1) {
        int x = s[t];
        int a = (t >= o) ? s[t - o] : 0;
        __syncthreads();
        s[t] = x + a;
        __syncthreads();
    }
    int incl = s[t];
    int base = bsum[blockIdx.x];
    if (i < N_NODES) ptr[i] = base + incl - v;
    if (i == N_NODES - 1) ptr[N_NODES] = base + incl;
}

__global__ __launch_bounds__(256)
void fill_csr_kernel(const int* __restrict__ ei, const int* __restrict__ row_ptr,
                     int* __restrict__ fill, int* __restrict__ csr_src,
                     int* __restrict__ csr_eid) {
    int e = blockIdx.x * 256 + threadIdx.x;
    if (e >= N_EDGES) return;
    int dst = ei[N_EDGES + e];
    int pos = row_ptr[dst] + atomicAdd(&fill[dst], 1);
    csr_src[pos] = ei[e];
    csr_eid[pos] = e;
}

__global__ __launch_bounds__(256)
void segptr_kernel(const int* __restrict__ batch, int nseg, int* __restrict__ ptr) {
    int s = blockIdx.x * 256 + threadIdx.x;
    if (s > nseg) return;
    int lo = 0, hi = N_NODES;
    while (lo < hi) {
        int mid = (lo + hi) >> 1;
        if (batch[mid] < s) lo = mid + 1; else hi = mid;
    }
    ptr[s] = lo;
}

// ---------------------------------------------------------------------------
// W [K][256] fp32 -> fragment-swizzled fp16 BS:
// BS[kt][cg][lane][j] = fp16(W[kt*32 + (lane>>4)*8 + j][cg*16 + (lane&15)])
__global__ __launch_bounds__(256)
void bs16_kernel(const float* __restrict__ W, _Float16* __restrict__ BS, int K) {
    int id = blockIdx.x * 256 + threadIdx.x;
    if (id >= K * 256) return;
    int j  = id & 7;
    int l  = (id >> 3) & 63;
    int cg = (id >> 9) & 15;
    int kt = id >> 13;
    int col = cg * 16 + (l & 15);
    int k   = kt * 32 + (l >> 4) * 8 + j;
    BS[id] = (_Float16)W[(size_t)k * 256 + col];
}

// ---------------------------------------------------------------------------
// agg_e[n] = sum over incoming edges of relu(edge_attr[e])  [N,32]
// (8 threads/row reading 16B each at lane-contiguous addresses: coalesced.)
__global__ __launch_bounds__(256)
void edge_gather_kernel(const float* __restrict__ ea, const int* __restrict__ row_ptr,
                        const int* __restrict__ csr_eid, float* __restrict__ agg_e) {
    int t = threadIdx.x;
    int g = t >> 3;
    int j = t & 7;
    int n = blockIdx.x * 32 + g;
    if (n >= N_NODES) return;
    int col = j << 2;
    float4 acc = {0.f, 0.f, 0.f, 0.f};
    int beg = row_ptr[n], end = row_ptr[n + 1];
    for (int e = beg; e < end; ++e) {
        int eid = csr_eid[e];
        float4 v = *(const float4*)(ea + (size_t)eid * DE + col);
        acc.x += fmaxf(v.x, 0.f);
        acc.y += fmaxf(v.y, 0.f);
        acc.z += fmaxf(v.z, 0.f);
        acc.w += fmaxf(v.w, 0.f);
    }
    *(float4*)(agg_e + (size_t)n * DE + col) = acc;
}

// ---------------------------------------------------------------------------
// Pre-activation buffers for the gather: Y0 = fp16(relu(x)) (layer 0),
// Y = fp16(relu(sc*h+sh)) (layers 1,2). Gather loop then is pure fp16 adds.
__global__ __launch_bounds__(256)
void relu16_f32_kernel(const float* __restrict__ x, _Float16* __restrict__ y) {
    size_t i = (size_t)(blockIdx.x * 256 + threadIdx.x) * 4;   // N*128 total
    if (i >= (size_t)N_NODES * 128) return;
    float4 v = ld4(x + i);
    f16x4 o = {(_Float16)fmaxf(v.x, 0.f), (_Float16)fmaxf(v.y, 0.f),
               (_Float16)fmaxf(v.z, 0.f), (_Float16)fmaxf(v.w, 0.f)};
    *(f16x4*)(y + i) = o;
}

__global__ __launch_bounds__(256)
void bnrelu16_kernel(const _Float16* __restrict__ h, const float* __restrict__ sc,
                     const float* __restrict__ sh, _Float16* __restrict__ y) {
    size_t i = (size_t)(blockIdx.x * 256 + threadIdx.x) * 8;   // N*256 total
    if (i >= (size_t)N_NODES * 256) return;
    int col = (int)(i & 255);
    f16x8 v = *(const f16x8*)(h + i);
    float4 s0 = ld4(sc + col), s1 = ld4(sc + col + 4);
    float4 t0 = ld4(sh + col), t1 = ld4(sh + col + 4);
    f16x8 o;
    o[0] = (_Float16)fmaxf(fmaf((float)v[0], s0.x, t0.x), 0.f);
    o[1] = (_Float16)fmaxf(fmaf((float)v[1], s0.y, t0.y), 0.f);
    o[2] = (_Float16)fmaxf(fmaf((float)v[2], s0.z, t0.z), 0.f);
    o[3] = (_Float16)fmaxf(fmaf((float)v[3], s0.w, t0.w), 0.f);
    o[4] = (_Float16)fmaxf(fmaf((float)v[4], s1.x, t1.x), 0.f);
    o[5] = (_Float16)fmaxf(fmaf((float)v[5], s1.y, t1.y), 0.f);
    o[6] = (_Float16)fmaxf(fmaf((float)v[6], s1.z, t1.z), 0.f);
    o[7] = (_Float16)fmaxf(fmaf((float)v[7], s1.w, t1.w), 0.f);
    *(f16x8*)(y + i) = o;
}

// ---------------------------------------------------------------------------
// Fused gather + MLP (coalesced-stage build):
//   stage: agg row = self(BN) + sum_{e} Y[src] || agg_e[n]; neighbor sum in
//          PACKED fp16. COALESCED lane layout: lane j, chunk c owns cols
//          [c*64 + j*8, +8) -> 8 lanes x 16B contiguous (128B) per row per
//          load instruction, vs old [j*CPT + c*8] layout whose lanes sat at
//          64B stride (every lane its own sector, 4x the L1 transactions).
//          R6 proved ILP-2 is not the lever (VALU/MFMA/HBM all idle at 48%
//          occ) -> the limiter is request count; this cuts it 4x for free.
//   then:  xout = fp16(relu( relu(A@W1+b1) @ W2 + b2 )), + BN stats.
// 32 rows/block, 4 waves each own a 64-col slab; ~18.9KB LDS.
// __launch_bounds__(256,8): R5's best occupancy config (VGPR 32, occ 51%).
template <bool BNIN, typename T, int NC>   // DIN = NC*32, K1 = DIN+32
__global__ __launch_bounds__(256, 8)
void fused_mlp_kernel(const T* __restrict__ X, const _Float16* __restrict__ Yg,
                      const int* __restrict__ row_ptr, const int* __restrict__ csr_src,
                      const float* __restrict__ agg_e,
                      const float* __restrict__ bnsc, const float* __restrict__ bnsh,
                      const _Float16* __restrict__ B1, const float* __restrict__ bias1,
                      const _Float16* __restrict__ B2, const float* __restrict__ bias2,
                      _Float16* __restrict__ C, float* __restrict__ bnslot) {
    constexpr int DIN  = NC * 32;
    constexpr int K1   = DIN + 32;
    constexpr int NKT1 = K1 / 32;
    constexpr int CPT  = DIN / 8;        // cols per stage-thread
    constexpr int NV   = CPT / 8;        // f16x8 chunks per stage-thread
    __shared__ __align__(16) _Float16 sBuf[32 * KSTR];   // A tile, then h1
    const int t = threadIdx.x;
    const int l = t & 63;
    const int w = t >> 6;
    const int lr = l & 15;
    const int lq = l >> 4;
    const int row0 = blockIdx.x << 5;   // 32 rows/block
    const int cb = w << 6;

    // ---- stage: gather-aggregate directly into LDS (8 threads/row) ----
    {
        const int r = t >> 3, j = t & 7;
        const int gr = row0 + r;
        const int jc = j << 3;           // lane's 8-col offset within a chunk
        if (gr < N_NODES) {
            f16x8 acc16[NV];
#pragma unroll
            for (int c = 0; c < NV; ++c) acc16[c] = (f16x8){0, 0, 0, 0, 0, 0, 0, 0};
            const int beg = row_ptr[gr], end = row_ptr[gr + 1];
            // fp16 neighbor loop; chunk c at cols [c*64 + jc, +8) -> lanes
            // contiguous within each 128B chunk (coalesced)
            for (int e = beg; e < end; ++e) {
                const _Float16* sp = Yg + (size_t)csr_src[e] * DIN + jc;
#pragma unroll
                for (int c = 0; c < NV; ++c) acc16[c] += *(const f16x8*)(sp + c * 64);
            }
            // self term (BN if BNIN, no relu) + fp16 neighbor sum
            const T* xp = X + (size_t)gr * DIN + jc;
#pragma unroll
            for (int c = 0; c < NV; ++c) {
                float4 v0f = ld4(xp + c * 64);
                float4 v1f = ld4(xp + c * 64 + 4);
                if (BNIN) {
                    float4 sa = *(const float4*)(bnsc + c * 64 + jc);
                    float4 sb = *(const float4*)(bnsc + c * 64 + jc + 4);
                    float4 ta = *(const float4*)(bnsh + c * 64 + jc);
                    float4 tb = *(const float4*)(bnsh + c * 64 + jc + 4);
                    v0f.x = fmaf(v0f.x, sa.x, ta.x);
                    v0f.y = fmaf(v0f.y, sa.y, ta.y);
                    v0f.z = fmaf(v0f.z, sa.z, ta.z);
                    v0f.w = fmaf(v0f.w, sa.w, ta.w);
                    v1f.x = fmaf(v1f.x, sb.x, tb.x);
                    v1f.y = fmaf(v1f.y, sb.y, tb.y);
                    v1f.z = fmaf(v1f.z, sb.z, tb.z);
                    v1f.w = fmaf(v1f.w, sb.w, tb.w);
                }
                f16x8 o;
                o[0] = (_Float16)(v0f.x + (float)acc16[c][0]);
                o[1] = (_Float16)(v0f.y + (float)acc16[c][1]);
                o[2] = (_Float16)(v0f.z + (float)acc16[c][2]);
                o[3] = (_Float16)(v0f.w + (float)acc16[c][3]);
                o[4] = (_Float16)(v1f.x + (float)acc16[c][4]);
                o[5] = (_Float16)(v1f.y + (float)acc16[c][5]);
                o[6] = (_Float16)(v1f.z + (float)acc16[c][6]);
                o[7] = (_Float16)(v1f.w + (float)acc16[c][7]);
                *(f16x8*)&sBuf[r * KSTR + c * 64 + jc] = o;
            }
            float4 ev = *(const float4*)(agg_e + (size_t)gr * DE + (j << 2));
            st4h(&sBuf[r * KSTR + DIN + (j << 2)], ev);
        } else {
            f16x8 z8 = {0, 0, 0, 0, 0, 0, 0, 0};
#pragma unroll
            for (int c = 0; c < NV; ++c)
                *(f16x8*)&sBuf[r * KSTR + c * 64 + jc] = z8;
            f16x4 z4 = {0, 0, 0, 0};
            *(f16x4*)&sBuf[r * KSTR + DIN + (j << 2)] = z4;
        }
    }
    __syncthreads();

    // ---- phase 1: A @ W1 (barrier-free) ----
    f32x4 acc1[2][4];
#pragma unroll
    for (int mt = 0; mt < 2; ++mt)
#pragma unroll
        for (int nt = 0; nt < 4; ++nt) acc1[mt][nt] = (f32x4){0.f, 0.f, 0.f, 0.f};
#pragma unroll
    for (int kt = 0; kt < NKT1; ++kt) {
        f16x8 af[2], bf[4];
#pragma unroll
        for (int mt = 0; mt < 2; ++mt)
            af[mt] = *(const f16x8*)&sBuf[(mt * 16 + lr) * KSTR + (kt << 5) + (lq << 3)];
        const size_t bb = ((size_t)(kt * 16 + (w << 2))) * 512 + (l << 3);
#pragma unroll
        for (int nt = 0; nt < 4; ++nt)
            bf[nt] = *(const f16x8*)(B1 + bb + nt * 512);
#pragma unroll
        for (int mt = 0; mt < 2; ++mt)
#pragma unroll
            for (int nt = 0; nt < 4; ++nt)
                acc1[mt][nt] = __builtin_amdgcn_mfma_f32_16x16x32_f16(
                    af[mt], bf[nt], acc1[mt][nt], 0, 0, 0);
    }
    __syncthreads();   // A tile dead; reuse plane for h1

    // ---- epilogue 1: relu(h1) -> LDS fp16 ----
#pragma unroll
    for (int nt = 0; nt < 4; ++nt) {
        int col = cb + nt * 16 + lr;
        float bv = bias1[col];
#pragma unroll
        for (int mt = 0; mt < 2; ++mt)
#pragma unroll
            for (int i = 0; i < 4; ++i) {
                int rr = mt * 16 + lq * 4 + i;
                sBuf[rr * KSTR + col] = (_Float16)fmaxf(acc1[mt][nt][i] + bv, 0.f);
            }
    }
    __syncthreads();

    // ---- phase 2: h1 @ W2 (barrier-free) ----
    f32x4 acc2[2][4];
#pragma unroll
    for (int mt = 0; mt < 2; ++mt)
#pragma unroll
        for (int nt = 0; nt < 4; ++nt) acc2[mt][nt] = (f32x4){0.f, 0.f, 0.f, 0.f};
#pragma unroll
    for (int kt = 0; kt < 8; ++kt) {
        f16x8 af[2], bf[4];
#pragma unroll
        for (int mt = 0; mt < 2; ++mt)
            af[mt] = *(const f16x8*)&sBuf[(mt * 16 + lr) * KSTR + (kt << 5) + (lq << 3)];
        const size_t bb = ((size_t)(kt * 16 + (w << 2))) * 512 + (l << 3);
#pragma unroll
        for (int nt = 0; nt < 4; ++nt)
            bf[nt] = *(const f16x8*)(B2 + bb + nt * 512);
#pragma unroll
        for (int mt = 0; mt < 2; ++mt)
#pragma unroll
            for (int nt = 0; nt < 4; ++nt)
                acc2[mt][nt] = __builtin_amdgcn_mfma_f32_16x16x32_f16(
                    af[mt], bf[nt], acc2[mt][nt], 0, 0, 0);
    }

    // ---- epilogue 2: bias + relu + fp16 store + BN stats ----
    float* slot = bnslot + (size_t)(blockIdx.x & (BN_SLOTS - 1)) * 512;
#pragma unroll
    for (int nt = 0; nt < 4; ++nt) {
        int col = cb + nt * 16 + lr;
        float bv = bias2[col];
        float s = 0.f, qq = 0.f;
#pragma unroll
        for (int mt = 0; mt < 2; ++mt)
#pragma unroll
            for (int i = 0; i < 4; ++i) {
                int row = row0 + mt * 16 + lq * 4 + i;
                if (row < N_NODES) {
                    float o = fmaxf(acc2[mt][nt][i] + bv, 0.f);
                    C[(size_t)row * 256 + col] = (_Float16)o;
                    s += o; qq += o * o;
                }
            }
        s += __shfl_xor(s, 16); s += __shfl_xor(s, 32);
        qq += __shfl_xor(qq, 16); qq += __shfl_xor(qq, 32);
        if (lq == 0) {
            atomicAdd(&slot[col], s);
            atomicAdd(&slot[256 + col], qq);
        }
    }
}

// reduce BN_SLOTS slots -> scale/shift
__global__ void bn_finalize_kernel(const float* __restrict__ slots,
                                   const float* __restrict__ g, const float* __restrict__ beta,
                                   float* __restrict__ scale, float* __restrict__ shift) {
    int c = threadIdx.x;
    float s = 0.f, q = 0.f;
    for (int k = 0; k < BN_SLOTS; ++k) {
        s += slots[(size_t)k * 512 + c];
        q += slots[(size_t)k * 512 + 256 + c];
    }
    float mu = s * (1.0f / N_NODES);
    float var = q * (1.0f / N_NODES) - mu * mu;
    float rstd = rsqrtf(var + 1e-5f);
    float sc = g[c] * rstd;
    scale[c] = sc;
    shift[c] = beta[c] - mu * sc;
}

// segmented sqrt-pool (fp16 input) with BN applied at load; fp32 output
__global__ __launch_bounds__(256)
void pool_seg_kernel(const _Float16* __restrict__ h, const int* __restrict__ ptr,
                     const float* __restrict__ bnsc, const float* __restrict__ bnsh,
                     float* __restrict__ out, int nseg) {
    int t = threadIdx.x;
    int g = t >> 6;
    int j = t & 63;
    int s = blockIdx.x * 4 + g;
    if (s >= nseg) return;
    int beg = ptr[s], end = ptr[s + 1];
    int col = j << 2;
    float4 sc = *(const float4*)(bnsc + col);
    float4 sh = *(const float4*)(bnsh + col);
    float4 acc = {0.f, 0.f, 0.f, 0.f};
    for (int i = beg; i < end; ++i) {
        float4 v = ld4(h + (size_t)i * 256 + col);
        acc.x += fmaf(v.x, sc.x, sh.x);
        acc.y += fmaf(v.y, sc.y, sh.y);
        acc.z += fmaf(v.z, sc.z, sh.z);
        acc.w += fmaf(v.w, sc.w, sh.w);
    }
    float w = rsqrtf(fmaxf((float)(end - beg), 1.0f));
    float4 o = {acc.x * w, acc.y * w, acc.z * w, acc.w * w};
    *(float4*)(out + (size_t)s * 256 + col) = o;
}

// ---------------------------------------------------------------------------
extern "C" void kernel_launch(void* const* d_in, const int* in_sizes, int n_in,
                              void* d_out, int out_size, void* d_ws, size_t ws_size,
                              hipStream_t stream) {
    const float* x  = (const float*)d_in[0];
    const float* ea = (const float*)d_in[1];
    const int*   ei = (const int*)d_in[2];
    const int*   fb = (const int*)d_in[3];
    const int*   gb = (const int*)d_in[4];
    const float* W1[3]   = {(const float*)d_in[5],  (const float*)d_in[11], (const float*)d_in[17]};
    const float* B1[3]   = {(const float*)d_in[6],  (const float*)d_in[12], (const float*)d_in[18]};
    const float* W2[3]   = {(const float*)d_in[7],  (const float*)d_in[13], (const float*)d_in[19]};
    const float* B2[3]   = {(const float*)d_in[8],  (const float*)d_in[14], (const float*)d_in[20]};
    const float* G[3]    = {(const float*)d_in[9],  (const float*)d_in[15], (const float*)d_in[21]};
    const float* BETA[3] = {(const float*)d_in[10], (const float*)d_in[16], (const float*)d_in[22]};

    const int FIN[3] = {160, 288, 288};
    const int NBLK = (N_NODES + 255) / 256;      // scan blocks

    float* ws = (float*)d_ws;
    size_t off = 0;
    _Float16* bufA = (_Float16*)(ws + off); off += (size_t)N_NODES * 128;  // N x 256 fp16
    _Float16* bufB = (_Float16*)(ws + off); off += (size_t)N_NODES * 128;
    _Float16* ybuf = (_Float16*)(ws + off); off += (size_t)N_NODES * 128;  // pre-activation Y
    float* agg_e = ws + off; off += (size_t)N_NODES * DE;
    float* bnss  = ws + off; off += 3 * 512;                 // per layer: scale|shift
    float* bnslots = ws + off; off += (size_t)3 * BN_SLOTS * 512;
    _Float16* w1f[3]; _Float16* w2f[3];
    {
        _Float16* sw = (_Float16*)(ws + off);
        _Float16* sw0 = sw;
        for (int l = 0; l < 3; ++l) { w1f[l] = sw; sw += 256 * FIN[l]; }
        for (int l = 0; l < 3; ++l) { w2f[l] = sw; sw += 256 * 256; }
        off += (size_t)(sw - sw0 + 1) / 2;
    }
    int* iw      = (int*)(ws + off);
    int* row_ptr = iw;                     iw += N_NODES + 1;
    int* deg     = iw;                     iw += N_NODES;
    int* fill    = iw;                     iw += N_NODES;
    int* csr_src = iw;                     iw += N_EDGES;
    int* csr_eid = iw;                     iw += N_EDGES;
    int* frag_ptr = iw;                    iw += N_FRAG + 1;
    int* graph_ptr = iw;                   iw += N_GRAPH + 1;
    int* bsum    = iw;                     iw += NBLK;

    hipMemsetAsync(deg, 0, 2 * N_NODES * sizeof(int), stream);
    hipMemsetAsync(bnslots, 0, (size_t)3 * BN_SLOTS * 512 * sizeof(float), stream);

    // weight fragment-swizzle to fp16 (once per layer)
    for (int l = 0; l < 3; ++l) {
        bs16_kernel<<<(FIN[l] * 256 + 255) / 256, 256, 0, stream>>>(W1[l], w1f[l], FIN[l]);
        bs16_kernel<<<(256 * 256 + 255) / 256, 256, 0, stream>>>(W2[l], w2f[l], 256);
    }

    // CSR build (hierarchical scan)
    count_deg_kernel<<<(N_EDGES + 255) / 256, 256, 0, stream>>>(ei, deg);
    block_sum_kernel<<<NBLK, 256, 0, stream>>>(deg, bsum);
    top_scan_kernel<<<1, 256, 0, stream>>>(bsum, NBLK);
    final_scan_kernel<<<NBLK, 256, 0, stream>>>(deg, bsum, row_ptr);
    fill_csr_kernel<<<(N_EDGES + 255) / 256, 256, 0, stream>>>(ei, row_ptr, fill, csr_src, csr_eid);

    segptr_kernel<<<(N_FRAG + 1 + 255) / 256, 256, 0, stream>>>(fb, N_FRAG, frag_ptr);
    segptr_kernel<<<(N_GRAPH + 1 + 255) / 256, 256, 0, stream>>>(gb, N_GRAPH, graph_ptr);

    edge_gather_kernel<<<(N_NODES + 31) / 32, 256, 0, stream>>>(ea, row_ptr, csr_eid, agg_e);

    const int nblk_mlp = (N_NODES + 31) / 32;    // 1563 blocks, 32 rows each
    // layer 0: Y0 = fp16(relu(x)), self = x (fp32)
    relu16_f32_kernel<<<(N_NODES * 128 / 4 + 255) / 256, 256, 0, stream>>>(x, ybuf);
    {
        float* slotsL = bnslots;
        fused_mlp_kernel<false, float, 4><<<nblk_mlp, 256, 0, stream>>>(
            x, ybuf, row_ptr, csr_src, agg_e, nullptr, nullptr,
            w1f[0], B1[0], w2f[0], B2[0], bufA, slotsL);
        bn_finalize_kernel<<<1, 256, 0, stream>>>(slotsL, G[0], BETA[0], bnss, bnss + 256);
    }
    // layer 1: Y = fp16(relu(BN0(bufA))), self = BN0(bufA)
    {
        float* slotsL = bnslots + (size_t)1 * BN_SLOTS * 512;
        const float* psc = bnss, * psh = bnss + 256;
        bnrelu16_kernel<<<(N_NODES * 256 / 8 + 255) / 256, 256, 0, stream>>>(bufA, psc, psh, ybuf);
        fused_mlp_kernel<true, _Float16, 8><<<nblk_mlp, 256, 0, stream>>>(
            bufA, ybuf, row_ptr, csr_src, agg_e, psc, psh,
            w1f[1], B1[1], w2f[1], B2[1], bufB, slotsL);
        bn_finalize_kernel<<<1, 256, 0, stream>>>(slotsL, G[1], BETA[1], bnss + 512, bnss + 768);
    }
    // layer 2: Y = fp16(relu(BN1(bufB))), self = BN1(bufB)
    {
        float* slotsL = bnslots + (size_t)2 * BN_SLOTS * 512;
        const float* psc = bnss + 512, * psh = bnss + 768;
        bnrelu16_kernel<<<(N_NODES * 256 / 8 + 255) / 256, 256, 0, stream>>>(bufB, psc, psh, ybuf);
        fused_mlp_kernel<true, _Float16, 8><<<nblk_mlp, 256, 0, stream>>>(
            bufB, ybuf, row_ptr, csr_src, agg_e, psc, psh,
            w1f[2], B1[2], w2f[2], B2[2], bufA, slotsL);
        bn_finalize_kernel<<<1, 256, 0, stream>>>(slotsL, G[2], BETA[2], bnss + 1024, bnss + 1280);
    }

    const float* fsc = bnss + 2 * 512;   // layer-2 BN scale/shift
    const float* fsh = fsc + 256;
    pool_seg_kernel<<<(N_FRAG + 3) / 4, 256, 0, stream>>>(bufA, frag_ptr, fsc, fsh,
                                                          (float*)d_out, N_FRAG);
    pool_seg_kernel<<<(N_GRAPH + 3) / 4, 256, 0, stream>>>(bufA, graph_ptr, fsc, fsh,
                                                           (float*)d_out + (size_t)N_FRAG * 256, N_GRAPH);
}

// Round 8
// 376.161 us; speedup vs baseline: 1.1441x; 1.1009x over previous
//
#include <hip/hip_runtime.h>

#define N_NODES 50000
#define N_EDGES 200000
#define DE 32
#define N_FRAG 10000
#define N_GRAPH 2000
#define BN_SLOTS 32
#define KSTR 296   // LDS stride (fp16 elems) for the 32-row A/h1 plane

typedef _Float16 f16x8 __attribute__((ext_vector_type(8)));
typedef _Float16 f16x4 __attribute__((ext_vector_type(4)));
typedef __attribute__((ext_vector_type(4))) float f32x4;

__device__ __forceinline__ float4 ld4(const float* p) { return *(const float4*)p; }
__device__ __forceinline__ float4 ld4(const _Float16* p) {
    f16x4 h = *(const f16x4*)p;
    float4 v; v.x = (float)h[0]; v.y = (float)h[1]; v.z = (float)h[2]; v.w = (float)h[3];
    return v;
}
__device__ __forceinline__ void st4h(_Float16* p, float4 v) {
    f16x4 h = {(_Float16)v.x, (_Float16)v.y, (_Float16)v.z, (_Float16)v.w};
    *(f16x4*)p = h;
}

// ---------------------------------------------------------------------------
// CSR build: in-degree count, hierarchical scan, fill
__global__ __launch_bounds__(256)
void count_deg_kernel(const int* __restrict__ ei, int* __restrict__ deg) {
    int e = blockIdx.x * 256 + threadIdx.x;
    if (e < N_EDGES) atomicAdd(&deg[ei[N_EDGES + e]], 1);
}

__global__ __launch_bounds__(256)
void block_sum_kernel(const int* __restrict__ deg, int* __restrict__ bsum) {
    int i = blockIdx.x * 256 + threadIdx.x;
    int v = (i < N_NODES) ? deg[i] : 0;
#pragma unroll
    for (int o = 1; o < 64; o <<= 1) v += __shfl_xor(v, o);
    __shared__ int wsum[4];
    if ((threadIdx.x & 63) == 0) wsum[threadIdx.x >> 6] = v;
    __syncthreads();
    if (threadIdx.x == 0) bsum[blockIdx.x] = wsum[0] + wsum[1] + wsum[2] + wsum[3];
}

__global__ __launch_bounds__(256)
void top_scan_kernel(int* __restrict__ bsum, int nb) {
    __shared__ int s[256];
    int t = threadIdx.x;
    s[t] = (t < nb) ? bsum[t] : 0;
    __syncthreads();
    for (int o = 1; o < 256; o <<= 1) {
        int v = s[t];
        int a = (t >= o) ? s[t - o] : 0;
        __syncthreads();
        s[t] = v + a;
        __syncthreads();
    }
    if (t < nb) bsum[t] = (t > 0) ? s[t - 1] : 0;
}

__global__ __launch_bounds__(256)
void final_scan_kernel(const int* __restrict__ deg, const int* __restrict__ bsum,
                       int* __restrict__ ptr) {
    __shared__ int s[256];
    int i = blockIdx.x * 256 + threadIdx.x;
    int t = threadIdx.x;
    int v = (i < N_NODES) ? deg[i] : 0;
    s[t] = v;
    __syncthreads();
    for (int o = 1; o < 256; o <<= 1) {
        int x = s[t];
        int a = (t >= o) ? s[t - o] : 0;
        __syncthreads();
        s[t] = x + a;
        __syncthreads();
    }
    int incl = s[t];
    int base = bsum[blockIdx.x];
    if (i < N_NODES) ptr[i] = base + incl - v;
    if (i == N_NODES - 1) ptr[N_NODES] = base + incl;
}

__global__ __launch_bounds__(256)
void fill_csr_kernel(const int* __restrict__ ei, const int* __restrict__ row_ptr,
                     int* __restrict__ fill, int* __restrict__ csr_src,
                     int* __restrict__ csr_eid) {
    int e = blockIdx.x * 256 + threadIdx.x;
    if (e >= N_EDGES) return;
    int dst = ei[N_EDGES + e];
    int pos = row_ptr[dst] + atomicAdd(&fill[dst], 1);
    csr_src[pos] = ei[e];
    csr_eid[pos] = e;
}

__global__ __launch_bounds__(256)
void segptr_kernel(const int* __restrict__ batch, int nseg, int* __restrict__ ptr) {
    int s = blockIdx.x * 256 + threadIdx.x;
    if (s > nseg) return;
    int lo = 0, hi = N_NODES;
    while (lo < hi) {
        int mid = (lo + hi) >> 1;
        if (batch[mid] < s) lo = mid + 1; else hi = mid;
    }
    ptr[s] = lo;
}

// ---------------------------------------------------------------------------
// W [K][256] fp32 -> fragment-swizzled fp16 BS:
// BS[kt][cg][lane][j] = fp16(W[kt*32 + (lane>>4)*8 + j][cg*16 + (lane&15)])
__global__ __launch_bounds__(256)
void bs16_kernel(const float* __restrict__ W, _Float16* __restrict__ BS, int K) {
    int id = blockIdx.x * 256 + threadIdx.x;
    if (id >= K * 256) return;
    int j  = id & 7;
    int l  = (id >> 3) & 63;
    int cg = (id >> 9) & 15;
    int kt = id >> 13;
    int col = cg * 16 + (l & 15);
    int k   = kt * 32 + (l >> 4) * 8 + j;
    BS[id] = (_Float16)W[(size_t)k * 256 + col];
}

// ---------------------------------------------------------------------------
// agg_e[n] = sum over incoming edges of relu(edge_attr[e])  [N,32]
// (8 threads/row reading 16B each at lane-contiguous addresses: coalesced.)
__global__ __launch_bounds__(256)
void edge_gather_kernel(const float* __restrict__ ea, const int* __restrict__ row_ptr,
                        const int* __restrict__ csr_eid, float* __restrict__ agg_e) {
    int t = threadIdx.x;
    int g = t >> 3;
    int j = t & 7;
    int n = blockIdx.x * 32 + g;
    if (n >= N_NODES) return;
    int col = j << 2;
    float4 acc = {0.f, 0.f, 0.f, 0.f};
    int beg = row_ptr[n], end = row_ptr[n + 1];
    for (int e = beg; e < end; ++e) {
        int eid = csr_eid[e];
        float4 v = *(const float4*)(ea + (size_t)eid * DE + col);
        acc.x += fmaxf(v.x, 0.f);
        acc.y += fmaxf(v.y, 0.f);
        acc.z += fmaxf(v.z, 0.f);
        acc.w += fmaxf(v.w, 0.f);
    }
    *(float4*)(agg_e + (size_t)n * DE + col) = acc;
}

// ---------------------------------------------------------------------------
// Pre-activation buffers for the gather: Y0 = fp16(relu(x)) (layer 0),
// Y = fp16(relu(sc*h+sh)) (layers 1,2). Gather loop then is pure fp16 adds.
__global__ __launch_bounds__(256)
void relu16_f32_kernel(const float* __restrict__ x, _Float16* __restrict__ y) {
    size_t i = (size_t)(blockIdx.x * 256 + threadIdx.x) * 4;   // N*128 total
    if (i >= (size_t)N_NODES * 128) return;
    float4 v = ld4(x + i);
    f16x4 o = {(_Float16)fmaxf(v.x, 0.f), (_Float16)fmaxf(v.y, 0.f),
               (_Float16)fmaxf(v.z, 0.f), (_Float16)fmaxf(v.w, 0.f)};
    *(f16x4*)(y + i) = o;
}

__global__ __launch_bounds__(256)
void bnrelu16_kernel(const _Float16* __restrict__ h, const float* __restrict__ sc,
                     const float* __restrict__ sh, _Float16* __restrict__ y) {
    size_t i = (size_t)(blockIdx.x * 256 + threadIdx.x) * 8;   // N*256 total
    if (i >= (size_t)N_NODES * 256) return;
    int col = (int)(i & 255);
    f16x8 v = *(const f16x8*)(h + i);
    float4 s0 = ld4(sc + col), s1 = ld4(sc + col + 4);
    float4 t0 = ld4(sh + col), t1 = ld4(sh + col + 4);
    f16x8 o;
    o[0] = (_Float16)fmaxf(fmaf((float)v[0], s0.x, t0.x), 0.f);
    o[1] = (_Float16)fmaxf(fmaf((float)v[1], s0.y, t0.y), 0.f);
    o[2] = (_Float16)fmaxf(fmaf((float)v[2], s0.z, t0.z), 0.f);
    o[3] = (_Float16)fmaxf(fmaf((float)v[3], s0.w, t0.w), 0.f);
    o[4] = (_Float16)fmaxf(fmaf((float)v[4], s1.x, t1.x), 0.f);
    o[5] = (_Float16)fmaxf(fmaf((float)v[5], s1.y, t1.y), 0.f);
    o[6] = (_Float16)fmaxf(fmaf((float)v[6], s1.z, t1.z), 0.f);
    o[7] = (_Float16)fmaxf(fmaf((float)v[7], s1.w, t1.w), 0.f);
    *(f16x8*)(y + i) = o;
}

// ---------------------------------------------------------------------------
// Fused gather + MLP (register-pipelined build):
//   stage: agg row = self(BN) + sum_{e} Y[src] || agg_e[n]; packed fp16,
//          coalesced lane layout (R7: 4x fewer L1 transactions, proven +18%).
//   then:  xout = fp16(relu( relu(A@W1+b1) @ W2 + b2 )), + BN stats.
// __launch_bounds__(256,4): VGPR cap 128. R7's VGPR=32 build exposed the
// full latency of EVERY memory op (no regs to keep loads in flight); the
// unrolled K-loops need ~8 hoisted B-frags to overlap. Resident blocks are
// grid/tail-limited at ~4/CU anyway, so the extra regs cost no occupancy.
// Epilogue 2 writes C via LDS bounce: R7 measured WRITE_SIZE 63MB vs 26MB
// compulsory (scattered 2B stores -> half-sector RMW). Stage outputs in the
// dead sBuf plane, then f16x8 row-contiguous stores (4/thread vs 32).
template <bool BNIN, typename T, int NC>   // DIN = NC*32, K1 = DIN+32
__global__ __launch_bounds__(256, 4)
void fused_mlp_kernel(const T* __restrict__ X, const _Float16* __restrict__ Yg,
                      const int* __restrict__ row_ptr, const int* __restrict__ csr_src,
                      const float* __restrict__ agg_e,
                      const float* __restrict__ bnsc, const float* __restrict__ bnsh,
                      const _Float16* __restrict__ B1, const float* __restrict__ bias1,
                      const _Float16* __restrict__ B2, const float* __restrict__ bias2,
                      _Float16* __restrict__ C, float* __restrict__ bnslot) {
    constexpr int DIN  = NC * 32;
    constexpr int K1   = DIN + 32;
    constexpr int NKT1 = K1 / 32;
    constexpr int CPT  = DIN / 8;        // cols per stage-thread
    constexpr int NV   = CPT / 8;        // f16x8 chunks per stage-thread
    __shared__ __align__(16) _Float16 sBuf[32 * KSTR];   // A tile, h1, then C
    const int t = threadIdx.x;
    const int l = t & 63;
    const int w = t >> 6;
    const int lr = l & 15;
    const int lq = l >> 4;
    const int row0 = blockIdx.x << 5;   // 32 rows/block
    const int cb = w << 6;

    // ---- stage: gather-aggregate directly into LDS (8 threads/row) ----
    {
        const int r = t >> 3, j = t & 7;
        const int gr = row0 + r;
        const int jc = j << 3;           // lane's 8-col offset within a chunk
        if (gr < N_NODES) {
            f16x8 acc16[NV];
#pragma unroll
            for (int c = 0; c < NV; ++c) acc16[c] = (f16x8){0, 0, 0, 0, 0, 0, 0, 0};
            const int beg = row_ptr[gr], end = row_ptr[gr + 1];
            // fp16 neighbor loop; chunk c at cols [c*64 + jc, +8) -> lanes
            // contiguous within each 128B chunk (coalesced)
            for (int e = beg; e < end; ++e) {
                const _Float16* sp = Yg + (size_t)csr_src[e] * DIN + jc;
#pragma unroll
                for (int c = 0; c < NV; ++c) acc16[c] += *(const f16x8*)(sp + c * 64);
            }
            // self term (BN if BNIN, no relu) + fp16 neighbor sum
            const T* xp = X + (size_t)gr * DIN + jc;
#pragma unroll
            for (int c = 0; c < NV; ++c) {
                float4 v0f = ld4(xp + c * 64);
                float4 v1f = ld4(xp + c * 64 + 4);
                if (BNIN) {
                    float4 sa = *(const float4*)(bnsc + c * 64 + jc);
                    float4 sb = *(const float4*)(bnsc + c * 64 + jc + 4);
                    float4 ta = *(const float4*)(bnsh + c * 64 + jc);
                    float4 tb = *(const float4*)(bnsh + c * 64 + jc + 4);
                    v0f.x = fmaf(v0f.x, sa.x, ta.x);
                    v0f.y = fmaf(v0f.y, sa.y, ta.y);
                    v0f.z = fmaf(v0f.z, sa.z, ta.z);
                    v0f.w = fmaf(v0f.w, sa.w, ta.w);
                    v1f.x = fmaf(v1f.x, sb.x, tb.x);
                    v1f.y = fmaf(v1f.y, sb.y, tb.y);
                    v1f.z = fmaf(v1f.z, sb.z, tb.z);
                    v1f.w = fmaf(v1f.w, sb.w, tb.w);
                }
                f16x8 o;
                o[0] = (_Float16)(v0f.x + (float)acc16[c][0]);
                o[1] = (_Float16)(v0f.y + (float)acc16[c][1]);
                o[2] = (_Float16)(v0f.z + (float)acc16[c][2]);
                o[3] = (_Float16)(v0f.w + (float)acc16[c][3]);
                o[4] = (_Float16)(v1f.x + (float)acc16[c][4]);
                o[5] = (_Float16)(v1f.y + (float)acc16[c][5]);
                o[6] = (_Float16)(v1f.z + (float)acc16[c][6]);
                o[7] = (_Float16)(v1f.w + (float)acc16[c][7]);
                *(f16x8*)&sBuf[r * KSTR + c * 64 + jc] = o;
            }
            float4 ev = *(const float4*)(agg_e + (size_t)gr * DE + (j << 2));
            st4h(&sBuf[r * KSTR + DIN + (j << 2)], ev);
        } else {
            f16x8 z8 = {0, 0, 0, 0, 0, 0, 0, 0};
#pragma unroll
            for (int c = 0; c < NV; ++c)
                *(f16x8*)&sBuf[r * KSTR + c * 64 + jc] = z8;
            f16x4 z4 = {0, 0, 0, 0};
            *(f16x4*)&sBuf[r * KSTR + DIN + (j << 2)] = z4;
        }
    }
    __syncthreads();

    // ---- phase 1: A @ W1 (barrier-free) ----
    f32x4 acc1[2][4];
#pragma unroll
    for (int mt = 0; mt < 2; ++mt)
#pragma unroll
        for (int nt = 0; nt < 4; ++nt) acc1[mt][nt] = (f32x4){0.f, 0.f, 0.f, 0.f};
#pragma unroll
    for (int kt = 0; kt < NKT1; ++kt) {
        f16x8 af[2], bf[4];
#pragma unroll
        for (int mt = 0; mt < 2; ++mt)
            af[mt] = *(const f16x8*)&sBuf[(mt * 16 + lr) * KSTR + (kt << 5) + (lq << 3)];
        const size_t bb = ((size_t)(kt * 16 + (w << 2))) * 512 + (l << 3);
#pragma unroll
        for (int nt = 0; nt < 4; ++nt)
            bf[nt] = *(const f16x8*)(B1 + bb + nt * 512);
#pragma unroll
        for (int mt = 0; mt < 2; ++mt)
#pragma unroll
            for (int nt = 0; nt < 4; ++nt)
                acc1[mt][nt] = __builtin_amdgcn_mfma_f32_16x16x32_f16(
                    af[mt], bf[nt], acc1[mt][nt], 0, 0, 0);
    }
    __syncthreads();   // A tile dead; reuse plane for h1

    // ---- epilogue 1: relu(h1) -> LDS fp16 ----
#pragma unroll
    for (int nt = 0; nt < 4; ++nt) {
        int col = cb + nt * 16 + lr;
        float bv = bias1[col];
#pragma unroll
        for (int mt = 0; mt < 2; ++mt)
#pragma unroll
            for (int i = 0; i < 4; ++i) {
                int rr = mt * 16 + lq * 4 + i;
                sBuf[rr * KSTR + col] = (_Float16)fmaxf(acc1[mt][nt][i] + bv, 0.f);
            }
    }
    __syncthreads();

    // ---- phase 2: h1 @ W2 (barrier-free) ----
    f32x4 acc2[2][4];
#pragma unroll
    for (int mt = 0; mt < 2; ++mt)
#pragma unroll
        for (int nt = 0; nt < 4; ++nt) acc2[mt][nt] = (f32x4){0.f, 0.f, 0.f, 0.f};
#pragma unroll
    for (int kt = 0; kt < 8; ++kt) {
        f16x8 af[2], bf[4];
#pragma unroll
        for (int mt = 0; mt < 2; ++mt)
            af[mt] = *(const f16x8*)&sBuf[(mt * 16 + lr) * KSTR + (kt << 5) + (lq << 3)];
        const size_t bb = ((size_t)(kt * 16 + (w << 2))) * 512 + (l << 3);
#pragma unroll
        for (int nt = 0; nt < 4; ++nt)
            bf[nt] = *(const f16x8*)(B2 + bb + nt * 512);
#pragma unroll
        for (int mt = 0; mt < 2; ++mt)
#pragma unroll
            for (int nt = 0; nt < 4; ++nt)
                acc2[mt][nt] = __builtin_amdgcn_mfma_f32_16x16x32_f16(
                    af[mt], bf[nt], acc2[mt][nt], 0, 0, 0);
    }
    __syncthreads();   // h1 reads done; reuse plane for C staging

    // ---- epilogue 2: bias + relu -> LDS fp16 + BN stats ----
    float* slot = bnslot + (size_t)(blockIdx.x & (BN_SLOTS - 1)) * 512;
#pragma unroll
    for (int nt = 0; nt < 4; ++nt) {
        int col = cb + nt * 16 + lr;
        float bv = bias2[col];
        float s = 0.f, qq = 0.f;
#pragma unroll
        for (int mt = 0; mt < 2; ++mt)
#pragma unroll
            for (int i = 0; i < 4; ++i) {
                int rr = mt * 16 + lq * 4 + i;
                float o = fmaxf(acc2[mt][nt][i] + bv, 0.f);
                sBuf[rr * KSTR + col] = (_Float16)o;
                if (row0 + rr < N_NODES) { s += o; qq += o * o; }
            }
        s += __shfl_xor(s, 16); s += __shfl_xor(s, 32);
        qq += __shfl_xor(qq, 16); qq += __shfl_xor(qq, 32);
        if (lq == 0) {
            atomicAdd(&slot[col], s);
            atomicAdd(&slot[256 + col], qq);
        }
    }
    __syncthreads();

    // ---- coalesced C write: f16x8 per thread, 512B contiguous per row ----
#pragma unroll
    for (int k = 0; k < 4; ++k) {
        int rr  = (t >> 5) + k * 8;
        int col = (t & 31) * 8;
        int row = row0 + rr;
        if (row < N_NODES) {
            f16x8 v = *(const f16x8*)&sBuf[rr * KSTR + col];
            *(f16x8*)(C + (size_t)row * 256 + col) = v;
        }
    }
}

// reduce BN_SLOTS slots -> scale/shift
__global__ void bn_finalize_kernel(const float* __restrict__ slots,
                                   const float* __restrict__ g, const float* __restrict__ beta,
                                   float* __restrict__ scale, float* __restrict__ shift) {
    int c = threadIdx.x;
    float s = 0.f, q = 0.f;
    for (int k = 0; k < BN_SLOTS; ++k) {
        s += slots[(size_t)k * 512 + c];
        q += slots[(size_t)k * 512 + 256 + c];
    }
    float mu = s * (1.0f / N_NODES);
    float var = q * (1.0f / N_NODES) - mu * mu;
    float rstd = rsqrtf(var + 1e-5f);
    float sc = g[c] * rstd;
    scale[c] = sc;
    shift[c] = beta[c] - mu * sc;
}

// segmented sqrt-pool (fp16 input) with BN applied at load; fp32 output
__global__ __launch_bounds__(256)
void pool_seg_kernel(const _Float16* __restrict__ h, const int* __restrict__ ptr,
                     const float* __restrict__ bnsc, const float* __restrict__ bnsh,
                     float* __restrict__ out, int nseg) {
    int t = threadIdx.x;
    int g = t >> 6;
    int j = t & 63;
    int s = blockIdx.x * 4 + g;
    if (s >= nseg) return;
    int beg = ptr[s], end = ptr[s + 1];
    int col = j << 2;
    float4 sc = *(const float4*)(bnsc + col);
    float4 sh = *(const float4*)(bnsh + col);
    float4 acc = {0.f, 0.f, 0.f, 0.f};
    for (int i = beg; i < end; ++i) {
        float4 v = ld4(h + (size_t)i * 256 + col);
        acc.x += fmaf(v.x, sc.x, sh.x);
        acc.y += fmaf(v.y, sc.y, sh.y);
        acc.z += fmaf(v.z, sc.z, sh.z);
        acc.w += fmaf(v.w, sc.w, sh.w);
    }
    float w = rsqrtf(fmaxf((float)(end - beg), 1.0f));
    float4 o = {acc.x * w, acc.y * w, acc.z * w, acc.w * w};
    *(float4*)(out + (size_t)s * 256 + col) = o;
}

// ---------------------------------------------------------------------------
extern "C" void kernel_launch(void* const* d_in, const int* in_sizes, int n_in,
                              void* d_out, int out_size, void* d_ws, size_t ws_size,
                              hipStream_t stream) {
    const float* x  = (const float*)d_in[0];
    const float* ea = (const float*)d_in[1];
    const int*   ei = (const int*)d_in[2];
    const int*   fb = (const int*)d_in[3];
    const int*   gb = (const int*)d_in[4];
    const float* W1[3]   = {(const float*)d_in[5],  (const float*)d_in[11], (const float*)d_in[17]};
    const float* B1[3]   = {(const float*)d_in[6],  (const float*)d_in[12], (const float*)d_in[18]};
    const float* W2[3]   = {(const float*)d_in[7],  (const float*)d_in[13], (const float*)d_in[19]};
    const float* B2[3]   = {(const float*)d_in[8],  (const float*)d_in[14], (const float*)d_in[20]};
    const float* G[3]    = {(const float*)d_in[9],  (const float*)d_in[15], (const float*)d_in[21]};
    const float* BETA[3] = {(const float*)d_in[10], (const float*)d_in[16], (const float*)d_in[22]};

    const int FIN[3] = {160, 288, 288};
    const int NBLK = (N_NODES + 255) / 256;      // scan blocks

    float* ws = (float*)d_ws;
    size_t off = 0;
    _Float16* bufA = (_Float16*)(ws + off); off += (size_t)N_NODES * 128;  // N x 256 fp16
    _Float16* bufB = (_Float16*)(ws + off); off += (size_t)N_NODES * 128;
    _Float16* ybuf = (_Float16*)(ws + off); off += (size_t)N_NODES * 128;  // pre-activation Y
    float* agg_e = ws + off; off += (size_t)N_NODES * DE;
    float* bnss  = ws + off; off += 3 * 512;                 // per layer: scale|shift
    float* bnslots = ws + off; off += (size_t)3 * BN_SLOTS * 512;
    _Float16* w1f[3]; _Float16* w2f[3];
    {
        _Float16* sw = (_Float16*)(ws + off);
        _Float16* sw0 = sw;
        for (int l = 0; l < 3; ++l) { w1f[l] = sw; sw += 256 * FIN[l]; }
        for (int l = 0; l < 3; ++l) { w2f[l] = sw; sw += 256 * 256; }
        off += (size_t)(sw - sw0 + 1) / 2;
    }
    int* iw      = (int*)(ws + off);
    int* row_ptr = iw;                     iw += N_NODES + 1;
    int* deg     = iw;                     iw += N_NODES;
    int* fill    = iw;                     iw += N_NODES;
    int* csr_src = iw;                     iw += N_EDGES;
    int* csr_eid = iw;                     iw += N_EDGES;
    int* frag_ptr = iw;                    iw += N_FRAG + 1;
    int* graph_ptr = iw;                   iw += N_GRAPH + 1;
    int* bsum    = iw;                     iw += NBLK;

    hipMemsetAsync(deg, 0, 2 * N_NODES * sizeof(int), stream);
    hipMemsetAsync(bnslots, 0, (size_t)3 * BN_SLOTS * 512 * sizeof(float), stream);

    // weight fragment-swizzle to fp16 (once per layer)
    for (int l = 0; l < 3; ++l) {
        bs16_kernel<<<(FIN[l] * 256 + 255) / 256, 256, 0, stream>>>(W1[l], w1f[l], FIN[l]);
        bs16_kernel<<<(256 * 256 + 255) / 256, 256, 0, stream>>>(W2[l], w2f[l], 256);
    }

    // CSR build (hierarchical scan)
    count_deg_kernel<<<(N_EDGES + 255) / 256, 256, 0, stream>>>(ei, deg);
    block_sum_kernel<<<NBLK, 256, 0, stream>>>(deg, bsum);
    top_scan_kernel<<<1, 256, 0, stream>>>(bsum, NBLK);
    final_scan_kernel<<<NBLK, 256, 0, stream>>>(deg, bsum, row_ptr);
    fill_csr_kernel<<<(N_EDGES + 255) / 256, 256, 0, stream>>>(ei, row_ptr, fill, csr_src, csr_eid);

    segptr_kernel<<<(N_FRAG + 1 + 255) / 256, 256, 0, stream>>>(fb, N_FRAG, frag_ptr);
    segptr_kernel<<<(N_GRAPH + 1 + 255) / 256, 256, 0, stream>>>(gb, N_GRAPH, graph_ptr);

    edge_gather_kernel<<<(N_NODES + 31) / 32, 256, 0, stream>>>(ea, row_ptr, csr_eid, agg_e);

    const int nblk_mlp = (N_NODES + 31) / 32;    // 1563 blocks, 32 rows each
    // layer 0: Y0 = fp16(relu(x)), self = x (fp32)
    relu16_f32_kernel<<<(N_NODES * 128 / 4 + 255) / 256, 256, 0, stream>>>(x, ybuf);
    {
        float* slotsL = bnslots;
        fused_mlp_kernel<false, float, 4><<<nblk_mlp, 256, 0, stream>>>(
            x, ybuf, row_ptr, csr_src, agg_e, nullptr, nullptr,
            w1f[0], B1[0], w2f[0], B2[0], bufA, slotsL);
        bn_finalize_kernel<<<1, 256, 0, stream>>>(slotsL, G[0], BETA[0], bnss, bnss + 256);
    }
    // layer 1: Y = fp16(relu(BN0(bufA))), self = BN0(bufA)
    {
        float* slotsL = bnslots + (size_t)1 * BN_SLOTS * 512;
        const float* psc = bnss, * psh = bnss + 256;
        bnrelu16_kernel<<<(N_NODES * 256 / 8 + 255) / 256, 256, 0, stream>>>(bufA, psc, psh, ybuf);
        fused_mlp_kernel<true, _Float16, 8><<<nblk_mlp, 256, 0, stream>>>(
            bufA, ybuf, row_ptr, csr_src, agg_e, psc, psh,
            w1f[1], B1[1], w2f[1], B2[1], bufB, slotsL);
        bn_finalize_kernel<<<1, 256, 0, stream>>>(slotsL, G[1], BETA[1], bnss + 512, bnss + 768);
    }
    // layer 2: Y = fp16(relu(BN1(bufB))), self = BN1(bufB)
    {
        float* slotsL = bnslots + (size_t)2 * BN_SLOTS * 512;
        const float* psc = bnss + 512, * psh = bnss + 768;
        bnrelu16_kernel<<<(N_NODES * 256 / 8 + 255) / 256, 256, 0, stream>>>(bufB, psc, psh, ybuf);
        fused_mlp_kernel<true, _Float16, 8><<<nblk_mlp, 256, 0, stream>>>(
            bufB, ybuf, row_ptr, csr_src, agg_e, psc, psh,
            w1f[2], B1[2], w2f[2], B2[2], bufA, slotsL);
        bn_finalize_kernel<<<1, 256, 0, stream>>>(slotsL, G[2], BETA[2], bnss + 1024, bnss + 1280);
    }

    const float* fsc = bnss + 2 * 512;   // layer-2 BN scale/shift
    const float* fsh = fsc + 256;
    pool_seg_kernel<<<(N_FRAG + 3) / 4, 256, 0, stream>>>(bufA, frag_ptr, fsc, fsh,
                                                          (float*)d_out, N_FRAG);
    pool_seg_kernel<<<(N_GRAPH + 3) / 4, 256, 0, stream>>>(bufA, graph_ptr, fsc, fsh,
                                                           (float*)d_out + (size_t)N_FRAG * 256, N_GRAPH);
}

// Round 9
// 357.001 us; speedup vs baseline: 1.2055x; 1.0537x over previous
//
#include <hip/hip_runtime.h>

#define N_NODES 50000
#define N_EDGES 200000
#define DE 32
#define N_FRAG 10000
#define N_GRAPH 2000
#define BN_SLOTS 32
#define KSTR 296   // LDS stride (fp16 elems) for the 64-row A/h1 plane

typedef _Float16 f16x8 __attribute__((ext_vector_type(8)));
typedef _Float16 f16x4 __attribute__((ext_vector_type(4)));
typedef __attribute__((ext_vector_type(4))) float f32x4;

__device__ __forceinline__ float4 ld4(const float* p) { return *(const float4*)p; }
__device__ __forceinline__ float4 ld4(const _Float16* p) {
    f16x4 h = *(const f16x4*)p;
    float4 v; v.x = (float)h[0]; v.y = (float)h[1]; v.z = (float)h[2]; v.w = (float)h[3];
    return v;
}
__device__ __forceinline__ void st4h(_Float16* p, float4 v) {
    f16x4 h = {(_Float16)v.x, (_Float16)v.y, (_Float16)v.z, (_Float16)v.w};
    *(f16x4*)p = h;
}

// ---------------------------------------------------------------------------
// CSR build: in-degree count, hierarchical scan, fill
__global__ __launch_bounds__(256)
void count_deg_kernel(const int* __restrict__ ei, int* __restrict__ deg) {
    int e = blockIdx.x * 256 + threadIdx.x;
    if (e < N_EDGES) atomicAdd(&deg[ei[N_EDGES + e]], 1);
}

__global__ __launch_bounds__(256)
void block_sum_kernel(const int* __restrict__ deg, int* __restrict__ bsum) {
    int i = blockIdx.x * 256 + threadIdx.x;
    int v = (i < N_NODES) ? deg[i] : 0;
#pragma unroll
    for (int o = 1; o < 64; o <<= 1) v += __shfl_xor(v, o);
    __shared__ int wsum[4];
    if ((threadIdx.x & 63) == 0) wsum[threadIdx.x >> 6] = v;
    __syncthreads();
    if (threadIdx.x == 0) bsum[blockIdx.x] = wsum[0] + wsum[1] + wsum[2] + wsum[3];
}

__global__ __launch_bounds__(256)
void top_scan_kernel(int* __restrict__ bsum, int nb) {
    __shared__ int s[256];
    int t = threadIdx.x;
    s[t] = (t < nb) ? bsum[t] : 0;
    __syncthreads();
    for (int o = 1; o < 256; o <<= 1) {
        int v = s[t];
        int a = (t >= o) ? s[t - o] : 0;
        __syncthreads();
        s[t] = v + a;
        __syncthreads();
    }
    if (t < nb) bsum[t] = (t > 0) ? s[t - 1] : 0;
}

__global__ __launch_bounds__(256)
void final_scan_kernel(const int* __restrict__ deg, const int* __restrict__ bsum,
                       int* __restrict__ ptr) {
    __shared__ int s[256];
    int i = blockIdx.x * 256 + threadIdx.x;
    int t = threadIdx.x;
    int v = (i < N_NODES) ? deg[i] : 0;
    s[t] = v;
    __syncthreads();
    for (int o = 1; o < 256; o <<= 1) {
        int x = s[t];
        int a = (t >= o) ? s[t - o] : 0;
        __syncthreads();
        s[t] = x + a;
        __syncthreads();
    }
    int incl = s[t];
    int base = bsum[blockIdx.x];
    if (i < N_NODES) ptr[i] = base + incl - v;
    if (i == N_NODES - 1) ptr[N_NODES] = base + incl;
}

__global__ __launch_bounds__(256)
void fill_csr_kernel(const int* __restrict__ ei, const int* __restrict__ row_ptr,
                     int* __restrict__ fill, int* __restrict__ csr_src,
                     int* __restrict__ csr_eid) {
    int e = blockIdx.x * 256 + threadIdx.x;
    if (e >= N_EDGES) return;
    int dst = ei[N_EDGES + e];
    int pos = row_ptr[dst] + atomicAdd(&fill[dst], 1);
    csr_src[pos] = ei[e];
    csr_eid[pos] = e;
}

// merged frag+graph segment-pointer build (one dispatch instead of two)
__global__ __launch_bounds__(256)
void segptr2_kernel(const int* __restrict__ fb, const int* __restrict__ gb,
                    int* __restrict__ frag_ptr, int* __restrict__ graph_ptr) {
    int id = blockIdx.x * 256 + threadIdx.x;
    const int* batch;
    int* ptr;
    int s;
    if (id <= N_FRAG) { batch = fb; ptr = frag_ptr; s = id; }
    else if (id <= N_FRAG + 1 + N_GRAPH) { batch = gb; ptr = graph_ptr; s = id - (N_FRAG + 1); }
    else return;
    int lo = 0, hi = N_NODES;
    while (lo < hi) {
        int mid = (lo + hi) >> 1;
        if (batch[mid] < s) lo = mid + 1; else hi = mid;
    }
    ptr[s] = lo;
}

// ---------------------------------------------------------------------------
// All 6 weight tensors fragment-swizzled fp16 in ONE dispatch.
// BS[kt][cg][lane][j] = fp16(W[kt*32 + (lane>>4)*8 + j][cg*16 + (lane&15)])
struct BsAll {
    const float* W[6];
    _Float16* BS[6];
    int base[7];   // cumulative element counts (K*256)
};

__global__ __launch_bounds__(256)
void bs16_all_kernel(BsAll a) {
    int id = blockIdx.x * 256 + threadIdx.x;
    if (id >= a.base[6]) return;
    int seg = 0;
#pragma unroll
    for (int i = 1; i < 6; ++i) seg += (id >= a.base[i]);
    int lid = id - a.base[seg];
    int j  = lid & 7;
    int l  = (lid >> 3) & 63;
    int cg = (lid >> 9) & 15;
    int kt = lid >> 13;
    int col = cg * 16 + (l & 15);
    int k   = kt * 32 + (l >> 4) * 8 + j;
    a.BS[seg][lid] = (_Float16)a.W[seg][(size_t)k * 256 + col];
}

// ---------------------------------------------------------------------------
// agg_e[n] = sum over incoming edges of relu(edge_attr[e])  [N,32]
__global__ __launch_bounds__(256)
void edge_gather_kernel(const float* __restrict__ ea, const int* __restrict__ row_ptr,
                        const int* __restrict__ csr_eid, float* __restrict__ agg_e) {
    int t = threadIdx.x;
    int g = t >> 3;
    int j = t & 7;
    int n = blockIdx.x * 32 + g;
    if (n >= N_NODES) return;
    int col = j << 2;
    float4 acc = {0.f, 0.f, 0.f, 0.f};
    int beg = row_ptr[n], end = row_ptr[n + 1];
    for (int e = beg; e < end; ++e) {
        int eid = csr_eid[e];
        float4 v = *(const float4*)(ea + (size_t)eid * DE + col);
        acc.x += fmaxf(v.x, 0.f);
        acc.y += fmaxf(v.y, 0.f);
        acc.z += fmaxf(v.z, 0.f);
        acc.w += fmaxf(v.w, 0.f);
    }
    *(float4*)(agg_e + (size_t)n * DE + col) = acc;
}

// ---------------------------------------------------------------------------
// Pre-activation buffers for the gather: Y0 = fp16(relu(x)) (layer 0),
// Y = fp16(relu(sc*h+sh)) (layers 1,2). Gather loop then is pure fp16 adds.
__global__ __launch_bounds__(256)
void relu16_f32_kernel(const float* __restrict__ x, _Float16* __restrict__ y) {
    size_t i = (size_t)(blockIdx.x * 256 + threadIdx.x) * 4;   // N*128 total
    if (i >= (size_t)N_NODES * 128) return;
    float4 v = ld4(x + i);
    f16x4 o = {(_Float16)fmaxf(v.x, 0.f), (_Float16)fmaxf(v.y, 0.f),
               (_Float16)fmaxf(v.z, 0.f), (_Float16)fmaxf(v.w, 0.f)};
    *(f16x4*)(y + i) = o;
}

__global__ __launch_bounds__(256)
void bnrelu16_kernel(const _Float16* __restrict__ h, const float* __restrict__ sc,
                     const float* __restrict__ sh, _Float16* __restrict__ y) {
    size_t i = (size_t)(blockIdx.x * 256 + threadIdx.x) * 8;   // N*256 total
    if (i >= (size_t)N_NODES * 256) return;
    int col = (int)(i & 255);
    f16x8 v = *(const f16x8*)(h + i);
    float4 s0 = ld4(sc + col), s1 = ld4(sc + col + 4);
    float4 t0 = ld4(sh + col), t1 = ld4(sh + col + 4);
    f16x8 o;
    o[0] = (_Float16)fmaxf(fmaf((float)v[0], s0.x, t0.x), 0.f);
    o[1] = (_Float16)fmaxf(fmaf((float)v[1], s0.y, t0.y), 0.f);
    o[2] = (_Float16)fmaxf(fmaf((float)v[2], s0.z, t0.z), 0.f);
    o[3] = (_Float16)fmaxf(fmaf((float)v[3], s0.w, t0.w), 0.f);
    o[4] = (_Float16)fmaxf(fmaf((float)v[4], s1.x, t1.x), 0.f);
    o[5] = (_Float16)fmaxf(fmaf((float)v[5], s1.y, t1.y), 0.f);
    o[6] = (_Float16)fmaxf(fmaf((float)v[6], s1.z, t1.z), 0.f);
    o[7] = (_Float16)fmaxf(fmaf((float)v[7], s1.w, t1.w), 0.f);
    *(f16x8*)(y + i) = o;
}

// ---------------------------------------------------------------------------
// Fused gather + MLP, 64-row M-tile:
//   R8 evidence: MLP phases dominate (R0 MLP-only = 44.6us of the 50.5).
//   Per K-step a wave did 4 B-loads -> 8 MFMAs; at 64 rows it's 4 B-loads
//   -> 16 MFMAs, and total B L2 traffic halves (435->218MB). R1's 64-row
//   failure predates the coalesced stage (R7), LDS-bounce C write (R8),
//   and the VGPR-128 cap; residency ceiling (4 blocks/CU @ 37.9KB LDS)
//   matches today's measured ~3 blocks/CU, so nothing is lost there.
//   stage: two 32-row halves, 8 threads/row, coalesced 128B chunks,
//          packed-fp16 neighbor sum, BN'd self term, agg_e tail.
//   MLP:   4 waves x 64-col slab; acc[4][4]; barrier-free K-loops.
//   epilogue: LDS bounce -> row-contiguous f16x8 C stores + BN stats.
template <bool BNIN, typename T, int NC>   // DIN = NC*32, K1 = DIN+32
__global__ __launch_bounds__(256, 4)
void fused_mlp_kernel(const T* __restrict__ X, const _Float16* __restrict__ Yg,
                      const int* __restrict__ row_ptr, const int* __restrict__ csr_src,
                      const float* __restrict__ agg_e,
                      const float* __restrict__ bnsc, const float* __restrict__ bnsh,
                      const _Float16* __restrict__ B1, const float* __restrict__ bias1,
                      const _Float16* __restrict__ B2, const float* __restrict__ bias2,
                      _Float16* __restrict__ C, float* __restrict__ bnslot) {
    constexpr int DIN  = NC * 32;
    constexpr int K1   = DIN + 32;
    constexpr int NKT1 = K1 / 32;
    constexpr int CPT  = DIN / 8;        // cols per stage-thread
    constexpr int NV   = CPT / 8;        // f16x8 chunks per stage-thread
    __shared__ __align__(16) _Float16 sBuf[64 * KSTR];   // A tile, h1, then C
    const int t = threadIdx.x;
    const int l = t & 63;
    const int w = t >> 6;
    const int lr = l & 15;
    const int lq = l >> 4;
    const int row0 = blockIdx.x << 6;   // 64 rows/block
    const int cb = w << 6;

    // ---- stage: gather-aggregate into LDS (8 threads/row, 2 halves) ----
    {
        const int r = t >> 3, j = t & 7;
        const int jc = j << 3;           // lane's 8-col offset within a chunk
#pragma unroll
        for (int half = 0; half < 2; ++half) {
            const int rr = half * 32 + r;
            const int gr = row0 + rr;
            if (gr < N_NODES) {
                f16x8 acc16[NV];
#pragma unroll
                for (int c = 0; c < NV; ++c) acc16[c] = (f16x8){0, 0, 0, 0, 0, 0, 0, 0};
                const int beg = row_ptr[gr], end = row_ptr[gr + 1];
                for (int e = beg; e < end; ++e) {
                    const _Float16* sp = Yg + (size_t)csr_src[e] * DIN + jc;
#pragma unroll
                    for (int c = 0; c < NV; ++c) acc16[c] += *(const f16x8*)(sp + c * 64);
                }
                // self term (BN if BNIN, no relu) + fp16 neighbor sum
                const T* xp = X + (size_t)gr * DIN + jc;
#pragma unroll
                for (int c = 0; c < NV; ++c) {
                    float4 v0f = ld4(xp + c * 64);
                    float4 v1f = ld4(xp + c * 64 + 4);
                    if (BNIN) {
                        float4 sa = *(const float4*)(bnsc + c * 64 + jc);
                        float4 sb = *(const float4*)(bnsc + c * 64 + jc + 4);
                        float4 ta = *(const float4*)(bnsh + c * 64 + jc);
                        float4 tb = *(const float4*)(bnsh + c * 64 + jc + 4);
                        v0f.x = fmaf(v0f.x, sa.x, ta.x);
                        v0f.y = fmaf(v0f.y, sa.y, ta.y);
                        v0f.z = fmaf(v0f.z, sa.z, ta.z);
                        v0f.w = fmaf(v0f.w, sa.w, ta.w);
                        v1f.x = fmaf(v1f.x, sb.x, tb.x);
                        v1f.y = fmaf(v1f.y, sb.y, tb.y);
                        v1f.z = fmaf(v1f.z, sb.z, tb.z);
                        v1f.w = fmaf(v1f.w, sb.w, tb.w);
                    }
                    f16x8 o;
                    o[0] = (_Float16)(v0f.x + (float)acc16[c][0]);
                    o[1] = (_Float16)(v0f.y + (float)acc16[c][1]);
                    o[2] = (_Float16)(v0f.z + (float)acc16[c][2]);
                    o[3] = (_Float16)(v0f.w + (float)acc16[c][3]);
                    o[4] = (_Float16)(v1f.x + (float)acc16[c][4]);
                    o[5] = (_Float16)(v1f.y + (float)acc16[c][5]);
                    o[6] = (_Float16)(v1f.z + (float)acc16[c][6]);
                    o[7] = (_Float16)(v1f.w + (float)acc16[c][7]);
                    *(f16x8*)&sBuf[rr * KSTR + c * 64 + jc] = o;
                }
                float4 ev = *(const float4*)(agg_e + (size_t)gr * DE + (j << 2));
                st4h(&sBuf[rr * KSTR + DIN + (j << 2)], ev);
            } else {
                f16x8 z8 = {0, 0, 0, 0, 0, 0, 0, 0};
#pragma unroll
                for (int c = 0; c < NV; ++c)
                    *(f16x8*)&sBuf[rr * KSTR + c * 64 + jc] = z8;
                f16x4 z4 = {0, 0, 0, 0};
                *(f16x4*)&sBuf[rr * KSTR + DIN + (j << 2)] = z4;
            }
        }
    }
    __syncthreads();

    // ---- phase 1: A @ W1 (barrier-free) ----
    f32x4 acc1[4][4];
#pragma unroll
    for (int mt = 0; mt < 4; ++mt)
#pragma unroll
        for (int nt = 0; nt < 4; ++nt) acc1[mt][nt] = (f32x4){0.f, 0.f, 0.f, 0.f};
#pragma unroll
    for (int kt = 0; kt < NKT1; ++kt) {
        f16x8 af[4], bf[4];
#pragma unroll
        for (int mt = 0; mt < 4; ++mt)
            af[mt] = *(const f16x8*)&sBuf[(mt * 16 + lr) * KSTR + (kt << 5) + (lq << 3)];
        const size_t bb = ((size_t)(kt * 16 + (w << 2))) * 512 + (l << 3);
#pragma unroll
        for (int nt = 0; nt < 4; ++nt)
            bf[nt] = *(const f16x8*)(B1 + bb + nt * 512);
#pragma unroll
        for (int mt = 0; mt < 4; ++mt)
#pragma unroll
            for (int nt = 0; nt < 4; ++nt)
                acc1[mt][nt] = __builtin_amdgcn_mfma_f32_16x16x32_f16(
                    af[mt], bf[nt], acc1[mt][nt], 0, 0, 0);
    }
    __syncthreads();   // A tile dead; reuse plane for h1

    // ---- epilogue 1: relu(h1) -> LDS fp16 ----
#pragma unroll
    for (int nt = 0; nt < 4; ++nt) {
        int col = cb + nt * 16 + lr;
        float bv = bias1[col];
#pragma unroll
        for (int mt = 0; mt < 4; ++mt)
#pragma unroll
            for (int i = 0; i < 4; ++i) {
                int rr = mt * 16 + lq * 4 + i;
                sBuf[rr * KSTR + col] = (_Float16)fmaxf(acc1[mt][nt][i] + bv, 0.f);
            }
    }
    __syncthreads();

    // ---- phase 2: h1 @ W2 (barrier-free) ----
    f32x4 acc2[4][4];
#pragma unroll
    for (int mt = 0; mt < 4; ++mt)
#pragma unroll
        for (int nt = 0; nt < 4; ++nt) acc2[mt][nt] = (f32x4){0.f, 0.f, 0.f, 0.f};
#pragma unroll
    for (int kt = 0; kt < 8; ++kt) {
        f16x8 af[4], bf[4];
#pragma unroll
        for (int mt = 0; mt < 4; ++mt)
            af[mt] = *(const f16x8*)&sBuf[(mt * 16 + lr) * KSTR + (kt << 5) + (lq << 3)];
        const size_t bb = ((size_t)(kt * 16 + (w << 2))) * 512 + (l << 3);
#pragma unroll
        for (int nt = 0; nt < 4; ++nt)
            bf[nt] = *(const f16x8*)(B2 + bb + nt * 512);
#pragma unroll
        for (int mt = 0; mt < 4; ++mt)
#pragma unroll
            for (int nt = 0; nt < 4; ++nt)
                acc2[mt][nt] = __builtin_amdgcn_mfma_f32_16x16x32_f16(
                    af[mt], bf[nt], acc2[mt][nt], 0, 0, 0);
    }
    __syncthreads();   // h1 reads done; reuse plane for C staging

    // ---- epilogue 2: bias + relu -> LDS fp16 + BN stats ----
    float* slot = bnslot + (size_t)(blockIdx.x & (BN_SLOTS - 1)) * 512;
#pragma unroll
    for (int nt = 0; nt < 4; ++nt) {
        int col = cb + nt * 16 + lr;
        float bv = bias2[col];
        float s = 0.f, qq = 0.f;
#pragma unroll
        for (int mt = 0; mt < 4; ++mt)
#pragma unroll
            for (int i = 0; i < 4; ++i) {
                int rr = mt * 16 + lq * 4 + i;
                float o = fmaxf(acc2[mt][nt][i] + bv, 0.f);
                sBuf[rr * KSTR + col] = (_Float16)o;
                if (row0 + rr < N_NODES) { s += o; qq += o * o; }
            }
        s += __shfl_xor(s, 16); s += __shfl_xor(s, 32);
        qq += __shfl_xor(qq, 16); qq += __shfl_xor(qq, 32);
        if (lq == 0) {
            atomicAdd(&slot[col], s);
            atomicAdd(&slot[256 + col], qq);
        }
    }
    __syncthreads();

    // ---- coalesced C write: f16x8 per thread, 512B contiguous per row ----
#pragma unroll
    for (int k = 0; k < 8; ++k) {
        int rr  = (t >> 5) + k * 8;
        int col = (t & 31) * 8;
        int row = row0 + rr;
        if (row < N_NODES) {
            f16x8 v = *(const f16x8*)&sBuf[rr * KSTR + col];
            *(f16x8*)(C + (size_t)row * 256 + col) = v;
        }
    }
}

// reduce BN_SLOTS slots -> scale/shift
__global__ void bn_finalize_kernel(const float* __restrict__ slots,
                                   const float* __restrict__ g, const float* __restrict__ beta,
                                   float* __restrict__ scale, float* __restrict__ shift) {
    int c = threadIdx.x;
    float s = 0.f, q = 0.f;
    for (int k = 0; k < BN_SLOTS; ++k) {
        s += slots[(size_t)k * 512 + c];
        q += slots[(size_t)k * 512 + 256 + c];
    }
    float mu = s * (1.0f / N_NODES);
    float var = q * (1.0f / N_NODES) - mu * mu;
    float rstd = rsqrtf(var + 1e-5f);
    float sc = g[c] * rstd;
    scale[c] = sc;
    shift[c] = beta[c] - mu * sc;
}

// segmented sqrt-pool (fp16 input) with BN applied at load; fp32 output
__global__ __launch_bounds__(256)
void pool_seg_kernel(const _Float16* __restrict__ h, const int* __restrict__ ptr,
                     const float* __restrict__ bnsc, const float* __restrict__ bnsh,
                     float* __restrict__ out, int nseg) {
    int t = threadIdx.x;
    int g = t >> 6;
    int j = t & 63;
    int s = blockIdx.x * 4 + g;
    if (s >= nseg) return;
    int beg = ptr[s], end = ptr[s + 1];
    int col = j << 2;
    float4 sc = *(const float4*)(bnsc + col);
    float4 sh = *(const float4*)(bnsh + col);
    float4 acc = {0.f, 0.f, 0.f, 0.f};
    for (int i = beg; i < end; ++i) {
        float4 v = ld4(h + (size_t)i * 256 + col);
        acc.x += fmaf(v.x, sc.x, sh.x);
        acc.y += fmaf(v.y, sc.y, sh.y);
        acc.z += fmaf(v.z, sc.z, sh.z);
        acc.w += fmaf(v.w, sc.w, sh.w);
    }
    float w = rsqrtf(fmaxf((float)(end - beg), 1.0f));
    float4 o = {acc.x * w, acc.y * w, acc.z * w, acc.w * w};
    *(float4*)(out + (size_t)s * 256 + col) = o;
}

// ---------------------------------------------------------------------------
extern "C" void kernel_launch(void* const* d_in, const int* in_sizes, int n_in,
                              void* d_out, int out_size, void* d_ws, size_t ws_size,
                              hipStream_t stream) {
    const float* x  = (const float*)d_in[0];
    const float* ea = (const float*)d_in[1];
    const int*   ei = (const int*)d_in[2];
    const int*   fb = (const int*)d_in[3];
    const int*   gb = (const int*)d_in[4];
    const float* W1[3]   = {(const float*)d_in[5],  (const float*)d_in[11], (const float*)d_in[17]};
    const float* B1[3]   = {(const float*)d_in[6],  (const float*)d_in[12], (const float*)d_in[18]};
    const float* W2[3]   = {(const float*)d_in[7],  (const float*)d_in[13], (const float*)d_in[19]};
    const float* B2[3]   = {(const float*)d_in[8],  (const float*)d_in[14], (const float*)d_in[20]};
    const float* G[3]    = {(const float*)d_in[9],  (const float*)d_in[15], (const float*)d_in[21]};
    const float* BETA[3] = {(const float*)d_in[10], (const float*)d_in[16], (const float*)d_in[22]};

    const int FIN[3] = {160, 288, 288};
    const int NBLK = (N_NODES + 255) / 256;      // scan blocks

    float* ws = (float*)d_ws;
    size_t off = 0;
    _Float16* bufA = (_Float16*)(ws + off); off += (size_t)N_NODES * 128;  // N x 256 fp16
    _Float16* bufB = (_Float16*)(ws + off); off += (size_t)N_NODES * 128;
    _Float16* ybuf = (_Float16*)(ws + off); off += (size_t)N_NODES * 128;  // pre-activation Y
    float* agg_e = ws + off; off += (size_t)N_NODES * DE;
    float* bnss  = ws + off; off += 3 * 512;                 // per layer: scale|shift
    float* bnslots = ws + off; off += (size_t)3 * BN_SLOTS * 512;
    _Float16* w1f[3]; _Float16* w2f[3];
    {
        _Float16* sw = (_Float16*)(ws + off);
        _Float16* sw0 = sw;
        for (int l = 0; l < 3; ++l) { w1f[l] = sw; sw += 256 * FIN[l]; }
        for (int l = 0; l < 3; ++l) { w2f[l] = sw; sw += 256 * 256; }
        off += (size_t)(sw - sw0 + 1) / 2;
    }
    int* iw      = (int*)(ws + off);
    int* row_ptr = iw;                     iw += N_NODES + 1;
    int* deg     = iw;                     iw += N_NODES;
    int* fill    = iw;                     iw += N_NODES;
    int* csr_src = iw;                     iw += N_EDGES;
    int* csr_eid = iw;                     iw += N_EDGES;
    int* frag_ptr = iw;                    iw += N_FRAG + 1;
    int* graph_ptr = iw;                   iw += N_GRAPH + 1;
    int* bsum    = iw;                     iw += NBLK;

    hipMemsetAsync(deg, 0, 2 * N_NODES * sizeof(int), stream);
    hipMemsetAsync(bnslots, 0, (size_t)3 * BN_SLOTS * 512 * sizeof(float), stream);

    // weight fragment-swizzle to fp16: all 6 tensors in one dispatch
    {
        BsAll a;
        a.W[0] = W1[0]; a.W[1] = W1[1]; a.W[2] = W1[2];
        a.W[3] = W2[0]; a.W[4] = W2[1]; a.W[5] = W2[2];
        a.BS[0] = w1f[0]; a.BS[1] = w1f[1]; a.BS[2] = w1f[2];
        a.BS[3] = w2f[0]; a.BS[4] = w2f[1]; a.BS[5] = w2f[2];
        int Ks[6] = {FIN[0], FIN[1], FIN[2], 256, 256, 256};
        int cum = 0;
        for (int i = 0; i < 6; ++i) { a.base[i] = cum; cum += Ks[i] * 256; }
        a.base[6] = cum;
        bs16_all_kernel<<<(cum + 255) / 256, 256, 0, stream>>>(a);
    }

    // CSR build (hierarchical scan)
    count_deg_kernel<<<(N_EDGES + 255) / 256, 256, 0, stream>>>(ei, deg);
    block_sum_kernel<<<NBLK, 256, 0, stream>>>(deg, bsum);
    top_scan_kernel<<<1, 256, 0, stream>>>(bsum, NBLK);
    final_scan_kernel<<<NBLK, 256, 0, stream>>>(deg, bsum, row_ptr);
    fill_csr_kernel<<<(N_EDGES + 255) / 256, 256, 0, stream>>>(ei, row_ptr, fill, csr_src, csr_eid);

    segptr2_kernel<<<(N_FRAG + N_GRAPH + 2 + 255) / 256, 256, 0, stream>>>(
        fb, gb, frag_ptr, graph_ptr);

    edge_gather_kernel<<<(N_NODES + 31) / 32, 256, 0, stream>>>(ea, row_ptr, csr_eid, agg_e);

    const int nblk_mlp = (N_NODES + 63) / 64;    // 782 blocks, 64 rows each
    // layer 0: Y0 = fp16(relu(x)), self = x (fp32)
    relu16_f32_kernel<<<(N_NODES * 128 / 4 + 255) / 256, 256, 0, stream>>>(x, ybuf);
    {
        float* slotsL = bnslots;
        fused_mlp_kernel<false, float, 4><<<nblk_mlp, 256, 0, stream>>>(
            x, ybuf, row_ptr, csr_src, agg_e, nullptr, nullptr,
            w1f[0], B1[0], w2f[0], B2[0], bufA, slotsL);
        bn_finalize_kernel<<<1, 256, 0, stream>>>(slotsL, G[0], BETA[0], bnss, bnss + 256);
    }
    // layer 1: Y = fp16(relu(BN0(bufA))), self = BN0(bufA)
    {
        float* slotsL = bnslots + (size_t)1 * BN_SLOTS * 512;
        const float* psc = bnss, * psh = bnss + 256;
        bnrelu16_kernel<<<(N_NODES * 256 / 8 + 255) / 256, 256, 0, stream>>>(bufA, psc, psh, ybuf);
        fused_mlp_kernel<true, _Float16, 8><<<nblk_mlp, 256, 0, stream>>>(
            bufA, ybuf, row_ptr, csr_src, agg_e, psc, psh,
            w1f[1], B1[1], w2f[1], B2[1], bufB, slotsL);
        bn_finalize_kernel<<<1, 256, 0, stream>>>(slotsL, G[1], BETA[1], bnss + 512, bnss + 768);
    }
    // layer 2: Y = fp16(relu(BN1(bufB))), self = BN1(bufB)
    {
        float* slotsL = bnslots + (size_t)2 * BN_SLOTS * 512;
        const float* psc = bnss + 512, * psh = bnss + 768;
        bnrelu16_kernel<<<(N_NODES * 256 / 8 + 255) / 256, 256, 0, stream>>>(bufB, psc, psh, ybuf);
        fused_mlp_kernel<true, _Float16, 8><<<nblk_mlp, 256, 0, stream>>>(
            bufB, ybuf, row_ptr, csr_src, agg_e, psc, psh,
            w1f[2], B1[2], w2f[2], B2[2], bufA, slotsL);
        bn_finalize_kernel<<<1, 256, 0, stream>>>(slotsL, G[2], BETA[2], bnss + 1024, bnss + 1280);
    }

    const float* fsc = bnss + 2 * 512;   // layer-2 BN scale/shift
    const float* fsh = fsc + 256;
    pool_seg_kernel<<<(N_FRAG + 3) / 4, 256, 0, stream>>>(bufA, frag_ptr, fsc, fsh,
                                                          (float*)d_out, N_FRAG);
    pool_seg_kernel<<<(N_GRAPH + 3) / 4, 256, 0, stream>>>(bufA, graph_ptr, fsc, fsh,
                                                           (float*)d_out + (size_t)N_FRAG * 256, N_GRAPH);
}

// Round 10
// 355.040 us; speedup vs baseline: 1.2121x; 1.0055x over previous
//
#include <hip/hip_runtime.h>

#define N_NODES 50000
#define N_EDGES 200000
#define DE 32
#define N_FRAG 10000
#define N_GRAPH 2000
#define BN_SLOTS 32
#define KSTR 296   // LDS stride (fp16 elems) for the 64-row A/h1 plane

typedef _Float16 f16x8 __attribute__((ext_vector_type(8)));
typedef _Float16 f16x4 __attribute__((ext_vector_type(4)));
typedef __attribute__((ext_vector_type(4))) float f32x4;

__device__ __forceinline__ float4 ld4(const float* p) { return *(const float4*)p; }
__device__ __forceinline__ float4 ld4(const _Float16* p) {
    f16x4 h = *(const f16x4*)p;
    float4 v; v.x = (float)h[0]; v.y = (float)h[1]; v.z = (float)h[2]; v.w = (float)h[3];
    return v;
}
__device__ __forceinline__ void st4h(_Float16* p, float4 v) {
    f16x4 h = {(_Float16)v.x, (_Float16)v.y, (_Float16)v.z, (_Float16)v.w};
    *(f16x4*)p = h;
}

// ---------------------------------------------------------------------------
// CSR build: in-degree count, hierarchical scan, fill
__global__ __launch_bounds__(256)
void count_deg_kernel(const int* __restrict__ ei, int* __restrict__ deg) {
    int e = blockIdx.x * 256 + threadIdx.x;
    if (e < N_EDGES) atomicAdd(&deg[ei[N_EDGES + e]], 1);
}

__global__ __launch_bounds__(256)
void block_sum_kernel(const int* __restrict__ deg, int* __restrict__ bsum) {
    int i = blockIdx.x * 256 + threadIdx.x;
    int v = (i < N_NODES) ? deg[i] : 0;
#pragma unroll
    for (int o = 1; o < 64; o <<= 1) v += __shfl_xor(v, o);
    __shared__ int wsum[4];
    if ((threadIdx.x & 63) == 0) wsum[threadIdx.x >> 6] = v;
    __syncthreads();
    if (threadIdx.x == 0) bsum[blockIdx.x] = wsum[0] + wsum[1] + wsum[2] + wsum[3];
}

__global__ __launch_bounds__(256)
void top_scan_kernel(int* __restrict__ bsum, int nb) {
    __shared__ int s[256];
    int t = threadIdx.x;
    s[t] = (t < nb) ? bsum[t] : 0;
    __syncthreads();
    for (int o = 1; o < 256; o <<= 1) {
        int v = s[t];
        int a = (t >= o) ? s[t - o] : 0;
        __syncthreads();
        s[t] = v + a;
        __syncthreads();
    }
    if (t < nb) bsum[t] = (t > 0) ? s[t - 1] : 0;
}

__global__ __launch_bounds__(256)
void final_scan_kernel(const int* __restrict__ deg, const int* __restrict__ bsum,
                       int* __restrict__ ptr) {
    __shared__ int s[256];
    int i = blockIdx.x * 256 + threadIdx.x;
    int t = threadIdx.x;
    int v = (i < N_NODES) ? deg[i] : 0;
    s[t] = v;
    __syncthreads();
    for (int o = 1; o < 256; o <<= 1) {
        int x = s[t];
        int a = (t >= o) ? s[t - o] : 0;
        __syncthreads();
        s[t] = x + a;
        __syncthreads();
    }
    int incl = s[t];
    int base = bsum[blockIdx.x];
    if (i < N_NODES) ptr[i] = base + incl - v;
    if (i == N_NODES - 1) ptr[N_NODES] = base + incl;
}

__global__ __launch_bounds__(256)
void fill_csr_kernel(const int* __restrict__ ei, const int* __restrict__ row_ptr,
                     int* __restrict__ fill, int* __restrict__ csr_src,
                     int* __restrict__ csr_eid) {
    int e = blockIdx.x * 256 + threadIdx.x;
    if (e >= N_EDGES) return;
    int dst = ei[N_EDGES + e];
    int pos = row_ptr[dst] + atomicAdd(&fill[dst], 1);
    csr_src[pos] = ei[e];
    csr_eid[pos] = e;
}

// merged frag+graph segment-pointer build (one dispatch instead of two)
__global__ __launch_bounds__(256)
void segptr2_kernel(const int* __restrict__ fb, const int* __restrict__ gb,
                    int* __restrict__ frag_ptr, int* __restrict__ graph_ptr) {
    int id = blockIdx.x * 256 + threadIdx.x;
    const int* batch;
    int* ptr;
    int s;
    if (id <= N_FRAG) { batch = fb; ptr = frag_ptr; s = id; }
    else if (id <= N_FRAG + 1 + N_GRAPH) { batch = gb; ptr = graph_ptr; s = id - (N_FRAG + 1); }
    else return;
    int lo = 0, hi = N_NODES;
    while (lo < hi) {
        int mid = (lo + hi) >> 1;
        if (batch[mid] < s) lo = mid + 1; else hi = mid;
    }
    ptr[s] = lo;
}

// ---------------------------------------------------------------------------
// All 6 weight tensors fragment-swizzled fp16 in ONE dispatch.
// BS[kt][cg][lane][j] = fp16(W[kt*32 + (lane>>4)*8 + j][cg*16 + (lane&15)])
struct BsAll {
    const float* W[6];
    _Float16* BS[6];
    int base[7];   // cumulative element counts (K*256)
};

__global__ __launch_bounds__(256)
void bs16_all_kernel(BsAll a) {
    int id = blockIdx.x * 256 + threadIdx.x;
    if (id >= a.base[6]) return;
    int seg = 0;
#pragma unroll
    for (int i = 1; i < 6; ++i) seg += (id >= a.base[i]);
    int lid = id - a.base[seg];
    int j  = lid & 7;
    int l  = (lid >> 3) & 63;
    int cg = (lid >> 9) & 15;
    int kt = lid >> 13;
    int col = cg * 16 + (l & 15);
    int k   = kt * 32 + (l >> 4) * 8 + j;
    a.BS[seg][lid] = (_Float16)a.W[seg][(size_t)k * 256 + col];
}

// ---------------------------------------------------------------------------
// agg_e[n] = sum over incoming edges of relu(edge_attr[e])  [N,32]
__global__ __launch_bounds__(256)
void edge_gather_kernel(const float* __restrict__ ea, const int* __restrict__ row_ptr,
                        const int* __restrict__ csr_eid, float* __restrict__ agg_e) {
    int t = threadIdx.x;
    int g = t >> 3;
    int j = t & 7;
    int n = blockIdx.x * 32 + g;
    if (n >= N_NODES) return;
    int col = j << 2;
    float4 acc = {0.f, 0.f, 0.f, 0.f};
    int beg = row_ptr[n], end = row_ptr[n + 1];
    for (int e = beg; e < end; ++e) {
        int eid = csr_eid[e];
        float4 v = *(const float4*)(ea + (size_t)eid * DE + col);
        acc.x += fmaxf(v.x, 0.f);
        acc.y += fmaxf(v.y, 0.f);
        acc.z += fmaxf(v.z, 0.f);
        acc.w += fmaxf(v.w, 0.f);
    }
    *(float4*)(agg_e + (size_t)n * DE + col) = acc;
}

// ---------------------------------------------------------------------------
// Pre-activation buffers for the gather: Y0 = fp16(relu(x)) (layer 0),
// Y = fp16(relu(sc*h+sh)) (layers 1,2). Gather loop then is pure fp16 adds.
__global__ __launch_bounds__(256)
void relu16_f32_kernel(const float* __restrict__ x, _Float16* __restrict__ y) {
    size_t i = (size_t)(blockIdx.x * 256 + threadIdx.x) * 4;   // N*128 total
    if (i >= (size_t)N_NODES * 128) return;
    float4 v = ld4(x + i);
    f16x4 o = {(_Float16)fmaxf(v.x, 0.f), (_Float16)fmaxf(v.y, 0.f),
               (_Float16)fmaxf(v.z, 0.f), (_Float16)fmaxf(v.w, 0.f)};
    *(f16x4*)(y + i) = o;
}

__global__ __launch_bounds__(256)
void bnrelu16_kernel(const _Float16* __restrict__ h, const float* __restrict__ sc,
                     const float* __restrict__ sh, _Float16* __restrict__ y) {
    size_t i = (size_t)(blockIdx.x * 256 + threadIdx.x) * 8;   // N*256 total
    if (i >= (size_t)N_NODES * 256) return;
    int col = (int)(i & 255);
    f16x8 v = *(const f16x8*)(h + i);
    float4 s0 = ld4(sc + col), s1 = ld4(sc + col + 4);
    float4 t0 = ld4(sh + col), t1 = ld4(sh + col + 4);
    f16x8 o;
    o[0] = (_Float16)fmaxf(fmaf((float)v[0], s0.x, t0.x), 0.f);
    o[1] = (_Float16)fmaxf(fmaf((float)v[1], s0.y, t0.y), 0.f);
    o[2] = (_Float16)fmaxf(fmaf((float)v[2], s0.z, t0.z), 0.f);
    o[3] = (_Float16)fmaxf(fmaf((float)v[3], s0.w, t0.w), 0.f);
    o[4] = (_Float16)fmaxf(fmaf((float)v[4], s1.x, t1.x), 0.f);
    o[5] = (_Float16)fmaxf(fmaf((float)v[5], s1.y, t1.y), 0.f);
    o[6] = (_Float16)fmaxf(fmaf((float)v[6], s1.z, t1.z), 0.f);
    o[7] = (_Float16)fmaxf(fmaf((float)v[7], s1.w, t1.w), 0.f);
    *(f16x8*)(y + i) = o;
}

// ---------------------------------------------------------------------------
// Fused gather + MLP, 64-row M-tile, 512 threads / 8 waves:
//   R9 evidence: VGPR 64 + AGPR 64 (acc[4][4]) = exactly the 128 cap — the
//   accumulator consumed the whole register budget, leaving zero headroom to
//   pipeline B/Y loads; occupancy was grid-limited at ~12 waves/CU.
//   8 waves x 32-col slab: acc[4][2] (32 AGPR/wave), same tile, same B
//   traffic/MFMA ratio, but waves/CU 12 -> 16 (VGPR cap 128 @ (512,4)) and
//   ~96 free VGPRs for the compiler to hoist loads across K-steps.
//   stage: 8 threads/row over all 64 rows, coalesced 128B chunks,
//          packed-fp16 neighbor sum, BN'd self term, agg_e tail.
//   epilogue: LDS bounce -> row-contiguous f16x8 C stores + BN stats.
template <bool BNIN, typename T, int NC>   // DIN = NC*32, K1 = DIN+32
__global__ __launch_bounds__(512, 4)
void fused_mlp_kernel(const T* __restrict__ X, const _Float16* __restrict__ Yg,
                      const int* __restrict__ row_ptr, const int* __restrict__ csr_src,
                      const float* __restrict__ agg_e,
                      const float* __restrict__ bnsc, const float* __restrict__ bnsh,
                      const _Float16* __restrict__ B1, const float* __restrict__ bias1,
                      const _Float16* __restrict__ B2, const float* __restrict__ bias2,
                      _Float16* __restrict__ C, float* __restrict__ bnslot) {
    constexpr int DIN  = NC * 32;
    constexpr int K1   = DIN + 32;
    constexpr int NKT1 = K1 / 32;
    constexpr int CPT  = DIN / 8;        // cols per stage-thread
    constexpr int NV   = CPT / 8;        // f16x8 chunks per stage-thread
    __shared__ __align__(16) _Float16 sBuf[64 * KSTR];   // A tile, h1, then C
    const int t = threadIdx.x;
    const int l = t & 63;
    const int w = t >> 6;                // 8 waves
    const int lr = l & 15;
    const int lq = l >> 4;
    const int row0 = blockIdx.x << 6;    // 64 rows/block
    const int cb = w << 5;               // 32-col slab per wave

    // ---- stage: gather-aggregate into LDS (8 threads/row, 64 rows) ----
    {
        const int r = t >> 3, j = t & 7;
        const int jc = j << 3;           // lane's 8-col offset within a chunk
        const int gr = row0 + r;
        if (gr < N_NODES) {
            f16x8 acc16[NV];
#pragma unroll
            for (int c = 0; c < NV; ++c) acc16[c] = (f16x8){0, 0, 0, 0, 0, 0, 0, 0};
            const int beg = row_ptr[gr], end = row_ptr[gr + 1];
            for (int e = beg; e < end; ++e) {
                const _Float16* sp = Yg + (size_t)csr_src[e] * DIN + jc;
#pragma unroll
                for (int c = 0; c < NV; ++c) acc16[c] += *(const f16x8*)(sp + c * 64);
            }
            // self term (BN if BNIN, no relu) + fp16 neighbor sum
            const T* xp = X + (size_t)gr * DIN + jc;
#pragma unroll
            for (int c = 0; c < NV; ++c) {
                float4 v0f = ld4(xp + c * 64);
                float4 v1f = ld4(xp + c * 64 + 4);
                if (BNIN) {
                    float4 sa = *(const float4*)(bnsc + c * 64 + jc);
                    float4 sb = *(const float4*)(bnsc + c * 64 + jc + 4);
                    float4 ta = *(const float4*)(bnsh + c * 64 + jc);
                    float4 tb = *(const float4*)(bnsh + c * 64 + jc + 4);
                    v0f.x = fmaf(v0f.x, sa.x, ta.x);
                    v0f.y = fmaf(v0f.y, sa.y, ta.y);
                    v0f.z = fmaf(v0f.z, sa.z, ta.z);
                    v0f.w = fmaf(v0f.w, sa.w, ta.w);
                    v1f.x = fmaf(v1f.x, sb.x, tb.x);
                    v1f.y = fmaf(v1f.y, sb.y, tb.y);
                    v1f.z = fmaf(v1f.z, sb.z, tb.z);
                    v1f.w = fmaf(v1f.w, sb.w, tb.w);
                }
                f16x8 o;
                o[0] = (_Float16)(v0f.x + (float)acc16[c][0]);
                o[1] = (_Float16)(v0f.y + (float)acc16[c][1]);
                o[2] = (_Float16)(v0f.z + (float)acc16[c][2]);
                o[3] = (_Float16)(v0f.w + (float)acc16[c][3]);
                o[4] = (_Float16)(v1f.x + (float)acc16[c][4]);
                o[5] = (_Float16)(v1f.y + (float)acc16[c][5]);
                o[6] = (_Float16)(v1f.z + (float)acc16[c][6]);
                o[7] = (_Float16)(v1f.w + (float)acc16[c][7]);
                *(f16x8*)&sBuf[r * KSTR + c * 64 + jc] = o;
            }
            float4 ev = *(const float4*)(agg_e + (size_t)gr * DE + (j << 2));
            st4h(&sBuf[r * KSTR + DIN + (j << 2)], ev);
        } else {
            f16x8 z8 = {0, 0, 0, 0, 0, 0, 0, 0};
#pragma unroll
            for (int c = 0; c < NV; ++c)
                *(f16x8*)&sBuf[r * KSTR + c * 64 + jc] = z8;
            f16x4 z4 = {0, 0, 0, 0};
            *(f16x4*)&sBuf[r * KSTR + DIN + (j << 2)] = z4;
        }
    }
    __syncthreads();

    // ---- phase 1: A @ W1 (barrier-free) ----
    f32x4 acc1[4][2];
#pragma unroll
    for (int mt = 0; mt < 4; ++mt)
#pragma unroll
        for (int nt = 0; nt < 2; ++nt) acc1[mt][nt] = (f32x4){0.f, 0.f, 0.f, 0.f};
#pragma unroll
    for (int kt = 0; kt < NKT1; ++kt) {
        f16x8 af[4], bf[2];
#pragma unroll
        for (int mt = 0; mt < 4; ++mt)
            af[mt] = *(const f16x8*)&sBuf[(mt * 16 + lr) * KSTR + (kt << 5) + (lq << 3)];
        const size_t bb = ((size_t)(kt * 16 + (w << 1))) * 512 + (l << 3);
#pragma unroll
        for (int nt = 0; nt < 2; ++nt)
            bf[nt] = *(const f16x8*)(B1 + bb + nt * 512);
#pragma unroll
        for (int mt = 0; mt < 4; ++mt)
#pragma unroll
            for (int nt = 0; nt < 2; ++nt)
                acc1[mt][nt] = __builtin_amdgcn_mfma_f32_16x16x32_f16(
                    af[mt], bf[nt], acc1[mt][nt], 0, 0, 0);
    }
    __syncthreads();   // A tile dead; reuse plane for h1

    // ---- epilogue 1: relu(h1) -> LDS fp16 ----
#pragma unroll
    for (int nt = 0; nt < 2; ++nt) {
        int col = cb + nt * 16 + lr;
        float bv = bias1[col];
#pragma unroll
        for (int mt = 0; mt < 4; ++mt)
#pragma unroll
            for (int i = 0; i < 4; ++i) {
                int rr = mt * 16 + lq * 4 + i;
                sBuf[rr * KSTR + col] = (_Float16)fmaxf(acc1[mt][nt][i] + bv, 0.f);
            }
    }
    __syncthreads();

    // ---- phase 2: h1 @ W2 (barrier-free) ----
    f32x4 acc2[4][2];
#pragma unroll
    for (int mt = 0; mt < 4; ++mt)
#pragma unroll
        for (int nt = 0; nt < 2; ++nt) acc2[mt][nt] = (f32x4){0.f, 0.f, 0.f, 0.f};
#pragma unroll
    for (int kt = 0; kt < 8; ++kt) {
        f16x8 af[4], bf[2];
#pragma unroll
        for (int mt = 0; mt < 4; ++mt)
            af[mt] = *(const f16x8*)&sBuf[(mt * 16 + lr) * KSTR + (kt << 5) + (lq << 3)];
        const size_t bb = ((size_t)(kt * 16 + (w << 1))) * 512 + (l << 3);
#pragma unroll
        for (int nt = 0; nt < 2; ++nt)
            bf[nt] = *(const f16x8*)(B2 + bb + nt * 512);
#pragma unroll
        for (int mt = 0; mt < 4; ++mt)
#pragma unroll
            for (int nt = 0; nt < 2; ++nt)
                acc2[mt][nt] = __builtin_amdgcn_mfma_f32_16x16x32_f16(
                    af[mt], bf[nt], acc2[mt][nt], 0, 0, 0);
    }
    __syncthreads();   // h1 reads done; reuse plane for C staging

    // ---- epilogue 2: bias + relu -> LDS fp16 + BN stats ----
    float* slot = bnslot + (size_t)(blockIdx.x & (BN_SLOTS - 1)) * 512;
#pragma unroll
    for (int nt = 0; nt < 2; ++nt) {
        int col = cb + nt * 16 + lr;
        float bv = bias2[col];
        float s = 0.f, qq = 0.f;
#pragma unroll
        for (int mt = 0; mt < 4; ++mt)
#pragma unroll
            for (int i = 0; i < 4; ++i) {
                int rr = mt * 16 + lq * 4 + i;
                float o = fmaxf(acc2[mt][nt][i] + bv, 0.f);
                sBuf[rr * KSTR + col] = (_Float16)o;
                if (row0 + rr < N_NODES) { s += o; qq += o * o; }
            }
        s += __shfl_xor(s, 16); s += __shfl_xor(s, 32);
        qq += __shfl_xor(qq, 16); qq += __shfl_xor(qq, 32);
        if (lq == 0) {
            atomicAdd(&slot[col], s);
            atomicAdd(&slot[256 + col], qq);
        }
    }
    __syncthreads();

    // ---- coalesced C write: f16x8 per thread, 512B contiguous per row ----
#pragma unroll
    for (int k = 0; k < 4; ++k) {
        int rr  = (t >> 5) + k * 16;
        int col = (t & 31) * 8;
        int row = row0 + rr;
        if (row < N_NODES) {
            f16x8 v = *(const f16x8*)&sBuf[rr * KSTR + col];
            *(f16x8*)(C + (size_t)row * 256 + col) = v;
        }
    }
}

// reduce BN_SLOTS slots -> scale/shift
__global__ void bn_finalize_kernel(const float* __restrict__ slots,
                                   const float* __restrict__ g, const float* __restrict__ beta,
                                   float* __restrict__ scale, float* __restrict__ shift) {
    int c = threadIdx.x;
    float s = 0.f, q = 0.f;
    for (int k = 0; k < BN_SLOTS; ++k) {
        s += slots[(size_t)k * 512 + c];
        q += slots[(size_t)k * 512 + 256 + c];
    }
    float mu = s * (1.0f / N_NODES);
    float var = q * (1.0f / N_NODES) - mu * mu;
    float rstd = rsqrtf(var + 1e-5f);
    float sc = g[c] * rstd;
    scale[c] = sc;
    shift[c] = beta[c] - mu * sc;
}

// segmented sqrt-pool (fp16 input) with BN applied at load; fp32 output
__global__ __launch_bounds__(256)
void pool_seg_kernel(const _Float16* __restrict__ h, const int* __restrict__ ptr,
                     const float* __restrict__ bnsc, const float* __restrict__ bnsh,
                     float* __restrict__ out, int nseg) {
    int t = threadIdx.x;
    int g = t >> 6;
    int j = t & 63;
    int s = blockIdx.x * 4 + g;
    if (s >= nseg) return;
    int beg = ptr[s], end = ptr[s + 1];
    int col = j << 2;
    float4 sc = *(const float4*)(bnsc + col);
    float4 sh = *(const float4*)(bnsh + col);
    float4 acc = {0.f, 0.f, 0.f, 0.f};
    for (int i = beg; i < end; ++i) {
        float4 v = ld4(h + (size_t)i * 256 + col);
        acc.x += fmaf(v.x, sc.x, sh.x);
        acc.y += fmaf(v.y, sc.y, sh.y);
        acc.z += fmaf(v.z, sc.z, sh.z);
        acc.w += fmaf(v.w, sc.w, sh.w);
    }
    float w = rsqrtf(fmaxf((float)(end - beg), 1.0f));
    float4 o = {acc.x * w, acc.y * w, acc.z * w, acc.w * w};
    *(float4*)(out + (size_t)s * 256 + col) = o;
}

// ---------------------------------------------------------------------------
extern "C" void kernel_launch(void* const* d_in, const int* in_sizes, int n_in,
                              void* d_out, int out_size, void* d_ws, size_t ws_size,
                              hipStream_t stream) {
    const float* x  = (const float*)d_in[0];
    const float* ea = (const float*)d_in[1];
    const int*   ei = (const int*)d_in[2];
    const int*   fb = (const int*)d_in[3];
    const int*   gb = (const int*)d_in[4];
    const float* W1[3]   = {(const float*)d_in[5],  (const float*)d_in[11], (const float*)d_in[17]};
    const float* B1[3]   = {(const float*)d_in[6],  (const float*)d_in[12], (const float*)d_in[18]};
    const float* W2[3]   = {(const float*)d_in[7],  (const float*)d_in[13], (const float*)d_in[19]};
    const float* B2[3]   = {(const float*)d_in[8],  (const float*)d_in[14], (const float*)d_in[20]};
    const float* G[3]    = {(const float*)d_in[9],  (const float*)d_in[15], (const float*)d_in[21]};
    const float* BETA[3] = {(const float*)d_in[10], (const float*)d_in[16], (const float*)d_in[22]};

    const int FIN[3] = {160, 288, 288};
    const int NBLK = (N_NODES + 255) / 256;      // scan blocks

    float* ws = (float*)d_ws;
    size_t off = 0;
    _Float16* bufA = (_Float16*)(ws + off); off += (size_t)N_NODES * 128;  // N x 256 fp16
    _Float16* bufB = (_Float16*)(ws + off); off += (size_t)N_NODES * 128;
    _Float16* ybuf = (_Float16*)(ws + off); off += (size_t)N_NODES * 128;  // pre-activation Y
    float* agg_e = ws + off; off += (size_t)N_NODES * DE;
    float* bnss  = ws + off; off += 3 * 512;                 // per layer: scale|shift
    float* bnslots = ws + off; off += (size_t)3 * BN_SLOTS * 512;
    _Float16* w1f[3]; _Float16* w2f[3];
    {
        _Float16* sw = (_Float16*)(ws + off);
        _Float16* sw0 = sw;
        for (int l = 0; l < 3; ++l) { w1f[l] = sw; sw += 256 * FIN[l]; }
        for (int l = 0; l < 3; ++l) { w2f[l] = sw; sw += 256 * 256; }
        off += (size_t)(sw - sw0 + 1) / 2;
    }
    int* iw      = (int*)(ws + off);
    int* row_ptr = iw;                     iw += N_NODES + 1;
    int* deg     = iw;                     iw += N_NODES;
    int* fill    = iw;                     iw += N_NODES;
    int* csr_src = iw;                     iw += N_EDGES;
    int* csr_eid = iw;                     iw += N_EDGES;
    int* frag_ptr = iw;                    iw += N_FRAG + 1;
    int* graph_ptr = iw;                   iw += N_GRAPH + 1;
    int* bsum    = iw;                     iw += NBLK;

    hipMemsetAsync(deg, 0, 2 * N_NODES * sizeof(int), stream);
    hipMemsetAsync(bnslots, 0, (size_t)3 * BN_SLOTS * 512 * sizeof(float), stream);

    // weight fragment-swizzle to fp16: all 6 tensors in one dispatch
    {
        BsAll a;
        a.W[0] = W1[0]; a.W[1] = W1[1]; a.W[2] = W1[2];
        a.W[3] = W2[0]; a.W[4] = W2[1]; a.W[5] = W2[2];
        a.BS[0] = w1f[0]; a.BS[1] = w1f[1]; a.BS[2] = w1f[2];
        a.BS[3] = w2f[0]; a.BS[4] = w2f[1]; a.BS[5] = w2f[2];
        int Ks[6] = {FIN[0], FIN[1], FIN[2], 256, 256, 256};
        int cum = 0;
        for (int i = 0; i < 6; ++i) { a.base[i] = cum; cum += Ks[i] * 256; }
        a.base[6] = cum;
        bs16_all_kernel<<<(cum + 255) / 256, 256, 0, stream>>>(a);
    }

    // CSR build (hierarchical scan)
    count_deg_kernel<<<(N_EDGES + 255) / 256, 256, 0, stream>>>(ei, deg);
    block_sum_kernel<<<NBLK, 256, 0, stream>>>(deg, bsum);
    top_scan_kernel<<<1, 256, 0, stream>>>(bsum, NBLK);
    final_scan_kernel<<<NBLK, 256, 0, stream>>>(deg, bsum, row_ptr);
    fill_csr_kernel<<<(N_EDGES + 255) / 256, 256, 0, stream>>>(ei, row_ptr, fill, csr_src, csr_eid);

    segptr2_kernel<<<(N_FRAG + N_GRAPH + 2 + 255) / 256, 256, 0, stream>>>(
        fb, gb, frag_ptr, graph_ptr);

    edge_gather_kernel<<<(N_NODES + 31) / 32, 256, 0, stream>>>(ea, row_ptr, csr_eid, agg_e);

    const int nblk_mlp = (N_NODES + 63) / 64;    // 782 blocks, 64 rows each
    // layer 0: Y0 = fp16(relu(x)), self = x (fp32)
    relu16_f32_kernel<<<(N_NODES * 128 / 4 + 255) / 256, 256, 0, stream>>>(x, ybuf);
    {
        float* slotsL = bnslots;
        fused_mlp_kernel<false, float, 4><<<nblk_mlp, 512, 0, stream>>>(
            x, ybuf, row_ptr, csr_src, agg_e, nullptr, nullptr,
            w1f[0], B1[0], w2f[0], B2[0], bufA, slotsL);
        bn_finalize_kernel<<<1, 256, 0, stream>>>(slotsL, G[0], BETA[0], bnss, bnss + 256);
    }
    // layer 1: Y = fp16(relu(BN0(bufA))), self = BN0(bufA)
    {
        float* slotsL = bnslots + (size_t)1 * BN_SLOTS * 512;
        const float* psc = bnss, * psh = bnss + 256;
        bnrelu16_kernel<<<(N_NODES * 256 / 8 + 255) / 256, 256, 0, stream>>>(bufA, psc, psh, ybuf);
        fused_mlp_kernel<true, _Float16, 8><<<nblk_mlp, 512, 0, stream>>>(
            bufA, ybuf, row_ptr, csr_src, agg_e, psc, psh,
            w1f[1], B1[1], w2f[1], B2[1], bufB, slotsL);
        bn_finalize_kernel<<<1, 256, 0, stream>>>(slotsL, G[1], BETA[1], bnss + 512, bnss + 768);
    }
    // layer 2: Y = fp16(relu(BN1(bufB))), self = BN1(bufB)
    {
        float* slotsL = bnslots + (size_t)2 * BN_SLOTS * 512;
        const float* psc = bnss + 512, * psh = bnss + 768;
        bnrelu16_kernel<<<(N_NODES * 256 / 8 + 255) / 256, 256, 0, stream>>>(bufB, psc, psh, ybuf);
        fused_mlp_kernel<true, _Float16, 8><<<nblk_mlp, 512, 0, stream>>>(
            bufB, ybuf, row_ptr, csr_src, agg_e, psc, psh,
            w1f[2], B1[2], w2f[2], B2[2], bufA, slotsL);
        bn_finalize_kernel<<<1, 256, 0, stream>>>(slotsL, G[2], BETA[2], bnss + 1024, bnss + 1280);
    }

    const float* fsc = bnss + 2 * 512;   // layer-2 BN scale/shift
    const float* fsh = fsc + 256;
    pool_seg_kernel<<<(N_FRAG + 3) / 4, 256, 0, stream>>>(bufA, frag_ptr, fsc, fsh,
                                                          (float*)d_out, N_FRAG);
    pool_seg_kernel<<<(N_GRAPH + 3) / 4, 256, 0, stream>>>(bufA, graph_ptr, fsc, fsh,
                                                           (float*)d_out + (size_t)N_FRAG * 256, N_GRAPH);
}

// Round 11
// 349.084 us; speedup vs baseline: 1.2328x; 1.0171x over previous
//
#include <hip/hip_runtime.h>

#define N_NODES 50000
#define N_EDGES 200000
#define DE 32
#define N_FRAG 10000
#define N_GRAPH 2000
#define BN_SLOTS 32
#define KSTR 296   // LDS stride (fp16 elems) for the 64-row A/h1 plane

typedef _Float16 f16x8 __attribute__((ext_vector_type(8)));
typedef _Float16 f16x4 __attribute__((ext_vector_type(4)));
typedef __attribute__((ext_vector_type(4))) float f32x4;

__device__ __forceinline__ float4 ld4(const float* p) { return *(const float4*)p; }
__device__ __forceinline__ float4 ld4(const _Float16* p) {
    f16x4 h = *(const f16x4*)p;
    float4 v; v.x = (float)h[0]; v.y = (float)h[1]; v.z = (float)h[2]; v.w = (float)h[3];
    return v;
}
__device__ __forceinline__ void st4h(_Float16* p, float4 v) {
    f16x4 h = {(_Float16)v.x, (_Float16)v.y, (_Float16)v.z, (_Float16)v.w};
    *(f16x4*)p = h;
}

// ---------------------------------------------------------------------------
// CSR build: in-degree count, hierarchical scan, fill
__global__ __launch_bounds__(256)
void count_deg_kernel(const int* __restrict__ ei, int* __restrict__ deg) {
    int e = blockIdx.x * 256 + threadIdx.x;
    if (e < N_EDGES) atomicAdd(&deg[ei[N_EDGES + e]], 1);
}

__global__ __launch_bounds__(256)
void block_sum_kernel(const int* __restrict__ deg, int* __restrict__ bsum) {
    int i = blockIdx.x * 256 + threadIdx.x;
    int v = (i < N_NODES) ? deg[i] : 0;
#pragma unroll
    for (int o = 1; o < 64; o <<= 1) v += __shfl_xor(v, o);
    __shared__ int wsum[4];
    if ((threadIdx.x & 63) == 0) wsum[threadIdx.x >> 6] = v;
    __syncthreads();
    if (threadIdx.x == 0) bsum[blockIdx.x] = wsum[0] + wsum[1] + wsum[2] + wsum[3];
}

__global__ __launch_bounds__(256)
void top_scan_kernel(int* __restrict__ bsum, int nb) {
    __shared__ int s[256];
    int t = threadIdx.x;
    s[t] = (t < nb) ? bsum[t] : 0;
    __syncthreads();
    for (int o = 1; o < 256; o <<= 1) {
        int v = s[t];
        int a = (t >= o) ? s[t - o] : 0;
        __syncthreads();
        s[t] = v + a;
        __syncthreads();
    }
    if (t < nb) bsum[t] = (t > 0) ? s[t - 1] : 0;
}

__global__ __launch_bounds__(256)
void final_scan_kernel(const int* __restrict__ deg, const int* __restrict__ bsum,
                       int* __restrict__ ptr) {
    __shared__ int s[256];
    int i = blockIdx.x * 256 + threadIdx.x;
    int t = threadIdx.x;
    int v = (i < N_NODES) ? deg[i] : 0;
    s[t] = v;
    __syncthreads();
    for (int o = 1; o < 256; o <<= 1) {
        int x = s[t];
        int a = (t >= o) ? s[t - o] : 0;
        __syncthreads();
        s[t] = x + a;
        __syncthreads();
    }
    int incl = s[t];
    int base = bsum[blockIdx.x];
    if (i < N_NODES) ptr[i] = base + incl - v;
    if (i == N_NODES - 1) ptr[N_NODES] = base + incl;
}

__global__ __launch_bounds__(256)
void fill_csr_kernel(const int* __restrict__ ei, const int* __restrict__ row_ptr,
                     int* __restrict__ fill, int* __restrict__ csr_src,
                     int* __restrict__ csr_eid) {
    int e = blockIdx.x * 256 + threadIdx.x;
    if (e >= N_EDGES) return;
    int dst = ei[N_EDGES + e];
    int pos = row_ptr[dst] + atomicAdd(&fill[dst], 1);
    csr_src[pos] = ei[e];
    csr_eid[pos] = e;
}

// merged frag+graph segment-pointer build (one dispatch instead of two)
__global__ __launch_bounds__(256)
void segptr2_kernel(const int* __restrict__ fb, const int* __restrict__ gb,
                    int* __restrict__ frag_ptr, int* __restrict__ graph_ptr) {
    int id = blockIdx.x * 256 + threadIdx.x;
    const int* batch;
    int* ptr;
    int s;
    if (id <= N_FRAG) { batch = fb; ptr = frag_ptr; s = id; }
    else if (id <= N_FRAG + 1 + N_GRAPH) { batch = gb; ptr = graph_ptr; s = id - (N_FRAG + 1); }
    else return;
    int lo = 0, hi = N_NODES;
    while (lo < hi) {
        int mid = (lo + hi) >> 1;
        if (batch[mid] < s) lo = mid + 1; else hi = mid;
    }
    ptr[s] = lo;
}

// ---------------------------------------------------------------------------
// All 6 weight tensors fragment-swizzled fp16 in ONE dispatch.
// BS[kt][cg][lane][j] = fp16(W[kt*32 + (lane>>4)*8 + j][cg*16 + (lane&15)])
struct BsAll {
    const float* W[6];
    _Float16* BS[6];
    int base[7];   // cumulative element counts (K*256)
};

__global__ __launch_bounds__(256)
void bs16_all_kernel(BsAll a) {
    int id = blockIdx.x * 256 + threadIdx.x;
    if (id >= a.base[6]) return;
    int seg = 0;
#pragma unroll
    for (int i = 1; i < 6; ++i) seg += (id >= a.base[i]);
    int lid = id - a.base[seg];
    int j  = lid & 7;
    int l  = (lid >> 3) & 63;
    int cg = (lid >> 9) & 15;
    int kt = lid >> 13;
    int col = cg * 16 + (l & 15);
    int k   = kt * 32 + (l >> 4) * 8 + j;
    a.BS[seg][lid] = (_Float16)a.W[seg][(size_t)k * 256 + col];
}

// ---------------------------------------------------------------------------
// agg_e[n] = sum over incoming edges of relu(edge_attr[e])  [N,32]
// unroll-2 ping-pong: next edge's 16B load in flight under current's adds.
__global__ __launch_bounds__(256)
void edge_gather_kernel(const float* __restrict__ ea, const int* __restrict__ row_ptr,
                        const int* __restrict__ csr_eid, float* __restrict__ agg_e) {
    int t = threadIdx.x;
    int g = t >> 3;
    int j = t & 7;
    int n = blockIdx.x * 32 + g;
    if (n >= N_NODES) return;
    int col = j << 2;
    float4 acc = {0.f, 0.f, 0.f, 0.f};
    int beg = row_ptr[n], end = row_ptr[n + 1];
    int e = beg;
    float4 va, vb;
    if (e < end) va = *(const float4*)(ea + (size_t)csr_eid[e] * DE + col);
    while (e + 2 <= end) {
        vb = *(const float4*)(ea + (size_t)csr_eid[e + 1] * DE + col);
        acc.x += fmaxf(va.x, 0.f); acc.y += fmaxf(va.y, 0.f);
        acc.z += fmaxf(va.z, 0.f); acc.w += fmaxf(va.w, 0.f);
        if (e + 2 < end) va = *(const float4*)(ea + (size_t)csr_eid[e + 2] * DE + col);
        acc.x += fmaxf(vb.x, 0.f); acc.y += fmaxf(vb.y, 0.f);
        acc.z += fmaxf(vb.z, 0.f); acc.w += fmaxf(vb.w, 0.f);
        e += 2;
    }
    if (e < end) {
        acc.x += fmaxf(va.x, 0.f); acc.y += fmaxf(va.y, 0.f);
        acc.z += fmaxf(va.z, 0.f); acc.w += fmaxf(va.w, 0.f);
    }
    *(float4*)(agg_e + (size_t)n * DE + col) = acc;
}

// ---------------------------------------------------------------------------
// Y0 = fp16(relu(x)) for the layer-0 gather.
__global__ __launch_bounds__(256)
void relu16_f32_kernel(const float* __restrict__ x, _Float16* __restrict__ y) {
    size_t i = (size_t)(blockIdx.x * 256 + threadIdx.x) * 4;   // N*128 total
    if (i >= (size_t)N_NODES * 128) return;
    float4 v = ld4(x + i);
    f16x4 o = {(_Float16)fmaxf(v.x, 0.f), (_Float16)fmaxf(v.y, 0.f),
               (_Float16)fmaxf(v.z, 0.f), (_Float16)fmaxf(v.w, 0.f)};
    *(f16x4*)(y + i) = o;
}

// ---------------------------------------------------------------------------
// Fused BN-finalize + Y = fp16(relu(sc*h+sh)) in one dispatch:
// each block recomputes scale/shift from the L2-hot 64KB slot array in a
// prologue (deterministic fp32 -> identical across blocks); block 0 also
// publishes the global copy for the next fused_mlp's self term. Removes the
// single-block bn_finalize dispatch + its serialization stall.
__global__ __launch_bounds__(256)
void bnfin_relu16_kernel(const float* __restrict__ slots,
                         const float* __restrict__ g, const float* __restrict__ beta,
                         const _Float16* __restrict__ h, _Float16* __restrict__ y,
                         float* __restrict__ scale_out, float* __restrict__ shift_out) {
    __shared__ float ssc[256], ssh[256];
    const int t = threadIdx.x;
    {
        float s = 0.f, q = 0.f;
        for (int k = 0; k < BN_SLOTS; ++k) {
            s += slots[(size_t)k * 512 + t];
            q += slots[(size_t)k * 512 + 256 + t];
        }
        float mu = s * (1.0f / N_NODES);
        float var = q * (1.0f / N_NODES) - mu * mu;
        float rstd = rsqrtf(var + 1e-5f);
        float sc = g[t] * rstd;
        float sh = beta[t] - mu * sc;
        ssc[t] = sc; ssh[t] = sh;
        if (blockIdx.x == 0) { scale_out[t] = sc; shift_out[t] = sh; }
    }
    __syncthreads();
    const size_t total = (size_t)N_NODES * 256 / 8;
    for (size_t idx = (size_t)blockIdx.x * 256 + t; idx < total;
         idx += (size_t)gridDim.x * 256) {
        size_t i = idx * 8;
        int col = (int)(i & 255);          // constant per thread (stride % 256 == 0)
        f16x8 v = *(const f16x8*)(h + i);
        f16x8 o;
#pragma unroll
        for (int k2 = 0; k2 < 8; ++k2)
            o[k2] = (_Float16)fmaxf(fmaf((float)v[k2], ssc[col + k2], ssh[col + k2]), 0.f);
        *(f16x8*)(y + i) = o;
    }
}

// ---------------------------------------------------------------------------
// Fused gather + MLP, 64-row M-tile, 512 threads / 8 waves (R10 structure).
// Stage gather: unroll-2 ping-pong (va/vb, no register copies, identical
// summation order) — R6's depth-2 retried with the coalesced layout and
// VGPR headroom (R10: 60 used / 128 cap) that R6 lacked.
template <bool BNIN, typename T, int NC>   // DIN = NC*32, K1 = DIN+32
__global__ __launch_bounds__(512, 4)
void fused_mlp_kernel(const T* __restrict__ X, const _Float16* __restrict__ Yg,
                      const int* __restrict__ row_ptr, const int* __restrict__ csr_src,
                      const float* __restrict__ agg_e,
                      const float* __restrict__ bnsc, const float* __restrict__ bnsh,
                      const _Float16* __restrict__ B1, const float* __restrict__ bias1,
                      const _Float16* __restrict__ B2, const float* __restrict__ bias2,
                      _Float16* __restrict__ C, float* __restrict__ bnslot) {
    constexpr int DIN  = NC * 32;
    constexpr int K1   = DIN + 32;
    constexpr int NKT1 = K1 / 32;
    constexpr int CPT  = DIN / 8;        // cols per stage-thread
    constexpr int NV   = CPT / 8;        // f16x8 chunks per stage-thread
    __shared__ __align__(16) _Float16 sBuf[64 * KSTR];   // A tile, h1, then C
    const int t = threadIdx.x;
    const int l = t & 63;
    const int w = t >> 6;                // 8 waves
    const int lr = l & 15;
    const int lq = l >> 4;
    const int row0 = blockIdx.x << 6;    // 64 rows/block
    const int cb = w << 5;               // 32-col slab per wave

    // ---- stage: gather-aggregate into LDS (8 threads/row, 64 rows) ----
    {
        const int r = t >> 3, j = t & 7;
        const int jc = j << 3;           // lane's 8-col offset within a chunk
        const int gr = row0 + r;
        if (gr < N_NODES) {
            f16x8 acc16[NV];
#pragma unroll
            for (int c = 0; c < NV; ++c) acc16[c] = (f16x8){0, 0, 0, 0, 0, 0, 0, 0};
            const int beg = row_ptr[gr], end = row_ptr[gr + 1];
            // unroll-2 ping-pong fp16 neighbor loop (coalesced 128B chunks)
            int e = beg;
            f16x8 va[NV], vb[NV];
            if (e < end) {
                const _Float16* sp = Yg + (size_t)csr_src[e] * DIN + jc;
#pragma unroll
                for (int c = 0; c < NV; ++c) va[c] = *(const f16x8*)(sp + c * 64);
            }
            while (e + 2 <= end) {
                {
                    const _Float16* sp = Yg + (size_t)csr_src[e + 1] * DIN + jc;
#pragma unroll
                    for (int c = 0; c < NV; ++c) vb[c] = *(const f16x8*)(sp + c * 64);
                }
#pragma unroll
                for (int c = 0; c < NV; ++c) acc16[c] += va[c];
                if (e + 2 < end) {
                    const _Float16* sp = Yg + (size_t)csr_src[e + 2] * DIN + jc;
#pragma unroll
                    for (int c = 0; c < NV; ++c) va[c] = *(const f16x8*)(sp + c * 64);
                }
#pragma unroll
                for (int c = 0; c < NV; ++c) acc16[c] += vb[c];
                e += 2;
            }
            if (e < end) {
#pragma unroll
                for (int c = 0; c < NV; ++c) acc16[c] += va[c];
            }
            // self term (BN if BNIN, no relu) + fp16 neighbor sum
            const T* xp = X + (size_t)gr * DIN + jc;
#pragma unroll
            for (int c = 0; c < NV; ++c) {
                float4 v0f = ld4(xp + c * 64);
                float4 v1f = ld4(xp + c * 64 + 4);
                if (BNIN) {
                    float4 sa = *(const float4*)(bnsc + c * 64 + jc);
                    float4 sb = *(const float4*)(bnsc + c * 64 + jc + 4);
                    float4 ta = *(const float4*)(bnsh + c * 64 + jc);
                    float4 tb = *(const float4*)(bnsh + c * 64 + jc + 4);
                    v0f.x = fmaf(v0f.x, sa.x, ta.x);
                    v0f.y = fmaf(v0f.y, sa.y, ta.y);
                    v0f.z = fmaf(v0f.z, sa.z, ta.z);
                    v0f.w = fmaf(v0f.w, sa.w, ta.w);
                    v1f.x = fmaf(v1f.x, sb.x, tb.x);
                    v1f.y = fmaf(v1f.y, sb.y, tb.y);
                    v1f.z = fmaf(v1f.z, sb.z, tb.z);
                    v1f.w = fmaf(v1f.w, sb.w, tb.w);
                }
                f16x8 o;
                o[0] = (_Float16)(v0f.x + (float)acc16[c][0]);
                o[1] = (_Float16)(v0f.y + (float)acc16[c][1]);
                o[2] = (_Float16)(v0f.z + (float)acc16[c][2]);
                o[3] = (_Float16)(v0f.w + (float)acc16[c][3]);
                o[4] = (_Float16)(v1f.x + (float)acc16[c][4]);
                o[5] = (_Float16)(v1f.y + (float)acc16[c][5]);
                o[6] = (_Float16)(v1f.z + (float)acc16[c][6]);
                o[7] = (_Float16)(v1f.w + (float)acc16[c][7]);
                *(f16x8*)&sBuf[r * KSTR + c * 64 + jc] = o;
            }
            float4 ev = *(const float4*)(agg_e + (size_t)gr * DE + (j << 2));
            st4h(&sBuf[r * KSTR + DIN + (j << 2)], ev);
        } else {
            f16x8 z8 = {0, 0, 0, 0, 0, 0, 0, 0};
#pragma unroll
            for (int c = 0; c < NV; ++c)
                *(f16x8*)&sBuf[r * KSTR + c * 64 + jc] = z8;
            f16x4 z4 = {0, 0, 0, 0};
            *(f16x4*)&sBuf[r * KSTR + DIN + (j << 2)] = z4;
        }
    }
    __syncthreads();

    // ---- phase 1: A @ W1 (barrier-free) ----
    f32x4 acc1[4][2];
#pragma unroll
    for (int mt = 0; mt < 4; ++mt)
#pragma unroll
        for (int nt = 0; nt < 2; ++nt) acc1[mt][nt] = (f32x4){0.f, 0.f, 0.f, 0.f};
#pragma unroll
    for (int kt = 0; kt < NKT1; ++kt) {
        f16x8 af[4], bf[2];
#pragma unroll
        for (int mt = 0; mt < 4; ++mt)
            af[mt] = *(const f16x8*)&sBuf[(mt * 16 + lr) * KSTR + (kt << 5) + (lq << 3)];
        const size_t bb = ((size_t)(kt * 16 + (w << 1))) * 512 + (l << 3);
#pragma unroll
        for (int nt = 0; nt < 2; ++nt)
            bf[nt] = *(const f16x8*)(B1 + bb + nt * 512);
#pragma unroll
        for (int mt = 0; mt < 4; ++mt)
#pragma unroll
            for (int nt = 0; nt < 2; ++nt)
                acc1[mt][nt] = __builtin_amdgcn_mfma_f32_16x16x32_f16(
                    af[mt], bf[nt], acc1[mt][nt], 0, 0, 0);
    }
    __syncthreads();   // A tile dead; reuse plane for h1

    // ---- epilogue 1: relu(h1) -> LDS fp16 ----
#pragma unroll
    for (int nt = 0; nt < 2; ++nt) {
        int col = cb + nt * 16 + lr;
        float bv = bias1[col];
#pragma unroll
        for (int mt = 0; mt < 4; ++mt)
#pragma unroll
            for (int i = 0; i < 4; ++i) {
                int rr = mt * 16 + lq * 4 + i;
                sBuf[rr * KSTR + col] = (_Float16)fmaxf(acc1[mt][nt][i] + bv, 0.f);
            }
    }
    __syncthreads();

    // ---- phase 2: h1 @ W2 (barrier-free) ----
    f32x4 acc2[4][2];
#pragma unroll
    for (int mt = 0; mt < 4; ++mt)
#pragma unroll
        for (int nt = 0; nt < 2; ++nt) acc2[mt][nt] = (f32x4){0.f, 0.f, 0.f, 0.f};
#pragma unroll
    for (int kt = 0; kt < 8; ++kt) {
        f16x8 af[4], bf[2];
#pragma unroll
        for (int mt = 0; mt < 4; ++mt)
            af[mt] = *(const f16x8*)&sBuf[(mt * 16 + lr) * KSTR + (kt << 5) + (lq << 3)];
        const size_t bb = ((size_t)(kt * 16 + (w << 1))) * 512 + (l << 3);
#pragma unroll
        for (int nt = 0; nt < 2; ++nt)
            bf[nt] = *(const f16x8*)(B2 + bb + nt * 512);
#pragma unroll
        for (int mt = 0; mt < 4; ++mt)
#pragma unroll
            for (int nt = 0; nt < 2; ++nt)
                acc2[mt][nt] = __builtin_amdgcn_mfma_f32_16x16x32_f16(
                    af[mt], bf[nt], acc2[mt][nt], 0, 0, 0);
    }
    __syncthreads();   // h1 reads done; reuse plane for C staging

    // ---- epilogue 2: bias + relu -> LDS fp16 + BN stats ----
    float* slot = bnslot + (size_t)(blockIdx.x & (BN_SLOTS - 1)) * 512;
#pragma unroll
    for (int nt = 0; nt < 2; ++nt) {
        int col = cb + nt * 16 + lr;
        float bv = bias2[col];
        float s = 0.f, qq = 0.f;
#pragma unroll
        for (int mt = 0; mt < 4; ++mt)
#pragma unroll
            for (int i = 0; i < 4; ++i) {
                int rr = mt * 16 + lq * 4 + i;
                float o = fmaxf(acc2[mt][nt][i] + bv, 0.f);
                sBuf[rr * KSTR + col] = (_Float16)o;
                if (row0 + rr < N_NODES) { s += o; qq += o * o; }
            }
        s += __shfl_xor(s, 16); s += __shfl_xor(s, 32);
        qq += __shfl_xor(qq, 16); qq += __shfl_xor(qq, 32);
        if (lq == 0) {
            atomicAdd(&slot[col], s);
            atomicAdd(&slot[256 + col], qq);
        }
    }
    __syncthreads();

    // ---- coalesced C write: f16x8 per thread, 512B contiguous per row ----
#pragma unroll
    for (int k = 0; k < 4; ++k) {
        int rr  = (t >> 5) + k * 16;
        int col = (t & 31) * 8;
        int row = row0 + rr;
        if (row < N_NODES) {
            f16x8 v = *(const f16x8*)&sBuf[rr * KSTR + col];
            *(f16x8*)(C + (size_t)row * 256 + col) = v;
        }
    }
}

// reduce BN_SLOTS slots -> scale/shift (kept only for layer 2 / pools)
__global__ void bn_finalize_kernel(const float* __restrict__ slots,
                                   const float* __restrict__ g, const float* __restrict__ beta,
                                   float* __restrict__ scale, float* __restrict__ shift) {
    int c = threadIdx.x;
    float s = 0.f, q = 0.f;
    for (int k = 0; k < BN_SLOTS; ++k) {
        s += slots[(size_t)k * 512 + c];
        q += slots[(size_t)k * 512 + 256 + c];
    }
    float mu = s * (1.0f / N_NODES);
    float var = q * (1.0f / N_NODES) - mu * mu;
    float rstd = rsqrtf(var + 1e-5f);
    float sc = g[c] * rstd;
    scale[c] = sc;
    shift[c] = beta[c] - mu * sc;
}

// both segmented sqrt-pools (frag + graph) in ONE dispatch; BN at load.
__global__ __launch_bounds__(256)
void pool_both_kernel(const _Float16* __restrict__ h,
                      const int* __restrict__ frag_ptr, const int* __restrict__ graph_ptr,
                      const float* __restrict__ bnsc, const float* __restrict__ bnsh,
                      float* __restrict__ out) {
    const int NFB = (N_FRAG + 3) / 4;   // 2500 frag blocks, then graph blocks
    int b = blockIdx.x;
    const int* ptr; float* o; int nseg; int sb;
    if (b < NFB) { ptr = frag_ptr; o = out; nseg = N_FRAG; sb = b * 4; }
    else { ptr = graph_ptr; o = out + (size_t)N_FRAG * 256; nseg = N_GRAPH; sb = (b - NFB) * 4; }
    int t = threadIdx.x;
    int g = t >> 6;
    int j = t & 63;
    int s = sb + g;
    if (s >= nseg) return;
    int beg = ptr[s], end = ptr[s + 1];
    int col = j << 2;
    float4 sc = *(const float4*)(bnsc + col);
    float4 sh = *(const float4*)(bnsh + col);
    float4 acc = {0.f, 0.f, 0.f, 0.f};
    for (int i = beg; i < end; ++i) {
        float4 v = ld4(h + (size_t)i * 256 + col);
        acc.x += fmaf(v.x, sc.x, sh.x);
        acc.y += fmaf(v.y, sc.y, sh.y);
        acc.z += fmaf(v.z, sc.z, sh.z);
        acc.w += fmaf(v.w, sc.w, sh.w);
    }
    float w = rsqrtf(fmaxf((float)(end - beg), 1.0f));
    float4 ov = {acc.x * w, acc.y * w, acc.z * w, acc.w * w};
    *(float4*)(o + (size_t)s * 256 + col) = ov;
}

// ---------------------------------------------------------------------------
extern "C" void kernel_launch(void* const* d_in, const int* in_sizes, int n_in,
                              void* d_out, int out_size, void* d_ws, size_t ws_size,
                              hipStream_t stream) {
    const float* x  = (const float*)d_in[0];
    const float* ea = (const float*)d_in[1];
    const int*   ei = (const int*)d_in[2];
    const int*   fb = (const int*)d_in[3];
    const int*   gb = (const int*)d_in[4];
    const float* W1[3]   = {(const float*)d_in[5],  (const float*)d_in[11], (const float*)d_in[17]};
    const float* B1[3]   = {(const float*)d_in[6],  (const float*)d_in[12], (const float*)d_in[18]};
    const float* W2[3]   = {(const float*)d_in[7],  (const float*)d_in[13], (const float*)d_in[19]};
    const float* B2[3]   = {(const float*)d_in[8],  (const float*)d_in[14], (const float*)d_in[20]};
    const float* G[3]    = {(const float*)d_in[9],  (const float*)d_in[15], (const float*)d_in[21]};
    const float* BETA[3] = {(const float*)d_in[10], (const float*)d_in[16], (const float*)d_in[22]};

    const int FIN[3] = {160, 288, 288};
    const int NBLK = (N_NODES + 255) / 256;      // scan blocks

    float* ws = (float*)d_ws;
    size_t off = 0;
    _Float16* bufA = (_Float16*)(ws + off); off += (size_t)N_NODES * 128;  // N x 256 fp16
    _Float16* bufB = (_Float16*)(ws + off); off += (size_t)N_NODES * 128;
    _Float16* ybuf = (_Float16*)(ws + off); off += (size_t)N_NODES * 128;  // pre-activation Y
    float* agg_e = ws + off; off += (size_t)N_NODES * DE;
    float* bnss  = ws + off; off += 3 * 512;                 // per layer: scale|shift
    float* bnslots = ws + off; off += (size_t)3 * BN_SLOTS * 512;
    _Float16* w1f[3]; _Float16* w2f[3];
    {
        _Float16* sw = (_Float16*)(ws + off);
        _Float16* sw0 = sw;
        for (int l = 0; l < 3; ++l) { w1f[l] = sw; sw += 256 * FIN[l]; }
        for (int l = 0; l < 3; ++l) { w2f[l] = sw; sw += 256 * 256; }
        off += (size_t)(sw - sw0 + 1) / 2;
    }
    int* iw      = (int*)(ws + off);
    int* row_ptr = iw;                     iw += N_NODES + 1;
    int* deg     = iw;                     iw += N_NODES;
    int* fill    = iw;                     iw += N_NODES;
    int* csr_src = iw;                     iw += N_EDGES;
    int* csr_eid = iw;                     iw += N_EDGES;
    int* frag_ptr = iw;                    iw += N_FRAG + 1;
    int* graph_ptr = iw;                   iw += N_GRAPH + 1;
    int* bsum    = iw;                     iw += NBLK;

    hipMemsetAsync(deg, 0, 2 * N_NODES * sizeof(int), stream);
    hipMemsetAsync(bnslots, 0, (size_t)3 * BN_SLOTS * 512 * sizeof(float), stream);

    // weight fragment-swizzle to fp16: all 6 tensors in one dispatch
    {
        BsAll a;
        a.W[0] = W1[0]; a.W[1] = W1[1]; a.W[2] = W1[2];
        a.W[3] = W2[0]; a.W[4] = W2[1]; a.W[5] = W2[2];
        a.BS[0] = w1f[0]; a.BS[1] = w1f[1]; a.BS[2] = w1f[2];
        a.BS[3] = w2f[0]; a.BS[4] = w2f[1]; a.BS[5] = w2f[2];
        int Ks[6] = {FIN[0], FIN[1], FIN[2], 256, 256, 256};
        int cum = 0;
        for (int i = 0; i < 6; ++i) { a.base[i] = cum; cum += Ks[i] * 256; }
        a.base[6] = cum;
        bs16_all_kernel<<<(cum + 255) / 256, 256, 0, stream>>>(a);
    }

    // CSR build (hierarchical scan)
    count_deg_kernel<<<(N_EDGES + 255) / 256, 256, 0, stream>>>(ei, deg);
    block_sum_kernel<<<NBLK, 256, 0, stream>>>(deg, bsum);
    top_scan_kernel<<<1, 256, 0, stream>>>(bsum, NBLK);
    final_scan_kernel<<<NBLK, 256, 0, stream>>>(deg, bsum, row_ptr);
    fill_csr_kernel<<<(N_EDGES + 255) / 256, 256, 0, stream>>>(ei, row_ptr, fill, csr_src, csr_eid);

    segptr2_kernel<<<(N_FRAG + N_GRAPH + 2 + 255) / 256, 256, 0, stream>>>(
        fb, gb, frag_ptr, graph_ptr);

    edge_gather_kernel<<<(N_NODES + 31) / 32, 256, 0, stream>>>(ea, row_ptr, csr_eid, agg_e);

    const int nblk_mlp = (N_NODES + 63) / 64;    // 782 blocks, 64 rows each
    // layer 0: Y0 = fp16(relu(x)), self = x (fp32)
    relu16_f32_kernel<<<(N_NODES * 128 / 4 + 255) / 256, 256, 0, stream>>>(x, ybuf);
    fused_mlp_kernel<false, float, 4><<<nblk_mlp, 512, 0, stream>>>(
        x, ybuf, row_ptr, csr_src, agg_e, nullptr, nullptr,
        w1f[0], B1[0], w2f[0], B2[0], bufA, bnslots);

    // layer 1: bnfin+Y pass (computes layer-0 scale/shift in-block; block 0
    // publishes global for fused_mlp's self term), then fused MLP
    bnfin_relu16_kernel<<<1024, 256, 0, stream>>>(
        bnslots, G[0], BETA[0], bufA, ybuf, bnss, bnss + 256);
    fused_mlp_kernel<true, _Float16, 8><<<nblk_mlp, 512, 0, stream>>>(
        bufA, ybuf, row_ptr, csr_src, agg_e, bnss, bnss + 256,
        w1f[1], B1[1], w2f[1], B2[1], bufB, bnslots + (size_t)1 * BN_SLOTS * 512);

    // layer 2
    bnfin_relu16_kernel<<<1024, 256, 0, stream>>>(
        bnslots + (size_t)1 * BN_SLOTS * 512, G[1], BETA[1], bufB, ybuf,
        bnss + 512, bnss + 768);
    fused_mlp_kernel<true, _Float16, 8><<<nblk_mlp, 512, 0, stream>>>(
        bufB, ybuf, row_ptr, csr_src, agg_e, bnss + 512, bnss + 768,
        w1f[2], B1[2], w2f[2], B2[2], bufA, bnslots + (size_t)2 * BN_SLOTS * 512);

    // layer-2 BN finalize (needed by pools), then both pools in one dispatch
    bn_finalize_kernel<<<1, 256, 0, stream>>>(
        bnslots + (size_t)2 * BN_SLOTS * 512, G[2], BETA[2], bnss + 1024, bnss + 1280);
    const int NFB = (N_FRAG + 3) / 4, NGB = (N_GRAPH + 3) / 4;
    pool_both_kernel<<<NFB + NGB, 256, 0, stream>>>(
        bufA, frag_ptr, graph_ptr, bnss + 1024, bnss + 1280, (float*)d_out);
}

// Round 12
// 335.175 us; speedup vs baseline: 1.2840x; 1.0415x over previous
//
#include <hip/hip_runtime.h>

#define N_NODES 50000
#define N_EDGES 200000
#define DE 32
#define N_FRAG 10000
#define N_GRAPH 2000
#define BN_SLOTS 32
#define KSTR 296   // LDS stride (fp16 elems) for the 64-row A/h1 plane

typedef _Float16 f16x8 __attribute__((ext_vector_type(8)));
typedef _Float16 f16x4 __attribute__((ext_vector_type(4)));
typedef __attribute__((ext_vector_type(4))) float f32x4;

__device__ __forceinline__ float4 ld4(const float* p) { return *(const float4*)p; }
__device__ __forceinline__ float4 ld4(const _Float16* p) {
    f16x4 h = *(const f16x4*)p;
    float4 v; v.x = (float)h[0]; v.y = (float)h[1]; v.z = (float)h[2]; v.w = (float)h[3];
    return v;
}
__device__ __forceinline__ void st4h(_Float16* p, float4 v) {
    f16x4 h = {(_Float16)v.x, (_Float16)v.y, (_Float16)v.z, (_Float16)v.w};
    *(f16x4*)p = h;
}

// ---------------------------------------------------------------------------
// CSR scan chain (dependent, kept as 3 small kernels)
__global__ __launch_bounds__(256)
void block_sum_kernel(const int* __restrict__ deg, int* __restrict__ bsum) {
    int i = blockIdx.x * 256 + threadIdx.x;
    int v = (i < N_NODES) ? deg[i] : 0;
#pragma unroll
    for (int o = 1; o < 64; o <<= 1) v += __shfl_xor(v, o);
    __shared__ int wsum[4];
    if ((threadIdx.x & 63) == 0) wsum[threadIdx.x >> 6] = v;
    __syncthreads();
    if (threadIdx.x == 0) bsum[blockIdx.x] = wsum[0] + wsum[1] + wsum[2] + wsum[3];
}

__global__ __launch_bounds__(256)
void top_scan_kernel(int* __restrict__ bsum, int nb) {
    __shared__ int s[256];
    int t = threadIdx.x;
    s[t] = (t < nb) ? bsum[t] : 0;
    __syncthreads();
    for (int o = 1; o < 256; o <<= 1) {
        int v = s[t];
        int a = (t >= o) ? s[t - o] : 0;
        __syncthreads();
        s[t] = v + a;
        __syncthreads();
    }
    if (t < nb) bsum[t] = (t > 0) ? s[t - 1] : 0;
}

__global__ __launch_bounds__(256)
void final_scan_kernel(const int* __restrict__ deg, const int* __restrict__ bsum,
                       int* __restrict__ ptr) {
    __shared__ int s[256];
    int i = blockIdx.x * 256 + threadIdx.x;
    int t = threadIdx.x;
    int v = (i < N_NODES) ? deg[i] : 0;
    s[t] = v;
    __syncthreads();
    for (int o = 1; o < 256; o <<= 1) {
        int x = s[t];
        int a = (t >= o) ? s[t - o] : 0;
        __syncthreads();
        s[t] = x + a;
        __syncthreads();
    }
    int incl = s[t];
    int base = bsum[blockIdx.x];
    if (i < N_NODES) ptr[i] = base + incl - v;
    if (i == N_NODES - 1) ptr[N_NODES] = base + incl;
}

__global__ __launch_bounds__(256)
void fill_csr_kernel(const int* __restrict__ ei, const int* __restrict__ row_ptr,
                     int* __restrict__ fill, int* __restrict__ csr_src,
                     int* __restrict__ csr_eid) {
    int e = blockIdx.x * 256 + threadIdx.x;
    if (e >= N_EDGES) return;
    int dst = ei[N_EDGES + e];
    int pos = row_ptr[dst] + atomicAdd(&fill[dst], 1);
    csr_src[pos] = ei[e];
    csr_eid[pos] = e;
}

// ---------------------------------------------------------------------------
// prep1 mega-kernel: 4 independent jobs in one dispatch (block-range split):
//   job0 bs16_all (weight swizzle), job1 count_deg, job2 segptr (frag+graph),
//   job3 relu16 (Y0 = fp16(relu(x))).
// R11 evidence: tail is gap/serialization-dominated; merging independent
// small kernels removes 3 dispatches.
struct PrepArgs {
    const float* W[6];
    _Float16* BS[6];
    int base[7];            // cumulative bs16 element counts
    int nb_bs;
    const int* ei;
    int* deg;
    int nb_deg;
    const int* fb; const int* gb;
    int* frag_ptr; int* graph_ptr;
    int nb_seg;
    const float* x;
    _Float16* y0;
};

__global__ __launch_bounds__(256)
void prep1_kernel(PrepArgs a) {
    int b = blockIdx.x;
    const int t = threadIdx.x;
    if (b < a.nb_bs) {
        int id = b * 256 + t;
        if (id < a.base[6]) {
            int seg = 0;
#pragma unroll
            for (int i = 1; i < 6; ++i) seg += (id >= a.base[i]);
            int lid = id - a.base[seg];
            int j  = lid & 7;
            int l  = (lid >> 3) & 63;
            int cg = (lid >> 9) & 15;
            int kt = lid >> 13;
            int col = cg * 16 + (l & 15);
            int k   = kt * 32 + (l >> 4) * 8 + j;
            a.BS[seg][lid] = (_Float16)a.W[seg][(size_t)k * 256 + col];
        }
        return;
    }
    b -= a.nb_bs;
    if (b < a.nb_deg) {
        int e = b * 256 + t;
        if (e < N_EDGES) atomicAdd(&a.deg[a.ei[N_EDGES + e]], 1);
        return;
    }
    b -= a.nb_deg;
    if (b < a.nb_seg) {
        int id = b * 256 + t;
        const int* batch;
        int* ptr;
        int s;
        if (id <= N_FRAG) { batch = a.fb; ptr = a.frag_ptr; s = id; }
        else if (id <= N_FRAG + 1 + N_GRAPH) { batch = a.gb; ptr = a.graph_ptr; s = id - (N_FRAG + 1); }
        else return;
        int lo = 0, hi = N_NODES;
        while (lo < hi) {
            int mid = (lo + hi) >> 1;
            if (batch[mid] < s) lo = mid + 1; else hi = mid;
        }
        ptr[s] = lo;
        return;
    }
    b -= a.nb_seg;
    size_t i = ((size_t)b * 256 + t) * 4;   // relu16: N*128 elements
    if (i < (size_t)N_NODES * 128) {
        float4 v = ld4(a.x + i);
        f16x4 o = {(_Float16)fmaxf(v.x, 0.f), (_Float16)fmaxf(v.y, 0.f),
                   (_Float16)fmaxf(v.z, 0.f), (_Float16)fmaxf(v.w, 0.f)};
        *(f16x4*)(a.y0 + i) = o;
    }
}

// ---------------------------------------------------------------------------
// Fused BN-finalize + Y = fp16(relu(sc*h+sh)) in one dispatch; each block
// recomputes scale/shift from the L2-hot slot array (deterministic fp32);
// block 0 publishes the global copy for the next fused_mlp's self term.
__global__ __launch_bounds__(256)
void bnfin_relu16_kernel(const float* __restrict__ slots,
                         const float* __restrict__ g, const float* __restrict__ beta,
                         const _Float16* __restrict__ h, _Float16* __restrict__ y,
                         float* __restrict__ scale_out, float* __restrict__ shift_out) {
    __shared__ float ssc[256], ssh[256];
    const int t = threadIdx.x;
    {
        float s = 0.f, q = 0.f;
        for (int k = 0; k < BN_SLOTS; ++k) {
            s += slots[(size_t)k * 512 + t];
            q += slots[(size_t)k * 512 + 256 + t];
        }
        float mu = s * (1.0f / N_NODES);
        float var = q * (1.0f / N_NODES) - mu * mu;
        float rstd = rsqrtf(var + 1e-5f);
        float sc = g[t] * rstd;
        float sh = beta[t] - mu * sc;
        ssc[t] = sc; ssh[t] = sh;
        if (blockIdx.x == 0) { scale_out[t] = sc; shift_out[t] = sh; }
    }
    __syncthreads();
    const size_t total = (size_t)N_NODES * 256 / 8;
    for (size_t idx = (size_t)blockIdx.x * 256 + t; idx < total;
         idx += (size_t)gridDim.x * 256) {
        size_t i = idx * 8;
        int col = (int)(i & 255);          // constant per thread (stride % 256 == 0)
        f16x8 v = *(const f16x8*)(h + i);
        f16x8 o;
#pragma unroll
        for (int k2 = 0; k2 < 8; ++k2)
            o[k2] = (_Float16)fmaxf(fmaf((float)v[k2], ssc[col + k2], ssh[col + k2]), 0.f);
        *(f16x8*)(y + i) = o;
    }
}

// ---------------------------------------------------------------------------
// Fused gather + MLP, 64-row M-tile, 512 threads / 8 waves (R10 structure;
// stage ping-pong reverted — proven null in R11).
// Layer 0 (!BNIN) additionally aggregates relu(edge_attr) INLINE in the same
// CSR walk (fp32, CSR order — bit-identical to the old edge_gather kernel),
// writes agg_e for layers 1/2, and uses it for its own LDS tail. This
// deletes the standalone edge_gather dispatch; its latency-bound loads hide
// under the stage's existing stalls.
template <bool BNIN, typename T, int NC>   // DIN = NC*32, K1 = DIN+32
__global__ __launch_bounds__(512, 4)
void fused_mlp_kernel(const T* __restrict__ X, const _Float16* __restrict__ Yg,
                      const int* __restrict__ row_ptr, const int* __restrict__ csr_src,
                      const int* __restrict__ csr_eid, const float* __restrict__ ea,
                      float* __restrict__ agg_e,
                      const float* __restrict__ bnsc, const float* __restrict__ bnsh,
                      const _Float16* __restrict__ B1, const float* __restrict__ bias1,
                      const _Float16* __restrict__ B2, const float* __restrict__ bias2,
                      _Float16* __restrict__ C, float* __restrict__ bnslot) {
    constexpr int DIN  = NC * 32;
    constexpr int K1   = DIN + 32;
    constexpr int NKT1 = K1 / 32;
    constexpr int CPT  = DIN / 8;        // cols per stage-thread
    constexpr int NV   = CPT / 8;        // f16x8 chunks per stage-thread
    __shared__ __align__(16) _Float16 sBuf[64 * KSTR];   // A tile, h1, then C
    const int t = threadIdx.x;
    const int l = t & 63;
    const int w = t >> 6;                // 8 waves
    const int lr = l & 15;
    const int lq = l >> 4;
    const int row0 = blockIdx.x << 6;    // 64 rows/block
    const int cb = w << 5;               // 32-col slab per wave

    // ---- stage: gather-aggregate into LDS (8 threads/row, 64 rows) ----
    {
        const int r = t >> 3, j = t & 7;
        const int jc = j << 3;           // lane's 8-col offset within a chunk
        const int gr = row0 + r;
        if (gr < N_NODES) {
            f16x8 acc16[NV];
#pragma unroll
            for (int c = 0; c < NV; ++c) acc16[c] = (f16x8){0, 0, 0, 0, 0, 0, 0, 0};
            float4 eacc = {0.f, 0.f, 0.f, 0.f};
            const int beg = row_ptr[gr], end = row_ptr[gr + 1];
            for (int e = beg; e < end; ++e) {
                const _Float16* sp = Yg + (size_t)csr_src[e] * DIN + jc;
#pragma unroll
                for (int c = 0; c < NV; ++c) acc16[c] += *(const f16x8*)(sp + c * 64);
                if (!BNIN) {
                    float4 ev = *(const float4*)(ea + (size_t)csr_eid[e] * DE + (j << 2));
                    eacc.x += fmaxf(ev.x, 0.f);
                    eacc.y += fmaxf(ev.y, 0.f);
                    eacc.z += fmaxf(ev.z, 0.f);
                    eacc.w += fmaxf(ev.w, 0.f);
                }
            }
            // self term (BN if BNIN, no relu) + fp16 neighbor sum
            const T* xp = X + (size_t)gr * DIN + jc;
#pragma unroll
            for (int c = 0; c < NV; ++c) {
                float4 v0f = ld4(xp + c * 64);
                float4 v1f = ld4(xp + c * 64 + 4);
                if (BNIN) {
                    float4 sa = *(const float4*)(bnsc + c * 64 + jc);
                    float4 sb = *(const float4*)(bnsc + c * 64 + jc + 4);
                    float4 ta = *(const float4*)(bnsh + c * 64 + jc);
                    float4 tb = *(const float4*)(bnsh + c * 64 + jc + 4);
                    v0f.x = fmaf(v0f.x, sa.x, ta.x);
                    v0f.y = fmaf(v0f.y, sa.y, ta.y);
                    v0f.z = fmaf(v0f.z, sa.z, ta.z);
                    v0f.w = fmaf(v0f.w, sa.w, ta.w);
                    v1f.x = fmaf(v1f.x, sb.x, tb.x);
                    v1f.y = fmaf(v1f.y, sb.y, tb.y);
                    v1f.z = fmaf(v1f.z, sb.z, tb.z);
                    v1f.w = fmaf(v1f.w, sb.w, tb.w);
                }
                f16x8 o;
                o[0] = (_Float16)(v0f.x + (float)acc16[c][0]);
                o[1] = (_Float16)(v0f.y + (float)acc16[c][1]);
                o[2] = (_Float16)(v0f.z + (float)acc16[c][2]);
                o[3] = (_Float16)(v0f.w + (float)acc16[c][3]);
                o[4] = (_Float16)(v1f.x + (float)acc16[c][4]);
                o[5] = (_Float16)(v1f.y + (float)acc16[c][5]);
                o[6] = (_Float16)(v1f.z + (float)acc16[c][6]);
                o[7] = (_Float16)(v1f.w + (float)acc16[c][7]);
                *(f16x8*)&sBuf[r * KSTR + c * 64 + jc] = o;
            }
            if (!BNIN) {
                *(float4*)(agg_e + (size_t)gr * DE + (j << 2)) = eacc;  // for l1/l2
                st4h(&sBuf[r * KSTR + DIN + (j << 2)], eacc);
            } else {
                float4 ev = *(const float4*)(agg_e + (size_t)gr * DE + (j << 2));
                st4h(&sBuf[r * KSTR + DIN + (j << 2)], ev);
            }
        } else {
            f16x8 z8 = {0, 0, 0, 0, 0, 0, 0, 0};
#pragma unroll
            for (int c = 0; c < NV; ++c)
                *(f16x8*)&sBuf[r * KSTR + c * 64 + jc] = z8;
            f16x4 z4 = {0, 0, 0, 0};
            *(f16x4*)&sBuf[r * KSTR + DIN + (j << 2)] = z4;
        }
    }
    __syncthreads();

    // ---- phase 1: A @ W1 (barrier-free) ----
    f32x4 acc1[4][2];
#pragma unroll
    for (int mt = 0; mt < 4; ++mt)
#pragma unroll
        for (int nt = 0; nt < 2; ++nt) acc1[mt][nt] = (f32x4){0.f, 0.f, 0.f, 0.f};
#pragma unroll
    for (int kt = 0; kt < NKT1; ++kt) {
        f16x8 af[4], bf[2];
#pragma unroll
        for (int mt = 0; mt < 4; ++mt)
            af[mt] = *(const f16x8*)&sBuf[(mt * 16 + lr) * KSTR + (kt << 5) + (lq << 3)];
        const size_t bb = ((size_t)(kt * 16 + (w << 1))) * 512 + (l << 3);
#pragma unroll
        for (int nt = 0; nt < 2; ++nt)
            bf[nt] = *(const f16x8*)(B1 + bb + nt * 512);
#pragma unroll
        for (int mt = 0; mt < 4; ++mt)
#pragma unroll
            for (int nt = 0; nt < 2; ++nt)
                acc1[mt][nt] = __builtin_amdgcn_mfma_f32_16x16x32_f16(
                    af[mt], bf[nt], acc1[mt][nt], 0, 0, 0);
    }
    __syncthreads();   // A tile dead; reuse plane for h1

    // ---- epilogue 1: relu(h1) -> LDS fp16 ----
#pragma unroll
    for (int nt = 0; nt < 2; ++nt) {
        int col = cb + nt * 16 + lr;
        float bv = bias1[col];
#pragma unroll
        for (int mt = 0; mt < 4; ++mt)
#pragma unroll
            for (int i = 0; i < 4; ++i) {
                int rr = mt * 16 + lq * 4 + i;
                sBuf[rr * KSTR + col] = (_Float16)fmaxf(acc1[mt][nt][i] + bv, 0.f);
            }
    }
    __syncthreads();

    // ---- phase 2: h1 @ W2 (barrier-free) ----
    f32x4 acc2[4][2];
#pragma unroll
    for (int mt = 0; mt < 4; ++mt)
#pragma unroll
        for (int nt = 0; nt < 2; ++nt) acc2[mt][nt] = (f32x4){0.f, 0.f, 0.f, 0.f};
#pragma unroll
    for (int kt = 0; kt < 8; ++kt) {
        f16x8 af[4], bf[2];
#pragma unroll
        for (int mt = 0; mt < 4; ++mt)
            af[mt] = *(const f16x8*)&sBuf[(mt * 16 + lr) * KSTR + (kt << 5) + (lq << 3)];
        const size_t bb = ((size_t)(kt * 16 + (w << 1))) * 512 + (l << 3);
#pragma unroll
        for (int nt = 0; nt < 2; ++nt)
            bf[nt] = *(const f16x8*)(B2 + bb + nt * 512);
#pragma unroll
        for (int mt = 0; mt < 4; ++mt)
#pragma unroll
            for (int nt = 0; nt < 2; ++nt)
                acc2[mt][nt] = __builtin_amdgcn_mfma_f32_16x16x32_f16(
                    af[mt], bf[nt], acc2[mt][nt], 0, 0, 0);
    }
    __syncthreads();   // h1 reads done; reuse plane for C staging

    // ---- epilogue 2: bias + relu -> LDS fp16 + BN stats ----
    float* slot = bnslot + (size_t)(blockIdx.x & (BN_SLOTS - 1)) * 512;
#pragma unroll
    for (int nt = 0; nt < 2; ++nt) {
        int col = cb + nt * 16 + lr;
        float bv = bias2[col];
        float s = 0.f, qq = 0.f;
#pragma unroll
        for (int mt = 0; mt < 4; ++mt)
#pragma unroll
            for (int i = 0; i < 4; ++i) {
                int rr = mt * 16 + lq * 4 + i;
                float o = fmaxf(acc2[mt][nt][i] + bv, 0.f);
                sBuf[rr * KSTR + col] = (_Float16)o;
                if (row0 + rr < N_NODES) { s += o; qq += o * o; }
            }
        s += __shfl_xor(s, 16); s += __shfl_xor(s, 32);
        qq += __shfl_xor(qq, 16); qq += __shfl_xor(qq, 32);
        if (lq == 0) {
            atomicAdd(&slot[col], s);
            atomicAdd(&slot[256 + col], qq);
        }
    }
    __syncthreads();

    // ---- coalesced C write: f16x8 per thread, 512B contiguous per row ----
#pragma unroll
    for (int k = 0; k < 4; ++k) {
        int rr  = (t >> 5) + k * 16;
        int col = (t & 31) * 8;
        int row = row0 + rr;
        if (row < N_NODES) {
            f16x8 v = *(const f16x8*)&sBuf[rr * KSTR + col];
            *(f16x8*)(C + (size_t)row * 256 + col) = v;
        }
    }
}

// ---------------------------------------------------------------------------
// Both segmented sqrt-pools (frag + graph) in ONE dispatch, with layer-2
// BN finalize computed per-block in a prologue (L2-hot slots) — removes the
// single-block bn_finalize dispatch.
__global__ __launch_bounds__(256)
void pool_both_kernel(const _Float16* __restrict__ h,
                      const int* __restrict__ frag_ptr, const int* __restrict__ graph_ptr,
                      const float* __restrict__ slots,
                      const float* __restrict__ g2, const float* __restrict__ beta2,
                      float* __restrict__ out) {
    __shared__ float ssc[256], ssh[256];
    const int t = threadIdx.x;
    {
        float s = 0.f, q = 0.f;
        for (int k = 0; k < BN_SLOTS; ++k) {
            s += slots[(size_t)k * 512 + t];
            q += slots[(size_t)k * 512 + 256 + t];
        }
        float mu = s * (1.0f / N_NODES);
        float var = q * (1.0f / N_NODES) - mu * mu;
        float rstd = rsqrtf(var + 1e-5f);
        float sc = g2[t] * rstd;
        ssc[t] = sc;
        ssh[t] = beta2[t] - mu * sc;
    }
    __syncthreads();
    const int NFB = (N_FRAG + 3) / 4;   // frag blocks first, then graph
    int b = blockIdx.x;
    const int* ptr; float* o; int nseg; int sb;
    if (b < NFB) { ptr = frag_ptr; o = out; nseg = N_FRAG; sb = b * 4; }
    else { ptr = graph_ptr; o = out + (size_t)N_FRAG * 256; nseg = N_GRAPH; sb = (b - NFB) * 4; }
    int g = t >> 6;
    int j = t & 63;
    int s = sb + g;
    if (s >= nseg) return;
    int beg = ptr[s], end = ptr[s + 1];
    int col = j << 2;
    float4 sc = *(const float4*)(ssc + col);
    float4 sh = *(const float4*)(ssh + col);
    float4 acc = {0.f, 0.f, 0.f, 0.f};
    for (int i = beg; i < end; ++i) {
        float4 v = ld4(h + (size_t)i * 256 + col);
        acc.x += fmaf(v.x, sc.x, sh.x);
        acc.y += fmaf(v.y, sc.y, sh.y);
        acc.z += fmaf(v.z, sc.z, sh.z);
        acc.w += fmaf(v.w, sc.w, sh.w);
    }
    float w = rsqrtf(fmaxf((float)(end - beg), 1.0f));
    float4 ov = {acc.x * w, acc.y * w, acc.z * w, acc.w * w};
    *(float4*)(o + (size_t)s * 256 + col) = ov;
}

// ---------------------------------------------------------------------------
extern "C" void kernel_launch(void* const* d_in, const int* in_sizes, int n_in,
                              void* d_out, int out_size, void* d_ws, size_t ws_size,
                              hipStream_t stream) {
    const float* x  = (const float*)d_in[0];
    const float* ea = (const float*)d_in[1];
    const int*   ei = (const int*)d_in[2];
    const int*   fb = (const int*)d_in[3];
    const int*   gb = (const int*)d_in[4];
    const float* W1[3]   = {(const float*)d_in[5],  (const float*)d_in[11], (const float*)d_in[17]};
    const float* B1[3]   = {(const float*)d_in[6],  (const float*)d_in[12], (const float*)d_in[18]};
    const float* W2[3]   = {(const float*)d_in[7],  (const float*)d_in[13], (const float*)d_in[19]};
    const float* B2[3]   = {(const float*)d_in[8],  (const float*)d_in[14], (const float*)d_in[20]};
    const float* G[3]    = {(const float*)d_in[9],  (const float*)d_in[15], (const float*)d_in[21]};
    const float* BETA[3] = {(const float*)d_in[10], (const float*)d_in[16], (const float*)d_in[22]};

    const int FIN[3] = {160, 288, 288};
    const int NBLK = (N_NODES + 255) / 256;      // scan blocks

    float* ws = (float*)d_ws;
    size_t off = 0;
    _Float16* bufA = (_Float16*)(ws + off); off += (size_t)N_NODES * 128;  // N x 256 fp16
    _Float16* bufB = (_Float16*)(ws + off); off += (size_t)N_NODES * 128;
    _Float16* ybuf = (_Float16*)(ws + off); off += (size_t)N_NODES * 128;  // pre-activation Y
    float* agg_e = ws + off; off += (size_t)N_NODES * DE;
    float* bnss  = ws + off; off += 3 * 512;                 // per layer: scale|shift
    float* bnslots = ws + off; off += (size_t)3 * BN_SLOTS * 512;
    _Float16* w1f[3]; _Float16* w2f[3];
    {
        _Float16* sw = (_Float16*)(ws + off);
        _Float16* sw0 = sw;
        for (int l = 0; l < 3; ++l) { w1f[l] = sw; sw += 256 * FIN[l]; }
        for (int l = 0; l < 3; ++l) { w2f[l] = sw; sw += 256 * 256; }
        off += (size_t)(sw - sw0 + 1) / 2;
    }
    int* iw      = (int*)(ws + off);
    int* row_ptr = iw;                     iw += N_NODES + 1;
    int* deg     = iw;                     iw += N_NODES;
    int* fill    = iw;                     iw += N_NODES;
    int* csr_src = iw;                     iw += N_EDGES;
    int* csr_eid = iw;                     iw += N_EDGES;
    int* frag_ptr = iw;                    iw += N_FRAG + 1;
    int* graph_ptr = iw;                   iw += N_GRAPH + 1;
    int* bsum    = iw;                     iw += NBLK;

    hipMemsetAsync(deg, 0, 2 * N_NODES * sizeof(int), stream);
    hipMemsetAsync(bnslots, 0, (size_t)3 * BN_SLOTS * 512 * sizeof(float), stream);

    // prep1: weight swizzle + deg count + segptrs + Y0 relu, one dispatch
    {
        PrepArgs a;
        a.W[0] = W1[0]; a.W[1] = W1[1]; a.W[2] = W1[2];
        a.W[3] = W2[0]; a.W[4] = W2[1]; a.W[5] = W2[2];
        a.BS[0] = w1f[0]; a.BS[1] = w1f[1]; a.BS[2] = w1f[2];
        a.BS[3] = w2f[0]; a.BS[4] = w2f[1]; a.BS[5] = w2f[2];
        int Ks[6] = {FIN[0], FIN[1], FIN[2], 256, 256, 256};
        int cum = 0;
        for (int i = 0; i < 6; ++i) { a.base[i] = cum; cum += Ks[i] * 256; }
        a.base[6] = cum;
        a.nb_bs  = (cum + 255) / 256;
        a.ei = ei; a.deg = deg;
        a.nb_deg = (N_EDGES + 255) / 256;
        a.fb = fb; a.gb = gb; a.frag_ptr = frag_ptr; a.graph_ptr = graph_ptr;
        a.nb_seg = (N_FRAG + N_GRAPH + 2 + 255) / 256;
        a.x = x; a.y0 = ybuf;
        int nb_relu = (N_NODES * 128 / 4 + 255) / 256;
        prep1_kernel<<<a.nb_bs + a.nb_deg + a.nb_seg + nb_relu, 256, 0, stream>>>(a);
    }

    // CSR scan chain + fill
    block_sum_kernel<<<NBLK, 256, 0, stream>>>(deg, bsum);
    top_scan_kernel<<<1, 256, 0, stream>>>(bsum, NBLK);
    final_scan_kernel<<<NBLK, 256, 0, stream>>>(deg, bsum, row_ptr);
    fill_csr_kernel<<<(N_EDGES + 255) / 256, 256, 0, stream>>>(ei, row_ptr, fill, csr_src, csr_eid);

    const int nblk_mlp = (N_NODES + 63) / 64;    // 782 blocks, 64 rows each
    // layer 0: inline edge aggregation (writes agg_e), self = x (fp32)
    fused_mlp_kernel<false, float, 4><<<nblk_mlp, 512, 0, stream>>>(
        x, ybuf, row_ptr, csr_src, csr_eid, ea, agg_e, nullptr, nullptr,
        w1f[0], B1[0], w2f[0], B2[0], bufA, bnslots);

    // layer 1
    bnfin_relu16_kernel<<<512, 256, 0, stream>>>(
        bnslots, G[0], BETA[0], bufA, ybuf, bnss, bnss + 256);
    fused_mlp_kernel<true, _Float16, 8><<<nblk_mlp, 512, 0, stream>>>(
        bufA, ybuf, row_ptr, csr_src, nullptr, nullptr, agg_e, bnss, bnss + 256,
        w1f[1], B1[1], w2f[1], B2[1], bufB, bnslots + (size_t)1 * BN_SLOTS * 512);

    // layer 2
    bnfin_relu16_kernel<<<512, 256, 0, stream>>>(
        bnslots + (size_t)1 * BN_SLOTS * 512, G[1], BETA[1], bufB, ybuf,
        bnss + 512, bnss + 768);
    fused_mlp_kernel<true, _Float16, 8><<<nblk_mlp, 512, 0, stream>>>(
        bufB, ybuf, row_ptr, csr_src, nullptr, nullptr, agg_e, bnss + 512, bnss + 768,
        w1f[2], B1[2], w2f[2], B2[2], bufA, bnslots + (size_t)2 * BN_SLOTS * 512);

    // both pools, with layer-2 BN finalize inline (per-block prologue)
    const int NFB = (N_FRAG + 3) / 4, NGB = (N_GRAPH + 3) / 4;
    pool_both_kernel<<<NFB + NGB, 256, 0, stream>>>(
        bufA, frag_ptr, graph_ptr, bnslots + (size_t)2 * BN_SLOTS * 512,
        G[2], BETA[2], (float*)d_out);
}